// Round 3
// baseline (6909.815 us; speedup 1.0000x reference)
//
#include <hip/hip_runtime.h>
#include <hip/hip_bf16.h>
#include <math.h>

#define N_NODES 10000
#define N_EDGES 160000
#define EB 8

__device__ __forceinline__ float sigmoidf_(float x){ return 1.f/(1.f+__expf(-x)); }
__device__ __forceinline__ unsigned short f2bf(float x){
  __hip_bfloat16 h = __float2bfloat16(x);
  return *reinterpret_cast<unsigned short*>(&h);
}

// ---------------- Kernel A: node transforms (unchanged) ----------------
__global__ __launch_bounds__(256) void k_node(
    const float* __restrict__ node_input,
    const float* __restrict__ w_src0, const float* __restrict__ b_src0,
    const float* __restrict__ w_src1,
    const float* __restrict__ w_dst0, const float* __restrict__ b_dst0,
    const float* __restrict__ w_dst1,
    float* __restrict__ ns_src, float* __restrict__ ns_dst,
    float* __restrict__ nv_src, float* __restrict__ nv_dst)
{
  __shared__ float sNI[8*321];
  int t = threadIdx.x;
  int n0 = blockIdx.x*8;
  for (int idx=t; idx<8*320; idx+=256){
    int nd = idx/320, r = idx - nd*320;
    sNI[nd*321+r] = node_input[(size_t)(n0+nd)*320 + r];
  }
  __syncthreads();
  {
    int o = t & 127, half = t >> 7;
    const float* w = half ? w_dst0 : w_src0;
    const float* b = half ? b_dst0 : b_src0;
    float* outp = half ? ns_dst : ns_src;
    float acc[8];
    #pragma unroll
    for (int nd=0;nd<8;nd++) acc[nd]=0.f;
    for (int k=0;k<128;k++){
      float wv = w[k*128+o];
      #pragma unroll
      for (int nd=0;nd<8;nd++) acc[nd] += sNI[nd*321+k]*wv;
    }
    const float rs = 0.08838834764831845f;
    float bo = b[o];
    #pragma unroll
    for (int nd=0;nd<8;nd++) outp[(size_t)(n0+nd)*128+o] = acc[nd]*rs + bo;
  }
  if (t < 192){
    int o = t & 63, c = t >> 6;
    for (int half=0; half<2; half++){
      const float* w = half ? w_dst1 : w_src1;
      float* outp = half ? nv_dst : nv_src;
      float acc[8];
      #pragma unroll
      for (int nd=0;nd<8;nd++) acc[nd]=0.f;
      for (int i=0;i<64;i++){
        float wv = w[i*64+o];
        #pragma unroll
        for (int nd=0;nd<8;nd++) acc[nd] += sNI[nd*321+128+i*3+c]*wv;
      }
      #pragma unroll
      for (int nd=0;nd<8;nd++) outp[(size_t)(n0+nd)*192 + o*3 + c] = acc[nd]*0.125f;
    }
  }
}

// ---------------- Kernel C: fused edge pipeline, register-tiled ----------------
#define OEA 0
#define OMV 32
#define OASV 1600
#define OBVS 2656
#define OWV1 3176
#define OES 3696
#define OH1 4240
#define OH2 4784
#define OMS 5328
#define OD0 6384
#define OD1 3696
#define OA 7952

__global__ __launch_bounds__(256,4) void k_edge2(
  const float* __restrict__ edge_attr, const float* __restrict__ edge_scalars,
  const int* __restrict__ edge_src, const int* __restrict__ edge_dst,
  const float* __restrict__ ns_src, const float* __restrict__ ns_dst,
  const float* __restrict__ nv_src, const float* __restrict__ nv_dst,
  const float* __restrict__ rw1, const float* __restrict__ rb1,
  const float* __restrict__ rw2, const float* __restrict__ rb2,
  const float* __restrict__ rw3, const float* __restrict__ rb3,
  const float* __restrict__ lw0, const float* __restrict__ lb0,
  const float* __restrict__ lw1, const float* __restrict__ alpha_dot,
  float* __restrict__ galpha, __hip_bfloat16* __restrict__ gval,
  __hip_bfloat16* __restrict__ gm1)
{
  __shared__ __align__(16) float L[8464];
  const int t = threadIdx.x;
  const int e0 = blockIdx.x * EB;

  // ---- P0: stage MS (all threads, FULL 128/edge), MV (all), ES (t<128), EA (t<32) ----
  {
    int e = t>>5, l = t&31;
    int s = edge_src[e0+e], d = edge_dst[e0+e];
    { // MS: 32 lanes x float4 = 128 floats per edge
      float4 a = *(const float4*)&ns_src[(size_t)s*128 + l*4];
      float4 b = *(const float4*)&ns_dst[(size_t)d*128 + l*4];
      float4 r; r.x=a.x+b.x; r.y=a.y+b.y; r.z=a.z+b.z; r.w=a.w+b.w;
      *(float4*)&L[OMS + e*132 + l*4] = r;
    }
    #pragma unroll
    for (int j=0;j<2;j++){ // MV: 48 float4 = 192 floats per edge
      int idx = l + 32*j;
      if (idx < 48){
        float4 a = *(const float4*)&nv_src[(size_t)s*192 + idx*4];
        float4 b = *(const float4*)&nv_dst[(size_t)d*192 + idx*4];
        float4 r; r.x=a.x+b.x; r.y=a.y+b.y; r.z=a.z+b.z; r.w=a.w+b.w;
        *(float4*)&L[OMV + e*196 + idx*4] = r;
      }
    }
  }
  if (t < 128){
    int e = t>>4, l = t&15;
    *(float4*)&L[OES + e*68 + l*4] = *(const float4*)&edge_scalars[(size_t)(e0+e)*64 + l*4];
  }
  if (t < 32){ int e=t>>2, c=t&3; L[OEA + e*4 + c] = edge_attr[(size_t)(e0+e)*4 + c]; }
  __syncthreads();

  // ---- P1: h1 = silu(es @ rw1 + rb1) ----
  {
    int e = t>>5, o = (t&31)*2;
    float a0 = rb1[o], a1 = rb1[o+1];
    for (int k=0;k<64;k+=4){
      float4 x = *(const float4*)&L[OES + e*68 + k];
      #pragma unroll
      for (int kk=0;kk<4;kk++){
        float2 w = *(const float2*)&rw1[(k+kk)*64 + o];
        float xv = (kk==0)?x.x:(kk==1)?x.y:(kk==2)?x.z:x.w;
        a0 += xv*w.x; a1 += xv*w.y;
      }
    }
    L[OH1 + e*68 + o]   = a0*sigmoidf_(a0);
    L[OH1 + e*68 + o+1] = a1*sigmoidf_(a1);
  }
  __syncthreads();

  // ---- P2: h2 = silu(h1 @ rw2 + rb2) ----
  {
    int e = t>>5, o = (t&31)*2;
    float a0 = rb2[o], a1 = rb2[o+1];
    for (int k=0;k<64;k+=4){
      float4 x = *(const float4*)&L[OH1 + e*68 + k];
      #pragma unroll
      for (int kk=0;kk<4;kk++){
        float2 w = *(const float2*)&rw2[(k+kk)*64 + o];
        float xv = (kk==0)?x.x:(kk==1)?x.y:(kk==2)?x.z:x.w;
        a0 += xv*w.x; a1 += xv*w.y;
      }
    }
    L[OH2 + e*68 + o]   = a0*sigmoidf_(a0);
    L[OH2 + e*68 + o+1] = a1*sigmoidf_(a1);
  }
  __syncthreads();

  // ---- P3: w = h2 @ rw3 + rb3, consumed on the fly ----
  {
    int og = t&63, eg = t>>6;
    int ea = eg*2, eb = ea+1;
    float esA = L[OEA + ea*4], esB = L[OEA + eb*4];
    {
      int o = og*4;
      float a0[4], a1[4];
      #pragma unroll
      for (int j=0;j<4;j++){ a0[j]=rb3[o+j]; a1[j]=a0[j]; }
      for (int k=0;k<64;k+=4){
        float4 h0 = *(const float4*)&L[OH2 + ea*68 + k];
        float4 h1 = *(const float4*)&L[OH2 + eb*68 + k];
        #pragma unroll
        for (int kk=0;kk<4;kk++){
          float4 w = *(const float4*)&rw3[(size_t)(k+kk)*448 + o];
          float x0 = (kk==0)?h0.x:(kk==1)?h0.y:(kk==2)?h0.z:h0.w;
          float x1 = (kk==0)?h1.x:(kk==1)?h1.y:(kk==2)?h1.z:h1.w;
          a0[0]+=x0*w.x; a0[1]+=x0*w.y; a0[2]+=x0*w.z; a0[3]+=x0*w.w;
          a1[0]+=x1*w.x; a1[1]+=x1*w.y; a1[2]+=x1*w.z; a1[3]+=x1*w.w;
        }
      }
      if (og < 32){
        float4 msA = *(const float4*)&L[OMS + ea*132 + o];
        float4 msB = *(const float4*)&L[OMS + eb*132 + o];
        float4 rA; rA.x=a0[0]*msA.x*esA; rA.y=a0[1]*msA.y*esA; rA.z=a0[2]*msA.z*esA; rA.w=a0[3]*msA.w*esA;
        float4 rB; rB.x=a1[0]*msB.x*esB; rB.y=a1[1]*msB.y*esB; rB.z=a1[2]*msB.z*esB; rB.w=a1[3]*msB.w*esB;
        *(float4*)&L[OD0 + ea*196 + o] = rA;
        *(float4*)&L[OD0 + eb*196 + o] = rB;
      } else {
        int oo = o-128;
        float4 msA = *(const float4*)&L[OMS + ea*132 + oo];
        float4 msB = *(const float4*)&L[OMS + eb*132 + oo];
        float4 rA; rA.x=a0[0]*msA.x; rA.y=a0[1]*msA.y; rA.z=a0[2]*msA.z; rA.w=a0[3]*msA.w;
        float4 rB; rB.x=a1[0]*msB.x; rB.y=a1[1]*msB.y; rB.z=a1[2]*msB.z; rB.w=a1[3]*msB.w;
        *(float4*)&L[OASV + ea*132 + oo] = rA;
        *(float4*)&L[OASV + eb*132 + oo] = rB;
      }
    }
    {
      int o1 = 256 + og*3;
      float a0[3], a1[3];
      #pragma unroll
      for (int j=0;j<3;j++){ a0[j]=rb3[o1+j]; a1[j]=a0[j]; }
      for (int k=0;k<64;k+=4){
        float4 h0 = *(const float4*)&L[OH2 + ea*68 + k];
        float4 h1 = *(const float4*)&L[OH2 + eb*68 + k];
        #pragma unroll
        for (int kk=0;kk<4;kk++){
          float x0 = (kk==0)?h0.x:(kk==1)?h0.y:(kk==2)?h0.z:h0.w;
          float x1 = (kk==0)?h1.x:(kk==1)?h1.y:(kk==2)?h1.z:h1.w;
          #pragma unroll
          for (int j=0;j<3;j++){
            float w = rw3[(size_t)(k+kk)*448 + o1 + j];
            a0[j]+=x0*w; a1[j]+=x1*w;
          }
        }
      }
      #pragma unroll
      for (int e2=0;e2<2;e2++){
        int e = eg*2+e2;
        float es = (e2==0)?esA:esB;
        #pragma unroll
        for (int j=0;j<3;j++){
          int col = o1+j;
          float a = (e2==0)?a0[j]:a1[j];
          if (col < 320){
            L[OBVS + e*65 + (col-256)] = a*es;
          } else if (col < 384){
            int oo = col-320;
            float dot = L[OMV+e*196+oo*3]  *L[OEA+e*4+1]
                      + L[OMV+e*196+oo*3+1]*L[OEA+e*4+2]
                      + L[OMV+e*196+oo*3+2]*L[OEA+e*4+3];
            L[OD0 + e*196 + 128 + oo] = a*dot*0.5773502691896258f;
          } else {
            L[OWV1 + e*65 + (col-384)] = a*0.7071067811865476f;
          }
        }
      }
    }
  }
  __syncthreads();

  // ---- P4: m0 = d0 @ lw0 /sqrt(192) + lb0 ; alpha logits + val_s out ----
  {
    int og = t&63, eg = t>>6;
    float palpha[2]; palpha[0]=0.f; palpha[1]=0.f;
    int isalpha = 0, h4 = 0;
    if (og < 40){
      int o = og*4, ea = eg*2;
      float a0[4], a1[4];
      #pragma unroll
      for (int j=0;j<4;j++){ a0[j]=0.f; a1[j]=0.f; }
      for (int k=0;k<192;k+=4){
        float4 d0a = *(const float4*)&L[OD0 + ea*196 + k];
        float4 d0b = *(const float4*)&L[OD0 + (ea+1)*196 + k];
        #pragma unroll
        for (int kk=0;kk<4;kk++){
          float4 w = *(const float4*)&lw0[(size_t)(k+kk)*160 + o];
          float x0 = (kk==0)?d0a.x:(kk==1)?d0a.y:(kk==2)?d0a.z:d0a.w;
          float x1 = (kk==0)?d0b.x:(kk==1)?d0b.y:(kk==2)?d0b.z:d0b.w;
          a0[0]+=x0*w.x; a0[1]+=x0*w.y; a0[2]+=x0*w.z; a0[3]+=x0*w.w;
          a1[0]+=x1*w.x; a1[1]+=x1*w.y; a1[2]+=x1*w.z; a1[3]+=x1*w.w;
        }
      }
      const float rs = 0.07216878364870323f;
      int h = o/40, kk0 = o%40;
      if (kk0 < 8){
        h4 = h; isalpha = 1;
        #pragma unroll
        for (int e2=0;e2<2;e2++){
          float p = 0.f;
          #pragma unroll
          for (int j=0;j<4;j++){
            float m = ((e2==0)?a0[j]:a1[j])*rs + lb0[o+j];
            float act = 0.6f*m + 0.4f*m*(2.f*sigmoidf_(m)-1.f);
            p += act * alpha_dot[h*8 + kk0 + j];
          }
          palpha[e2] = p;
        }
      } else {
        #pragma unroll
        for (int e2=0;e2<2;e2++){
          int e = eg*2+e2;
          ushort4 u;
          u.x = f2bf(((e2==0)?a0[0]:a1[0])*rs + lb0[o]);
          u.y = f2bf(((e2==0)?a0[1]:a1[1])*rs + lb0[o+1]);
          u.z = f2bf(((e2==0)?a0[2]:a1[2])*rs + lb0[o+2]);
          u.w = f2bf(((e2==0)?a0[3]:a1[3])*rs + lb0[o+3]);
          *(ushort4*)&gval[(size_t)(e0+e)*128 + h*32 + (kk0-8)] = u;
        }
      }
    }
    if (isalpha){
      float q0 = __shfl_down(palpha[0], 1);
      float q1 = __shfl_down(palpha[1], 1);
      if ((og%10)==0){
        int e = eg*2;
        galpha[(size_t)(e0+e)*4 + h4]   = palpha[0]+q0;
        galpha[(size_t)(e0+e+1)*4 + h4] = palpha[1]+q1;
      }
    }
  }
  __syncthreads();

  // ---- P5-prep: build d1 (3 comps) + A = asv @ lw1[0:128] ----
  {
    for (int idx=t; idx<3072; idx+=256){
      int c = idx>>10, rem = idx&1023, e = rem>>7, i = rem&127;
      float v;
      if (i < 64){
        v = L[OBVS + e*65 + i] * L[OMV + e*196 + i*3 + c];
      } else {
        int ii = i-64;
        int ca = (c+1)%3, cb = (c+2)%3;
        v = L[OWV1 + e*65 + ii] *
            (L[OMV+e*196+ii*3+ca]*L[OEA+e*4+1+cb] - L[OMV+e*196+ii*3+cb]*L[OEA+e*4+1+ca]);
      }
      L[OD1 + c*1056 + e*132 + i] = v;
    }
    int e = t>>5, oo = (t&31)*2;
    float a0=0.f, a1=0.f;
    for (int k=0;k<128;k+=4){
      float4 x = *(const float4*)&L[OASV + e*132 + k];
      #pragma unroll
      for (int kk=0;kk<4;kk++){
        float2 w = *(const float2*)&lw1[(size_t)(k+kk)*64 + oo];
        float xv = (kk==0)?x.x:(kk==1)?x.y:(kk==2)?x.z:x.w;
        a0 += xv*w.x; a1 += xv*w.y;
      }
    }
    L[OA + e*64 + oo]   = a0;
    L[OA + e*64 + oo+1] = a1;
  }
  __syncthreads();

  // ---- P5b: m1[c] = (A*ev_c  ++  d1c @ lw1[128:256]) /16 ----
  if (t < 192){
    int og = t&15, sub = t>>4;
    int c = sub>>2, eg = sub&3;
    int o = og*4, ea = eg*2;
    float a0[4], a1[4];
    {
      float evA = L[OEA + ea*4 + 1 + c], evB = L[OEA + (ea+1)*4 + 1 + c];
      float4 AA = *(const float4*)&L[OA + ea*64 + o];
      float4 AB = *(const float4*)&L[OA + (ea+1)*64 + o];
      a0[0]=AA.x*evA; a0[1]=AA.y*evA; a0[2]=AA.z*evA; a0[3]=AA.w*evA;
      a1[0]=AB.x*evB; a1[1]=AB.y*evB; a1[2]=AB.z*evB; a1[3]=AB.w*evB;
    }
    for (int k=0;k<128;k+=4){
      float4 xa = *(const float4*)&L[OD1 + c*1056 + ea*132 + k];
      float4 xb = *(const float4*)&L[OD1 + c*1056 + (ea+1)*132 + k];
      #pragma unroll
      for (int kk=0;kk<4;kk++){
        float4 w = *(const float4*)&lw1[(size_t)(128+k+kk)*64 + o];
        float x0 = (kk==0)?xa.x:(kk==1)?xa.y:(kk==2)?xa.z:xa.w;
        float x1 = (kk==0)?xb.x:(kk==1)?xb.y:(kk==2)?xb.z:xb.w;
        a0[0]+=x0*w.x; a0[1]+=x0*w.y; a0[2]+=x0*w.z; a0[3]+=x0*w.w;
        a1[0]+=x1*w.x; a1[1]+=x1*w.y; a1[2]+=x1*w.z; a1[3]+=x1*w.w;
      }
    }
    const float r16 = 0.0625f;
    #pragma unroll
    for (int e2=0;e2<2;e2++){
      int e = ea+e2;
      ushort4 u;
      u.x = f2bf(((e2==0)?a0[0]:a1[0])*r16);
      u.y = f2bf(((e2==0)?a0[1]:a1[1])*r16);
      u.z = f2bf(((e2==0)?a0[2]:a1[2])*r16);
      u.w = f2bf(((e2==0)?a0[3]:a1[3])*r16);
      *(ushort4*)&gm1[((size_t)(e0+e)*3 + c)*64 + o] = u;
    }
  }
}

// ---------------- Kernel D: per-dst softmax + aggregation (unchanged) ----------------
__global__ __launch_bounds__(320) void k_agg(
  const int* __restrict__ edge_dst,
  const float* __restrict__ galpha, const __hip_bfloat16* __restrict__ gval,
  const __hip_bfloat16* __restrict__ gm1,
  const float* __restrict__ pw0, const float* __restrict__ pb0,
  const float* __restrict__ pw1,
  float* __restrict__ out)
{
  __shared__ float sRed[256], sW[256], sAm[4], sInv[4], sNS[128], sNV[192];
  int t = threadIdx.x;
  int n = blockIdx.x;
  int lo, hi;
  {
    int a=0,b=N_EDGES;
    while(a<b){int m=(a+b)>>1; if (edge_dst[m] < n) a=m+1; else b=m;}
    lo=a; a=lo; b=N_EDGES;
    while(a<b){int m=(a+b)>>1; if (edge_dst[m] < n+1) a=m+1; else b=m;}
    hi=a;
  }
  if (t < 256){
    int g=t>>2, h=t&3;
    float m=-1e30f;
    for (int e=lo+g; e<hi; e+=64) m = fmaxf(m, galpha[(size_t)e*4+h]);
    sRed[t]=m;
  }
  __syncthreads();
  for (int s=32; s>=1; s>>=1){
    if (t < s*4) sRed[t] = fmaxf(sRed[t], sRed[t+s*4]);
    __syncthreads();
  }
  if (t<4) sAm[t] = (hi>lo) ? sRed[t] : 0.f;
  __syncthreads();
  if (t < 256){
    int g=t>>2, h=t&3; float ssum=0.f;
    for (int e=lo+g; e<hi; e+=64) ssum += __expf(galpha[(size_t)e*4+h]-sAm[h]);
    sRed[t]=ssum;
  }
  __syncthreads();
  for (int s=32; s>=1; s>>=1){
    if (t < s*4) sRed[t] += sRed[t+s*4];
    __syncthreads();
  }
  if (t<4) sInv[t] = 1.f / fmaxf(sRed[t], 1e-12f);
  __syncthreads();
  float acc = 0.f;
  int cq=0, oq=0, hq=0;
  if (t < 128){ hq = t>>5; }
  else { int q=t-128; cq=q>>6; oq=q&63; hq=oq>>4; }
  for (int base=lo; base<hi; base+=64){
    int nn = min(64, hi-base);
    if (t < 256){ int j=t>>2,h=t&3; if (j<nn) sW[t] = __expf(galpha[(size_t)(base+j)*4+h]-sAm[h])*sInv[h]; }
    __syncthreads();
    if (t < 128){
      for (int j=0;j<nn;j++) acc += sW[j*4+hq]*__bfloat162float(gval[(size_t)(base+j)*128+t]);
    } else {
      for (int j=0;j<nn;j++) acc += sW[j*4+hq]*__bfloat162float(gm1[(size_t)((size_t)(base+j)*3+cq)*64+oq]);
    }
    __syncthreads();
  }
  if (t < 128) sNS[t]=acc; else sNV[oq*3+cq]=acc;
  __syncthreads();
  if (t < 128){
    float a = 0.f;
    for (int k=0;k<128;k++) a += sNS[k]*pw0[k*128+t];
    out[(size_t)n*320+t] = a*0.08838834764831845f + pb0[t];
  } else {
    float a = 0.f;
    for (int i=0;i<64;i++) a += sNV[i*3+cq]*pw1[i*64+oq];
    out[(size_t)n*320+128+oq*3+cq] = a*0.125f;
  }
}

extern "C" void kernel_launch(void* const* d_in, const int* in_sizes, int n_in,
                              void* d_out, int out_size, void* d_ws, size_t ws_size,
                              hipStream_t stream)
{
  const float* node_input  = (const float*)d_in[0];
  const float* edge_attr   = (const float*)d_in[1];
  const float* edge_scalars= (const float*)d_in[2];
  const int*   edge_src    = (const int*)d_in[3];
  const int*   edge_dst    = (const int*)d_in[4];
  const float* w_src0=(const float*)d_in[5];  const float* b_src0=(const float*)d_in[6];
  const float* w_src1=(const float*)d_in[7];
  const float* w_dst0=(const float*)d_in[8];  const float* b_dst0=(const float*)d_in[9];
  const float* w_dst1=(const float*)d_in[10];
  const float* rw1=(const float*)d_in[11];    const float* rb1=(const float*)d_in[12];
  const float* rw2=(const float*)d_in[13];    const float* rb2=(const float*)d_in[14];
  const float* rw3=(const float*)d_in[15];    const float* rb3=(const float*)d_in[16];
  const float* lw0=(const float*)d_in[17];    const float* lb0=(const float*)d_in[18];
  const float* lw1=(const float*)d_in[19];
  const float* alpha_dot=(const float*)d_in[20];
  const float* pw0=(const float*)d_in[21];    const float* pb0=(const float*)d_in[22];
  const float* pw1=(const float*)d_in[23];
  float* out = (float*)d_out;

  float* ns_src = (float*)d_ws;
  float* ns_dst = ns_src + (size_t)N_NODES*128;
  float* nv_src = ns_dst + (size_t)N_NODES*128;
  float* nv_dst = nv_src + (size_t)N_NODES*192;
  float* galpha = nv_dst + (size_t)N_NODES*192;
  __hip_bfloat16* gval = (__hip_bfloat16*)(galpha + (size_t)N_EDGES*4);
  __hip_bfloat16* gm1  = gval + (size_t)N_EDGES*128;

  k_node<<<N_NODES/8, 256, 0, stream>>>(node_input, w_src0,b_src0,w_src1,
                                        w_dst0,b_dst0,w_dst1,
                                        ns_src,ns_dst,nv_src,nv_dst);
  k_edge2<<<N_EDGES/EB, 256, 0, stream>>>(edge_attr, edge_scalars, edge_src, edge_dst,
                                          ns_src,ns_dst,nv_src,nv_dst,
                                          rw1,rb1,rw2,rb2,rw3,rb3,
                                          lw0,lb0,lw1,alpha_dot,
                                          galpha,gval,gm1);
  k_agg<<<N_NODES, 320, 0, stream>>>(edge_dst, galpha, gval, gm1, pw0,pb0,pw1, out);
}

// Round 4
// 1669.705 us; speedup vs baseline: 4.1383x; 4.1383x over previous
//
#include <hip/hip_runtime.h>
#include <hip/hip_bf16.h>
#include <math.h>

#define N_NODES 10000
#define N_EDGES 160000
#define EB 8

__device__ __forceinline__ float sigmoidf_(float x){ return 1.f/(1.f+__expf(-x)); }
__device__ __forceinline__ unsigned short f2bf(float x){
  __hip_bfloat16 h = __float2bfloat16(x);
  return *reinterpret_cast<unsigned short*>(&h);
}

// ---------------- Kernel A: node transforms (unchanged) ----------------
__global__ __launch_bounds__(256) void k_node(
    const float* __restrict__ node_input,
    const float* __restrict__ w_src0, const float* __restrict__ b_src0,
    const float* __restrict__ w_src1,
    const float* __restrict__ w_dst0, const float* __restrict__ b_dst0,
    const float* __restrict__ w_dst1,
    float* __restrict__ ns_src, float* __restrict__ ns_dst,
    float* __restrict__ nv_src, float* __restrict__ nv_dst)
{
  __shared__ float sNI[8*321];
  int t = threadIdx.x;
  int n0 = blockIdx.x*8;
  for (int idx=t; idx<8*320; idx+=256){
    int nd = idx/320, r = idx - nd*320;
    sNI[nd*321+r] = node_input[(size_t)(n0+nd)*320 + r];
  }
  __syncthreads();
  {
    int o = t & 127, half = t >> 7;
    const float* w = half ? w_dst0 : w_src0;
    const float* b = half ? b_dst0 : b_src0;
    float* outp = half ? ns_dst : ns_src;
    float acc[8];
    #pragma unroll
    for (int nd=0;nd<8;nd++) acc[nd]=0.f;
    for (int k=0;k<128;k++){
      float wv = w[k*128+o];
      #pragma unroll
      for (int nd=0;nd<8;nd++) acc[nd] += sNI[nd*321+k]*wv;
    }
    const float rs = 0.08838834764831845f;
    float bo = b[o];
    #pragma unroll
    for (int nd=0;nd<8;nd++) outp[(size_t)(n0+nd)*128+o] = acc[nd]*rs + bo;
  }
  if (t < 192){
    int o = t & 63, c = t >> 6;
    for (int half=0; half<2; half++){
      const float* w = half ? w_dst1 : w_src1;
      float* outp = half ? nv_dst : nv_src;
      float acc[8];
      #pragma unroll
      for (int nd=0;nd<8;nd++) acc[nd]=0.f;
      for (int i=0;i<64;i++){
        float wv = w[i*64+o];
        #pragma unroll
        for (int nd=0;nd<8;nd++) acc[nd] += sNI[nd*321+128+i*3+c]*wv;
      }
      #pragma unroll
      for (int nd=0;nd<8;nd++) outp[(size_t)(n0+nd)*192 + o*3 + c] = acc[nd]*0.125f;
    }
  }
}

// ---------------- Kernel C: fused edge pipeline, register-tiled ----------------
#define OEA 0
#define OMV 32
#define OASV 1600
#define OBVS 2656
#define OWV1 3176
#define OES 3696
#define OH1 4240
#define OH2 4784
#define OMS 5328
#define OD0 6384
#define OD1 3696
#define OA 7952

// NOTE: single-arg launch_bounds — round 3's (256,4) set waves-per-eu>=4,
// capped VGPRs, and forced ~2KB/thread scratch spill (10.7GB WRITE_SIZE).
__global__ __launch_bounds__(256) void k_edge2(
  const float* __restrict__ edge_attr, const float* __restrict__ edge_scalars,
  const int* __restrict__ edge_src, const int* __restrict__ edge_dst,
  const float* __restrict__ ns_src, const float* __restrict__ ns_dst,
  const float* __restrict__ nv_src, const float* __restrict__ nv_dst,
  const float* __restrict__ rw1, const float* __restrict__ rb1,
  const float* __restrict__ rw2, const float* __restrict__ rb2,
  const float* __restrict__ rw3, const float* __restrict__ rb3,
  const float* __restrict__ lw0, const float* __restrict__ lb0,
  const float* __restrict__ lw1, const float* __restrict__ alpha_dot,
  float* __restrict__ galpha, __hip_bfloat16* __restrict__ gval,
  __hip_bfloat16* __restrict__ gm1)
{
  __shared__ __align__(16) float L[8464];
  const int t = threadIdx.x;
  const int e0 = blockIdx.x * EB;

  // ---- P0: stage MS (all threads, full 128/edge), MV (all), ES (t<128), EA (t<32) ----
  {
    int e = t>>5, l = t&31;
    int s = edge_src[e0+e], d = edge_dst[e0+e];
    {
      float4 a = *(const float4*)&ns_src[(size_t)s*128 + l*4];
      float4 b = *(const float4*)&ns_dst[(size_t)d*128 + l*4];
      float4 r; r.x=a.x+b.x; r.y=a.y+b.y; r.z=a.z+b.z; r.w=a.w+b.w;
      *(float4*)&L[OMS + e*132 + l*4] = r;
    }
    #pragma unroll
    for (int j=0;j<2;j++){
      int idx = l + 32*j;
      if (idx < 48){
        float4 a = *(const float4*)&nv_src[(size_t)s*192 + idx*4];
        float4 b = *(const float4*)&nv_dst[(size_t)d*192 + idx*4];
        float4 r; r.x=a.x+b.x; r.y=a.y+b.y; r.z=a.z+b.z; r.w=a.w+b.w;
        *(float4*)&L[OMV + e*196 + idx*4] = r;
      }
    }
  }
  if (t < 128){
    int e = t>>4, l = t&15;
    *(float4*)&L[OES + e*68 + l*4] = *(const float4*)&edge_scalars[(size_t)(e0+e)*64 + l*4];
  }
  if (t < 32){ int e=t>>2, c=t&3; L[OEA + e*4 + c] = edge_attr[(size_t)(e0+e)*4 + c]; }
  __syncthreads();

  // ---- P1: h1 = silu(es @ rw1 + rb1) ----
  {
    int e = t>>5, o = (t&31)*2;
    float a0 = rb1[o], a1 = rb1[o+1];
    #pragma unroll 4
    for (int k=0;k<64;k+=4){
      float4 x = *(const float4*)&L[OES + e*68 + k];
      #pragma unroll
      for (int kk=0;kk<4;kk++){
        float2 w = *(const float2*)&rw1[(k+kk)*64 + o];
        float xv = (kk==0)?x.x:(kk==1)?x.y:(kk==2)?x.z:x.w;
        a0 += xv*w.x; a1 += xv*w.y;
      }
    }
    L[OH1 + e*68 + o]   = a0*sigmoidf_(a0);
    L[OH1 + e*68 + o+1] = a1*sigmoidf_(a1);
  }
  __syncthreads();

  // ---- P2: h2 = silu(h1 @ rw2 + rb2) ----
  {
    int e = t>>5, o = (t&31)*2;
    float a0 = rb2[o], a1 = rb2[o+1];
    #pragma unroll 4
    for (int k=0;k<64;k+=4){
      float4 x = *(const float4*)&L[OH1 + e*68 + k];
      #pragma unroll
      for (int kk=0;kk<4;kk++){
        float2 w = *(const float2*)&rw2[(k+kk)*64 + o];
        float xv = (kk==0)?x.x:(kk==1)?x.y:(kk==2)?x.z:x.w;
        a0 += xv*w.x; a1 += xv*w.y;
      }
    }
    L[OH2 + e*68 + o]   = a0*sigmoidf_(a0);
    L[OH2 + e*68 + o+1] = a1*sigmoidf_(a1);
  }
  __syncthreads();

  // ---- P3: w = h2 @ rw3 + rb3, consumed on the fly ----
  {
    int og = t&63, eg = t>>6;
    int ea = eg*2, eb = ea+1;
    float esA = L[OEA + ea*4], esB = L[OEA + eb*4];
    {
      int o = og*4;
      float a0[4], a1[4];
      #pragma unroll
      for (int j=0;j<4;j++){ a0[j]=rb3[o+j]; a1[j]=a0[j]; }
      #pragma unroll 2
      for (int k=0;k<64;k+=4){
        float4 h0 = *(const float4*)&L[OH2 + ea*68 + k];
        float4 h1 = *(const float4*)&L[OH2 + eb*68 + k];
        #pragma unroll
        for (int kk=0;kk<4;kk++){
          float4 w = *(const float4*)&rw3[(size_t)(k+kk)*448 + o];
          float x0 = (kk==0)?h0.x:(kk==1)?h0.y:(kk==2)?h0.z:h0.w;
          float x1 = (kk==0)?h1.x:(kk==1)?h1.y:(kk==2)?h1.z:h1.w;
          a0[0]+=x0*w.x; a0[1]+=x0*w.y; a0[2]+=x0*w.z; a0[3]+=x0*w.w;
          a1[0]+=x1*w.x; a1[1]+=x1*w.y; a1[2]+=x1*w.z; a1[3]+=x1*w.w;
        }
      }
      if (og < 32){
        float4 msA = *(const float4*)&L[OMS + ea*132 + o];
        float4 msB = *(const float4*)&L[OMS + eb*132 + o];
        float4 rA; rA.x=a0[0]*msA.x*esA; rA.y=a0[1]*msA.y*esA; rA.z=a0[2]*msA.z*esA; rA.w=a0[3]*msA.w*esA;
        float4 rB; rB.x=a1[0]*msB.x*esB; rB.y=a1[1]*msB.y*esB; rB.z=a1[2]*msB.z*esB; rB.w=a1[3]*msB.w*esB;
        *(float4*)&L[OD0 + ea*196 + o] = rA;
        *(float4*)&L[OD0 + eb*196 + o] = rB;
      } else {
        int oo = o-128;
        float4 msA = *(const float4*)&L[OMS + ea*132 + oo];
        float4 msB = *(const float4*)&L[OMS + eb*132 + oo];
        float4 rA; rA.x=a0[0]*msA.x; rA.y=a0[1]*msA.y; rA.z=a0[2]*msA.z; rA.w=a0[3]*msA.w;
        float4 rB; rB.x=a1[0]*msB.x; rB.y=a1[1]*msB.y; rB.z=a1[2]*msB.z; rB.w=a1[3]*msB.w;
        *(float4*)&L[OASV + ea*132 + oo] = rA;
        *(float4*)&L[OASV + eb*132 + oo] = rB;
      }
    }
    {
      int o1 = 256 + og*3;
      float a0[3], a1[3];
      #pragma unroll
      for (int j=0;j<3;j++){ a0[j]=rb3[o1+j]; a1[j]=a0[j]; }
      #pragma unroll 2
      for (int k=0;k<64;k+=4){
        float4 h0 = *(const float4*)&L[OH2 + ea*68 + k];
        float4 h1 = *(const float4*)&L[OH2 + eb*68 + k];
        #pragma unroll
        for (int kk=0;kk<4;kk++){
          float x0 = (kk==0)?h0.x:(kk==1)?h0.y:(kk==2)?h0.z:h0.w;
          float x1 = (kk==0)?h1.x:(kk==1)?h1.y:(kk==2)?h1.z:h1.w;
          #pragma unroll
          for (int j=0;j<3;j++){
            float w = rw3[(size_t)(k+kk)*448 + o1 + j];
            a0[j]+=x0*w; a1[j]+=x1*w;
          }
        }
      }
      #pragma unroll
      for (int e2=0;e2<2;e2++){
        int e = eg*2+e2;
        float es = (e2==0)?esA:esB;
        #pragma unroll
        for (int j=0;j<3;j++){
          int col = o1+j;
          float a = (e2==0)?a0[j]:a1[j];
          if (col < 320){
            L[OBVS + e*65 + (col-256)] = a*es;
          } else if (col < 384){
            int oo = col-320;
            float dot = L[OMV+e*196+oo*3]  *L[OEA+e*4+1]
                      + L[OMV+e*196+oo*3+1]*L[OEA+e*4+2]
                      + L[OMV+e*196+oo*3+2]*L[OEA+e*4+3];
            L[OD0 + e*196 + 128 + oo] = a*dot*0.5773502691896258f;
          } else {
            L[OWV1 + e*65 + (col-384)] = a*0.7071067811865476f;
          }
        }
      }
    }
  }
  __syncthreads();

  // ---- P4: m0 = d0 @ lw0 /sqrt(192) + lb0 ; alpha logits + val_s out ----
  {
    int og = t&63, eg = t>>6;
    float palpha[2]; palpha[0]=0.f; palpha[1]=0.f;
    int isalpha = 0, h4 = 0;
    if (og < 40){
      int o = og*4, ea = eg*2;
      float a0[4], a1[4];
      #pragma unroll
      for (int j=0;j<4;j++){ a0[j]=0.f; a1[j]=0.f; }
      #pragma unroll 2
      for (int k=0;k<192;k+=4){
        float4 d0a = *(const float4*)&L[OD0 + ea*196 + k];
        float4 d0b = *(const float4*)&L[OD0 + (ea+1)*196 + k];
        #pragma unroll
        for (int kk=0;kk<4;kk++){
          float4 w = *(const float4*)&lw0[(size_t)(k+kk)*160 + o];
          float x0 = (kk==0)?d0a.x:(kk==1)?d0a.y:(kk==2)?d0a.z:d0a.w;
          float x1 = (kk==0)?d0b.x:(kk==1)?d0b.y:(kk==2)?d0b.z:d0b.w;
          a0[0]+=x0*w.x; a0[1]+=x0*w.y; a0[2]+=x0*w.z; a0[3]+=x0*w.w;
          a1[0]+=x1*w.x; a1[1]+=x1*w.y; a1[2]+=x1*w.z; a1[3]+=x1*w.w;
        }
      }
      const float rs = 0.07216878364870323f;
      int h = o/40, kk0 = o%40;
      if (kk0 < 8){
        h4 = h; isalpha = 1;
        #pragma unroll
        for (int e2=0;e2<2;e2++){
          float p = 0.f;
          #pragma unroll
          for (int j=0;j<4;j++){
            float m = ((e2==0)?a0[j]:a1[j])*rs + lb0[o+j];
            float act = 0.6f*m + 0.4f*m*(2.f*sigmoidf_(m)-1.f);
            p += act * alpha_dot[h*8 + kk0 + j];
          }
          palpha[e2] = p;
        }
      } else {
        #pragma unroll
        for (int e2=0;e2<2;e2++){
          int e = eg*2+e2;
          ushort4 u;
          u.x = f2bf(((e2==0)?a0[0]:a1[0])*rs + lb0[o]);
          u.y = f2bf(((e2==0)?a0[1]:a1[1])*rs + lb0[o+1]);
          u.z = f2bf(((e2==0)?a0[2]:a1[2])*rs + lb0[o+2]);
          u.w = f2bf(((e2==0)?a0[3]:a1[3])*rs + lb0[o+3]);
          *(ushort4*)&gval[(size_t)(e0+e)*128 + h*32 + (kk0-8)] = u;
        }
      }
    }
    if (isalpha){
      float q0 = __shfl_down(palpha[0], 1);
      float q1 = __shfl_down(palpha[1], 1);
      if ((og%10)==0){
        int e = eg*2;
        galpha[(size_t)(e0+e)*4 + h4]   = palpha[0]+q0;
        galpha[(size_t)(e0+e+1)*4 + h4] = palpha[1]+q1;
      }
    }
  }
  __syncthreads();

  // ---- P5-prep: build d1 (3 comps) + A = asv @ lw1[0:128] ----
  {
    for (int idx=t; idx<3072; idx+=256){
      int c = idx>>10, rem = idx&1023, e = rem>>7, i = rem&127;
      float v;
      if (i < 64){
        v = L[OBVS + e*65 + i] * L[OMV + e*196 + i*3 + c];
      } else {
        int ii = i-64;
        int ca = (c+1)%3, cb = (c+2)%3;
        v = L[OWV1 + e*65 + ii] *
            (L[OMV+e*196+ii*3+ca]*L[OEA+e*4+1+cb] - L[OMV+e*196+ii*3+cb]*L[OEA+e*4+1+ca]);
      }
      L[OD1 + c*1056 + e*132 + i] = v;
    }
    int e = t>>5, oo = (t&31)*2;
    float a0=0.f, a1=0.f;
    #pragma unroll 2
    for (int k=0;k<128;k+=4){
      float4 x = *(const float4*)&L[OASV + e*132 + k];
      #pragma unroll
      for (int kk=0;kk<4;kk++){
        float2 w = *(const float2*)&lw1[(size_t)(k+kk)*64 + oo];
        float xv = (kk==0)?x.x:(kk==1)?x.y:(kk==2)?x.z:x.w;
        a0 += xv*w.x; a1 += xv*w.y;
      }
    }
    L[OA + e*64 + oo]   = a0;
    L[OA + e*64 + oo+1] = a1;
  }
  __syncthreads();

  // ---- P5b: m1[c] = (A*ev_c  ++  d1c @ lw1[128:256]) /16 ----
  if (t < 192){
    int og = t&15, sub = t>>4;
    int c = sub>>2, eg = sub&3;
    int o = og*4, ea = eg*2;
    float a0[4], a1[4];
    {
      float evA = L[OEA + ea*4 + 1 + c], evB = L[OEA + (ea+1)*4 + 1 + c];
      float4 AA = *(const float4*)&L[OA + ea*64 + o];
      float4 AB = *(const float4*)&L[OA + (ea+1)*64 + o];
      a0[0]=AA.x*evA; a0[1]=AA.y*evA; a0[2]=AA.z*evA; a0[3]=AA.w*evA;
      a1[0]=AB.x*evB; a1[1]=AB.y*evB; a1[2]=AB.z*evB; a1[3]=AB.w*evB;
    }
    #pragma unroll 2
    for (int k=0;k<128;k+=4){
      float4 xa = *(const float4*)&L[OD1 + c*1056 + ea*132 + k];
      float4 xb = *(const float4*)&L[OD1 + c*1056 + (ea+1)*132 + k];
      #pragma unroll
      for (int kk=0;kk<4;kk++){
        float4 w = *(const float4*)&lw1[(size_t)(128+k+kk)*64 + o];
        float x0 = (kk==0)?xa.x:(kk==1)?xa.y:(kk==2)?xa.z:xa.w;
        float x1 = (kk==0)?xb.x:(kk==1)?xb.y:(kk==2)?xb.z:xb.w;
        a0[0]+=x0*w.x; a0[1]+=x0*w.y; a0[2]+=x0*w.z; a0[3]+=x0*w.w;
        a1[0]+=x1*w.x; a1[1]+=x1*w.y; a1[2]+=x1*w.z; a1[3]+=x1*w.w;
      }
    }
    const float r16 = 0.0625f;
    #pragma unroll
    for (int e2=0;e2<2;e2++){
      int e = ea+e2;
      ushort4 u;
      u.x = f2bf(((e2==0)?a0[0]:a1[0])*r16);
      u.y = f2bf(((e2==0)?a0[1]:a1[1])*r16);
      u.z = f2bf(((e2==0)?a0[2]:a1[2])*r16);
      u.w = f2bf(((e2==0)?a0[3]:a1[3])*r16);
      *(ushort4*)&gm1[((size_t)(e0+e)*3 + c)*64 + o] = u;
    }
  }
}

// ---------------- Kernel D: per-dst softmax + aggregation (unchanged) ----------------
__global__ __launch_bounds__(320) void k_agg(
  const int* __restrict__ edge_dst,
  const float* __restrict__ galpha, const __hip_bfloat16* __restrict__ gval,
  const __hip_bfloat16* __restrict__ gm1,
  const float* __restrict__ pw0, const float* __restrict__ pb0,
  const float* __restrict__ pw1,
  float* __restrict__ out)
{
  __shared__ float sRed[256], sW[256], sAm[4], sInv[4], sNS[128], sNV[192];
  int t = threadIdx.x;
  int n = blockIdx.x;
  int lo, hi;
  {
    int a=0,b=N_EDGES;
    while(a<b){int m=(a+b)>>1; if (edge_dst[m] < n) a=m+1; else b=m;}
    lo=a; a=lo; b=N_EDGES;
    while(a<b){int m=(a+b)>>1; if (edge_dst[m] < n+1) a=m+1; else b=m;}
    hi=a;
  }
  if (t < 256){
    int g=t>>2, h=t&3;
    float m=-1e30f;
    for (int e=lo+g; e<hi; e+=64) m = fmaxf(m, galpha[(size_t)e*4+h]);
    sRed[t]=m;
  }
  __syncthreads();
  for (int s=32; s>=1; s>>=1){
    if (t < s*4) sRed[t] = fmaxf(sRed[t], sRed[t+s*4]);
    __syncthreads();
  }
  if (t<4) sAm[t] = (hi>lo) ? sRed[t] : 0.f;
  __syncthreads();
  if (t < 256){
    int g=t>>2, h=t&3; float ssum=0.f;
    for (int e=lo+g; e<hi; e+=64) ssum += __expf(galpha[(size_t)e*4+h]-sAm[h]);
    sRed[t]=ssum;
  }
  __syncthreads();
  for (int s=32; s>=1; s>>=1){
    if (t < s*4) sRed[t] += sRed[t+s*4];
    __syncthreads();
  }
  if (t<4) sInv[t] = 1.f / fmaxf(sRed[t], 1e-12f);
  __syncthreads();
  float acc = 0.f;
  int cq=0, oq=0, hq=0;
  if (t < 128){ hq = t>>5; }
  else { int q=t-128; cq=q>>6; oq=q&63; hq=oq>>4; }
  for (int base=lo; base<hi; base+=64){
    int nn = min(64, hi-base);
    if (t < 256){ int j=t>>2,h=t&3; if (j<nn) sW[t] = __expf(galpha[(size_t)(base+j)*4+h]-sAm[h])*sInv[h]; }
    __syncthreads();
    if (t < 128){
      for (int j=0;j<nn;j++) acc += sW[j*4+hq]*__bfloat162float(gval[(size_t)(base+j)*128+t]);
    } else {
      for (int j=0;j<nn;j++) acc += sW[j*4+hq]*__bfloat162float(gm1[(size_t)((size_t)(base+j)*3+cq)*64+oq]);
    }
    __syncthreads();
  }
  if (t < 128) sNS[t]=acc; else sNV[oq*3+cq]=acc;
  __syncthreads();
  if (t < 128){
    float a = 0.f;
    for (int k=0;k<128;k++) a += sNS[k]*pw0[k*128+t];
    out[(size_t)n*320+t] = a*0.08838834764831845f + pb0[t];
  } else {
    float a = 0.f;
    for (int i=0;i<64;i++) a += sNV[i*3+cq]*pw1[i*64+oq];
    out[(size_t)n*320+128+oq*3+cq] = a*0.125f;
  }
}

extern "C" void kernel_launch(void* const* d_in, const int* in_sizes, int n_in,
                              void* d_out, int out_size, void* d_ws, size_t ws_size,
                              hipStream_t stream)
{
  const float* node_input  = (const float*)d_in[0];
  const float* edge_attr   = (const float*)d_in[1];
  const float* edge_scalars= (const float*)d_in[2];
  const int*   edge_src    = (const int*)d_in[3];
  const int*   edge_dst    = (const int*)d_in[4];
  const float* w_src0=(const float*)d_in[5];  const float* b_src0=(const float*)d_in[6];
  const float* w_src1=(const float*)d_in[7];
  const float* w_dst0=(const float*)d_in[8];  const float* b_dst0=(const float*)d_in[9];
  const float* w_dst1=(const float*)d_in[10];
  const float* rw1=(const float*)d_in[11];    const float* rb1=(const float*)d_in[12];
  const float* rw2=(const float*)d_in[13];    const float* rb2=(const float*)d_in[14];
  const float* rw3=(const float*)d_in[15];    const float* rb3=(const float*)d_in[16];
  const float* lw0=(const float*)d_in[17];    const float* lb0=(const float*)d_in[18];
  const float* lw1=(const float*)d_in[19];
  const float* alpha_dot=(const float*)d_in[20];
  const float* pw0=(const float*)d_in[21];    const float* pb0=(const float*)d_in[22];
  const float* pw1=(const float*)d_in[23];
  float* out = (float*)d_out;

  float* ns_src = (float*)d_ws;
  float* ns_dst = ns_src + (size_t)N_NODES*128;
  float* nv_src = ns_dst + (size_t)N_NODES*128;
  float* nv_dst = nv_src + (size_t)N_NODES*192;
  float* galpha = nv_dst + (size_t)N_NODES*192;
  __hip_bfloat16* gval = (__hip_bfloat16*)(galpha + (size_t)N_EDGES*4);
  __hip_bfloat16* gm1  = gval + (size_t)N_EDGES*128;

  k_node<<<N_NODES/8, 256, 0, stream>>>(node_input, w_src0,b_src0,w_src1,
                                        w_dst0,b_dst0,w_dst1,
                                        ns_src,ns_dst,nv_src,nv_dst);
  k_edge2<<<N_EDGES/EB, 256, 0, stream>>>(edge_attr, edge_scalars, edge_src, edge_dst,
                                          ns_src,ns_dst,nv_src,nv_dst,
                                          rw1,rb1,rw2,rb2,rw3,rb3,
                                          lw0,lb0,lw1,alpha_dot,
                                          galpha,gval,gm1);
  k_agg<<<N_NODES, 320, 0, stream>>>(edge_dst, galpha, gval, gm1, pw0,pb0,pw1, out);
}

// Round 5
// 1095.007 us; speedup vs baseline: 6.3103x; 1.5248x over previous
//
#include <hip/hip_runtime.h>
#include <hip/hip_bf16.h>
#include <math.h>

#define N_NODES 10000
#define N_EDGES 160000
#define EB 16

__device__ __forceinline__ float sigmoidf_(float x){ return 1.f/(1.f+__expf(-x)); }
__device__ __forceinline__ unsigned short f2bf(float x){
  __hip_bfloat16 h = __float2bfloat16(x);
  return *reinterpret_cast<unsigned short*>(&h);
}

// ---------------- Kernel A: node transforms (unchanged) ----------------
__global__ __launch_bounds__(256) void k_node(
    const float* __restrict__ node_input,
    const float* __restrict__ w_src0, const float* __restrict__ b_src0,
    const float* __restrict__ w_src1,
    const float* __restrict__ w_dst0, const float* __restrict__ b_dst0,
    const float* __restrict__ w_dst1,
    float* __restrict__ ns_src, float* __restrict__ ns_dst,
    float* __restrict__ nv_src, float* __restrict__ nv_dst)
{
  __shared__ float sNI[8*321];
  int t = threadIdx.x;
  int n0 = blockIdx.x*8;
  for (int idx=t; idx<8*320; idx+=256){
    int nd = idx/320, r = idx - nd*320;
    sNI[nd*321+r] = node_input[(size_t)(n0+nd)*320 + r];
  }
  __syncthreads();
  {
    int o = t & 127, half = t >> 7;
    const float* w = half ? w_dst0 : w_src0;
    const float* b = half ? b_dst0 : b_src0;
    float* outp = half ? ns_dst : ns_src;
    float acc[8];
    #pragma unroll
    for (int nd=0;nd<8;nd++) acc[nd]=0.f;
    for (int k=0;k<128;k++){
      float wv = w[k*128+o];
      #pragma unroll
      for (int nd=0;nd<8;nd++) acc[nd] += sNI[nd*321+k]*wv;
    }
    const float rs = 0.08838834764831845f;
    float bo = b[o];
    #pragma unroll
    for (int nd=0;nd<8;nd++) outp[(size_t)(n0+nd)*128+o] = acc[nd]*rs + bo;
  }
  if (t < 192){
    int o = t & 63, c = t >> 6;
    for (int half=0; half<2; half++){
      const float* w = half ? w_dst1 : w_src1;
      float* outp = half ? nv_dst : nv_src;
      float acc[8];
      #pragma unroll
      for (int nd=0;nd<8;nd++) acc[nd]=0.f;
      for (int i=0;i<64;i++){
        float wv = w[i*64+o];
        #pragma unroll
        for (int nd=0;nd<8;nd++) acc[nd] += sNI[nd*321+128+i*3+c]*wv;
      }
      #pragma unroll
      for (int nd=0;nd<8;nd++) outp[(size_t)(n0+nd)*192 + o*3 + c] = acc[nd]*0.125f;
    }
  }
}

// ---------------- Kernel C: EB=16, 4 edges/thread register tiling ----------------
// LDS float offsets (76160 B total):
#define OEA  0       // 16*4    = 64     (persistent)
#define OMV  64      // 16*196  = 3136   (persistent)
#define OASV 3200    // 16*132  = 2112   (persistent)
#define OBVS 5312    // 16*65   = 1040   (persistent)
#define OWV1 6352    // 16*65   = 1040   (persistent)
#define OES  7392    // 16*68   = 1088   (region X: P0-P1)
#define OD0  7392    // 16*196  = 3136   (region X: P3-P4)
#define OD1  7392    // 3*2112  = 6336   (region X: P5)
#define OH1  13728   // 16*68   = 1088   (P1-P2)
#define OH2  14816   // 16*68   = 1088   (P2-P3)
#define OMS  15904   // 16*132  = 2112   (P0-P3)
#define OA   18016   // 16*64   = 1024   (P5)

__global__ __launch_bounds__(256) void k_edge3(
  const float* __restrict__ edge_attr, const float* __restrict__ edge_scalars,
  const int* __restrict__ edge_src, const int* __restrict__ edge_dst,
  const float* __restrict__ ns_src, const float* __restrict__ ns_dst,
  const float* __restrict__ nv_src, const float* __restrict__ nv_dst,
  const float* __restrict__ rw1, const float* __restrict__ rb1,
  const float* __restrict__ rw2, const float* __restrict__ rb2,
  const float* __restrict__ rw3, const float* __restrict__ rb3,
  const float* __restrict__ lw0, const float* __restrict__ lb0,
  const float* __restrict__ lw1, const float* __restrict__ alpha_dot,
  float* __restrict__ galpha, __hip_bfloat16* __restrict__ gval,
  __hip_bfloat16* __restrict__ gm1)
{
  __shared__ __align__(16) float L[19040];
  const int t = threadIdx.x;
  const int e0 = blockIdx.x * EB;

  // ---- P0: staging ----
  {
    int e = t>>4, l = t&15;
    int s = edge_src[e0+e], d = edge_dst[e0+e];
    #pragma unroll
    for (int j=0;j<2;j++){
      int idx = l + 16*j;
      float4 a = *(const float4*)&ns_src[(size_t)s*128 + idx*4];
      float4 b = *(const float4*)&ns_dst[(size_t)d*128 + idx*4];
      float4 r; r.x=a.x+b.x; r.y=a.y+b.y; r.z=a.z+b.z; r.w=a.w+b.w;
      *(float4*)&L[OMS + e*132 + idx*4] = r;
    }
    #pragma unroll
    for (int j=0;j<3;j++){
      int idx = l + 16*j;
      float4 a = *(const float4*)&nv_src[(size_t)s*192 + idx*4];
      float4 b = *(const float4*)&nv_dst[(size_t)d*192 + idx*4];
      float4 r; r.x=a.x+b.x; r.y=a.y+b.y; r.z=a.z+b.z; r.w=a.w+b.w;
      *(float4*)&L[OMV + e*196 + idx*4] = r;
    }
    *(float4*)&L[OES + e*68 + l*4] = *(const float4*)&edge_scalars[(size_t)(e0+e)*64 + l*4];
  }
  if (t < 64) L[OEA + t] = edge_attr[(size_t)e0*4 + t];
  __syncthreads();

  // ---- P1: h1 = silu(es @ rw1 + rb1), 1 edge x 4 cols/thread ----
  {
    int e = t>>4, o = (t&15)*4;
    float4 b = *(const float4*)&rb1[o];
    float a0=b.x, a1=b.y, a2=b.z, a3=b.w;
    for (int k=0;k<64;k+=4){
      float4 x = *(const float4*)&L[OES + e*68 + k];
      #pragma unroll
      for (int kk=0;kk<4;kk++){
        float4 w = *(const float4*)&rw1[(k+kk)*64 + o];
        float xv = (kk==0)?x.x:(kk==1)?x.y:(kk==2)?x.z:x.w;
        a0 += xv*w.x; a1 += xv*w.y; a2 += xv*w.z; a3 += xv*w.w;
      }
    }
    float4 r; r.x=a0*sigmoidf_(a0); r.y=a1*sigmoidf_(a1); r.z=a2*sigmoidf_(a2); r.w=a3*sigmoidf_(a3);
    *(float4*)&L[OH1 + e*68 + o] = r;
  }
  __syncthreads();

  // ---- P2: h2 = silu(h1 @ rw2 + rb2) ----
  {
    int e = t>>4, o = (t&15)*4;
    float4 b = *(const float4*)&rb2[o];
    float a0=b.x, a1=b.y, a2=b.z, a3=b.w;
    for (int k=0;k<64;k+=4){
      float4 x = *(const float4*)&L[OH1 + e*68 + k];
      #pragma unroll
      for (int kk=0;kk<4;kk++){
        float4 w = *(const float4*)&rw2[(k+kk)*64 + o];
        float xv = (kk==0)?x.x:(kk==1)?x.y:(kk==2)?x.z:x.w;
        a0 += xv*w.x; a1 += xv*w.y; a2 += xv*w.z; a3 += xv*w.w;
      }
    }
    float4 r; r.x=a0*sigmoidf_(a0); r.y=a1*sigmoidf_(a1); r.z=a2*sigmoidf_(a2); r.w=a3*sigmoidf_(a3);
    *(float4*)&L[OH2 + e*68 + o] = r;
  }
  __syncthreads();

  // ---- P3: w = h2 @ rw3 + rb3, 4 edges x 4 cols (j0) + 4 edges x 3 cols (j1) ----
  {
    int og = t&63, eg = t>>6;
    int eb4 = eg*4;
    // j0: cols o..o+3, o in [0,256)
    {
      int o = og*4;
      float4 b3 = *(const float4*)&rb3[o];
      float acc[4][4];
      #pragma unroll
      for (int e2=0;e2<4;e2++){ acc[e2][0]=b3.x; acc[e2][1]=b3.y; acc[e2][2]=b3.z; acc[e2][3]=b3.w; }
      #pragma unroll 2
      for (int k=0;k<64;k+=4){
        float4 h[4];
        #pragma unroll
        for (int e2=0;e2<4;e2++) h[e2] = *(const float4*)&L[OH2 + (eb4+e2)*68 + k];
        #pragma unroll
        for (int kk=0;kk<4;kk++){
          float4 w = *(const float4*)&rw3[(size_t)(k+kk)*448 + o];
          #pragma unroll
          for (int e2=0;e2<4;e2++){
            float xv = (kk==0)?h[e2].x:(kk==1)?h[e2].y:(kk==2)?h[e2].z:h[e2].w;
            acc[e2][0]+=xv*w.x; acc[e2][1]+=xv*w.y; acc[e2][2]+=xv*w.z; acc[e2][3]+=xv*w.w;
          }
        }
      }
      if (og < 32){
        #pragma unroll
        for (int e2=0;e2<4;e2++){
          int e = eb4+e2;
          float es = L[OEA + e*4];
          float4 ms = *(const float4*)&L[OMS + e*132 + o];
          float4 r; r.x=acc[e2][0]*ms.x*es; r.y=acc[e2][1]*ms.y*es; r.z=acc[e2][2]*ms.z*es; r.w=acc[e2][3]*ms.w*es;
          *(float4*)&L[OD0 + e*196 + o] = r;
        }
      } else {
        int oo = o-128;
        #pragma unroll
        for (int e2=0;e2<4;e2++){
          int e = eb4+e2;
          float4 ms = *(const float4*)&L[OMS + e*132 + oo];
          float4 r; r.x=acc[e2][0]*ms.x; r.y=acc[e2][1]*ms.y; r.z=acc[e2][2]*ms.z; r.w=acc[e2][3]*ms.w;
          *(float4*)&L[OASV + e*132 + oo] = r;
        }
      }
    }
    // j1: cols o1..o1+2, o1 in [256,448)
    {
      int o1 = 256 + og*3;
      float acc[4][3];
      #pragma unroll
      for (int j=0;j<3;j++){ float b=rb3[o1+j]; acc[0][j]=b; acc[1][j]=b; acc[2][j]=b; acc[3][j]=b; }
      #pragma unroll 2
      for (int k=0;k<64;k+=4){
        float4 h[4];
        #pragma unroll
        for (int e2=0;e2<4;e2++) h[e2] = *(const float4*)&L[OH2 + (eb4+e2)*68 + k];
        #pragma unroll
        for (int kk=0;kk<4;kk++){
          #pragma unroll
          for (int j=0;j<3;j++){
            float w = rw3[(size_t)(k+kk)*448 + o1 + j];
            #pragma unroll
            for (int e2=0;e2<4;e2++){
              float xv = (kk==0)?h[e2].x:(kk==1)?h[e2].y:(kk==2)?h[e2].z:h[e2].w;
              acc[e2][j] += xv*w;
            }
          }
        }
      }
      #pragma unroll
      for (int e2=0;e2<4;e2++){
        int e = eb4+e2;
        float es = L[OEA + e*4];
        #pragma unroll
        for (int j=0;j<3;j++){
          int col = o1+j;
          float a = acc[e2][j];
          if (col < 320){
            L[OBVS + e*65 + (col-256)] = a*es;
          } else if (col < 384){
            int oo = col-320;
            float dot = L[OMV+e*196+oo*3]  *L[OEA+e*4+1]
                      + L[OMV+e*196+oo*3+1]*L[OEA+e*4+2]
                      + L[OMV+e*196+oo*3+2]*L[OEA+e*4+3];
            L[OD0 + e*196 + 128 + oo] = a*dot*0.5773502691896258f;
          } else {
            L[OWV1 + e*65 + (col-384)] = a*0.7071067811865476f;
          }
        }
      }
    }
  }
  __syncthreads();

  // ---- P4: m0 = d0 @ lw0 /sqrt(192) + lb0 ; alpha logits + val_s ----
  {
    int og = t&63, eg = t>>6;
    int eb4 = eg*4;
    if (og < 40){
      int o = og*4;
      float acc[4][4];
      #pragma unroll
      for (int e2=0;e2<4;e2++){ acc[e2][0]=0.f; acc[e2][1]=0.f; acc[e2][2]=0.f; acc[e2][3]=0.f; }
      #pragma unroll 2
      for (int k=0;k<192;k+=4){
        float4 d[4];
        #pragma unroll
        for (int e2=0;e2<4;e2++) d[e2] = *(const float4*)&L[OD0 + (eb4+e2)*196 + k];
        #pragma unroll
        for (int kk=0;kk<4;kk++){
          float4 w = *(const float4*)&lw0[(size_t)(k+kk)*160 + o];
          #pragma unroll
          for (int e2=0;e2<4;e2++){
            float xv = (kk==0)?d[e2].x:(kk==1)?d[e2].y:(kk==2)?d[e2].z:d[e2].w;
            acc[e2][0]+=xv*w.x; acc[e2][1]+=xv*w.y; acc[e2][2]+=xv*w.z; acc[e2][3]+=xv*w.w;
          }
        }
      }
      const float rs = 0.07216878364870323f;
      int h = og/10, kk0 = (og*4)%40;
      if (kk0 < 8){
        float4 lb = *(const float4*)&lb0[o];
        float palpha[4];
        #pragma unroll
        for (int e2=0;e2<4;e2++){
          float p = 0.f;
          #pragma unroll
          for (int j=0;j<4;j++){
            float m = acc[e2][j]*rs + ((j==0)?lb.x:(j==1)?lb.y:(j==2)?lb.z:lb.w);
            float act = 0.6f*m + 0.4f*m*(2.f*sigmoidf_(m)-1.f);
            p += act * alpha_dot[h*8 + kk0 + j];
          }
          palpha[e2] = p;
        }
        #pragma unroll
        for (int e2=0;e2<4;e2++){
          float q = __shfl_down(palpha[e2], 1);
          palpha[e2] += q;
        }
        if (kk0 == 0){
          #pragma unroll
          for (int e2=0;e2<4;e2++)
            galpha[(size_t)(e0+eb4+e2)*4 + h] = palpha[e2];
        }
      } else {
        float4 lb = *(const float4*)&lb0[o];
        #pragma unroll
        for (int e2=0;e2<4;e2++){
          int e = eb4+e2;
          ushort4 u;
          u.x = f2bf(acc[e2][0]*rs + lb.x);
          u.y = f2bf(acc[e2][1]*rs + lb.y);
          u.z = f2bf(acc[e2][2]*rs + lb.z);
          u.w = f2bf(acc[e2][3]*rs + lb.w);
          *(ushort4*)&gval[(size_t)(e0+e)*128 + h*32 + (kk0-8)] = u;
        }
      }
    }
  }
  __syncthreads();

  // ---- P5-prep: build d1 (3 comps) + A = asv @ lw1[0:128] ----
  {
    for (int idx=t; idx<6144; idx+=256){
      int c = idx>>11, rem = idx&2047, e = rem>>7, i = rem&127;
      float v;
      if (i < 64){
        v = L[OBVS + e*65 + i] * L[OMV + e*196 + i*3 + c];
      } else {
        int ii = i-64;
        int ca = (c+1)%3, cb = (c+2)%3;
        v = L[OWV1 + e*65 + ii] *
            (L[OMV+e*196+ii*3+ca]*L[OEA+e*4+1+cb] - L[OMV+e*196+ii*3+cb]*L[OEA+e*4+1+ca]);
      }
      L[OD1 + c*2112 + e*132 + i] = v;
    }
    int e = t>>4, oo = (t&15)*4;
    float a0=0.f, a1=0.f, a2=0.f, a3=0.f;
    #pragma unroll 2
    for (int k=0;k<128;k+=4){
      float4 x = *(const float4*)&L[OASV + e*132 + k];
      #pragma unroll
      for (int kk=0;kk<4;kk++){
        float4 w = *(const float4*)&lw1[(size_t)(k+kk)*64 + oo];
        float xv = (kk==0)?x.x:(kk==1)?x.y:(kk==2)?x.z:x.w;
        a0 += xv*w.x; a1 += xv*w.y; a2 += xv*w.z; a3 += xv*w.w;
      }
    }
    float4 r; r.x=a0; r.y=a1; r.z=a2; r.w=a3;
    *(float4*)&L[OA + e*64 + oo] = r;
  }
  __syncthreads();

  // ---- P5b: m1[c] = (A*ev_c + d1c @ lw1[128:256]) /16, 3 comps fused ----
  {
    int e = t>>4, o = (t&15)*4;
    float ev0 = L[OEA + e*4 + 1], ev1 = L[OEA + e*4 + 2], ev2 = L[OEA + e*4 + 3];
    float4 Av = *(const float4*)&L[OA + e*64 + o];
    float acc[3][4];
    acc[0][0]=Av.x*ev0; acc[0][1]=Av.y*ev0; acc[0][2]=Av.z*ev0; acc[0][3]=Av.w*ev0;
    acc[1][0]=Av.x*ev1; acc[1][1]=Av.y*ev1; acc[1][2]=Av.z*ev1; acc[1][3]=Av.w*ev1;
    acc[2][0]=Av.x*ev2; acc[2][1]=Av.y*ev2; acc[2][2]=Av.z*ev2; acc[2][3]=Av.w*ev2;
    #pragma unroll 2
    for (int k=0;k<128;k+=4){
      float4 x0 = *(const float4*)&L[OD1 + 0*2112 + e*132 + k];
      float4 x1 = *(const float4*)&L[OD1 + 1*2112 + e*132 + k];
      float4 x2 = *(const float4*)&L[OD1 + 2*2112 + e*132 + k];
      #pragma unroll
      for (int kk=0;kk<4;kk++){
        float4 w = *(const float4*)&lw1[(size_t)(128+k+kk)*64 + o];
        float v0 = (kk==0)?x0.x:(kk==1)?x0.y:(kk==2)?x0.z:x0.w;
        float v1 = (kk==0)?x1.x:(kk==1)?x1.y:(kk==2)?x1.z:x1.w;
        float v2 = (kk==0)?x2.x:(kk==1)?x2.y:(kk==2)?x2.z:x2.w;
        acc[0][0]+=v0*w.x; acc[0][1]+=v0*w.y; acc[0][2]+=v0*w.z; acc[0][3]+=v0*w.w;
        acc[1][0]+=v1*w.x; acc[1][1]+=v1*w.y; acc[1][2]+=v1*w.z; acc[1][3]+=v1*w.w;
        acc[2][0]+=v2*w.x; acc[2][1]+=v2*w.y; acc[2][2]+=v2*w.z; acc[2][3]+=v2*w.w;
      }
    }
    const float r16 = 0.0625f;
    #pragma unroll
    for (int c=0;c<3;c++){
      ushort4 u;
      u.x = f2bf(acc[c][0]*r16);
      u.y = f2bf(acc[c][1]*r16);
      u.z = f2bf(acc[c][2]*r16);
      u.w = f2bf(acc[c][3]*r16);
      *(ushort4*)&gm1[((size_t)(e0+e)*3 + c)*64 + o] = u;
    }
  }
}

// ---------------- Kernel D: per-dst softmax + aggregation (unchanged) ----------------
__global__ __launch_bounds__(320) void k_agg(
  const int* __restrict__ edge_dst,
  const float* __restrict__ galpha, const __hip_bfloat16* __restrict__ gval,
  const __hip_bfloat16* __restrict__ gm1,
  const float* __restrict__ pw0, const float* __restrict__ pb0,
  const float* __restrict__ pw1,
  float* __restrict__ out)
{
  __shared__ float sRed[256], sW[256], sAm[4], sInv[4], sNS[128], sNV[192];
  int t = threadIdx.x;
  int n = blockIdx.x;
  int lo, hi;
  {
    int a=0,b=N_EDGES;
    while(a<b){int m=(a+b)>>1; if (edge_dst[m] < n) a=m+1; else b=m;}
    lo=a; a=lo; b=N_EDGES;
    while(a<b){int m=(a+b)>>1; if (edge_dst[m] < n+1) a=m+1; else b=m;}
    hi=a;
  }
  if (t < 256){
    int g=t>>2, h=t&3;
    float m=-1e30f;
    for (int e=lo+g; e<hi; e+=64) m = fmaxf(m, galpha[(size_t)e*4+h]);
    sRed[t]=m;
  }
  __syncthreads();
  for (int s=32; s>=1; s>>=1){
    if (t < s*4) sRed[t] = fmaxf(sRed[t], sRed[t+s*4]);
    __syncthreads();
  }
  if (t<4) sAm[t] = (hi>lo) ? sRed[t] : 0.f;
  __syncthreads();
  if (t < 256){
    int g=t>>2, h=t&3; float ssum=0.f;
    for (int e=lo+g; e<hi; e+=64) ssum += __expf(galpha[(size_t)e*4+h]-sAm[h]);
    sRed[t]=ssum;
  }
  __syncthreads();
  for (int s=32; s>=1; s>>=1){
    if (t < s*4) sRed[t] += sRed[t+s*4];
    __syncthreads();
  }
  if (t<4) sInv[t] = 1.f / fmaxf(sRed[t], 1e-12f);
  __syncthreads();
  float acc = 0.f;
  int cq=0, oq=0, hq=0;
  if (t < 128){ hq = t>>5; }
  else { int q=t-128; cq=q>>6; oq=q&63; hq=oq>>4; }
  for (int base=lo; base<hi; base+=64){
    int nn = min(64, hi-base);
    if (t < 256){ int j=t>>2,h=t&3; if (j<nn) sW[t] = __expf(galpha[(size_t)(base+j)*4+h]-sAm[h])*sInv[h]; }
    __syncthreads();
    if (t < 128){
      for (int j=0;j<nn;j++) acc += sW[j*4+hq]*__bfloat162float(gval[(size_t)(base+j)*128+t]);
    } else {
      for (int j=0;j<nn;j++) acc += sW[j*4+hq]*__bfloat162float(gm1[(size_t)((size_t)(base+j)*3+cq)*64+oq]);
    }
    __syncthreads();
  }
  if (t < 128) sNS[t]=acc; else sNV[oq*3+cq]=acc;
  __syncthreads();
  if (t < 128){
    float a = 0.f;
    for (int k=0;k<128;k++) a += sNS[k]*pw0[k*128+t];
    out[(size_t)n*320+t] = a*0.08838834764831845f + pb0[t];
  } else {
    float a = 0.f;
    for (int i=0;i<64;i++) a += sNV[i*3+cq]*pw1[i*64+oq];
    out[(size_t)n*320+128+oq*3+cq] = a*0.125f;
  }
}

extern "C" void kernel_launch(void* const* d_in, const int* in_sizes, int n_in,
                              void* d_out, int out_size, void* d_ws, size_t ws_size,
                              hipStream_t stream)
{
  const float* node_input  = (const float*)d_in[0];
  const float* edge_attr   = (const float*)d_in[1];
  const float* edge_scalars= (const float*)d_in[2];
  const int*   edge_src    = (const int*)d_in[3];
  const int*   edge_dst    = (const int*)d_in[4];
  const float* w_src0=(const float*)d_in[5];  const float* b_src0=(const float*)d_in[6];
  const float* w_src1=(const float*)d_in[7];
  const float* w_dst0=(const float*)d_in[8];  const float* b_dst0=(const float*)d_in[9];
  const float* w_dst1=(const float*)d_in[10];
  const float* rw1=(const float*)d_in[11];    const float* rb1=(const float*)d_in[12];
  const float* rw2=(const float*)d_in[13];    const float* rb2=(const float*)d_in[14];
  const float* rw3=(const float*)d_in[15];    const float* rb3=(const float*)d_in[16];
  const float* lw0=(const float*)d_in[17];    const float* lb0=(const float*)d_in[18];
  const float* lw1=(const float*)d_in[19];
  const float* alpha_dot=(const float*)d_in[20];
  const float* pw0=(const float*)d_in[21];    const float* pb0=(const float*)d_in[22];
  const float* pw1=(const float*)d_in[23];
  float* out = (float*)d_out;

  float* ns_src = (float*)d_ws;
  float* ns_dst = ns_src + (size_t)N_NODES*128;
  float* nv_src = ns_dst + (size_t)N_NODES*128;
  float* nv_dst = nv_src + (size_t)N_NODES*192;
  float* galpha = nv_dst + (size_t)N_NODES*192;
  __hip_bfloat16* gval = (__hip_bfloat16*)(galpha + (size_t)N_EDGES*4);
  __hip_bfloat16* gm1  = gval + (size_t)N_EDGES*128;

  k_node<<<N_NODES/8, 256, 0, stream>>>(node_input, w_src0,b_src0,w_src1,
                                        w_dst0,b_dst0,w_dst1,
                                        ns_src,ns_dst,nv_src,nv_dst);
  k_edge3<<<N_EDGES/EB, 256, 0, stream>>>(edge_attr, edge_scalars, edge_src, edge_dst,
                                          ns_src,ns_dst,nv_src,nv_dst,
                                          rw1,rb1,rw2,rb2,rw3,rb3,
                                          lw0,lb0,lw1,alpha_dot,
                                          galpha,gval,gm1);
  k_agg<<<N_NODES, 320, 0, stream>>>(edge_dst, galpha, gval, gm1, pw0,pb0,pw1, out);
}

// Round 6
// 729.479 us; speedup vs baseline: 9.4723x; 1.5011x over previous
//
#include <hip/hip_runtime.h>
#include <hip/hip_bf16.h>
#include <math.h>

#define N_NODES 10000
#define N_EDGES 160000
#define EB 16

typedef unsigned short ushort_t;
using f32x4 = __attribute__((ext_vector_type(4))) float;
using s16x8 = __attribute__((ext_vector_type(8))) short;

__device__ __forceinline__ float sigmoidf_(float x){ return 1.f/(1.f+__expf(-x)); }
__device__ __forceinline__ unsigned short f2bf(float x){
  __hip_bfloat16 h = __float2bfloat16(x);
  return *reinterpret_cast<unsigned short*>(&h);
}

// ---------------- Kernel P: pack lw0 (col-permuted) + lw1 into bf16 MFMA-frag order ----
// lw0p: [10 nt][6 kt][64 lane][8]  (perm: cols 0..31 = alpha cols, 32..159 = gval order)
// lw1p: [4 nt][8 kt][64 lane][8]
__global__ __launch_bounds__(256) void k_pack(
  const float* __restrict__ lw0, const float* __restrict__ lw1,
  ushort_t* __restrict__ lw0p, ushort_t* __restrict__ lw1p)
{
  int idx = blockIdx.x*256 + threadIdx.x;
  if (idx < 30720){
    int nt = idx/3072, r = idx - nt*3072;
    int kt = r>>9, lane = (r>>3)&63, i = r&7;
    int k = kt*32 + (lane>>4)*8 + i;
    int cp = nt*16 + (lane&15);
    int col;
    if (cp < 32){ col = (cp>>3)*40 + (cp&7); }
    else { int q = cp-32; col = (q>>5)*40 + 8 + (q&31); }
    lw0p[idx] = f2bf(lw0[(size_t)k*160 + col]);
  } else if (idx < 47104){
    int j = idx - 30720;
    int nt = j/4096, r = j - nt*4096;
    int kt = r>>9, lane = (r>>3)&63, i = r&7;
    int k = kt*32 + (lane>>4)*8 + i;
    int col = nt*16 + (lane&15);
    lw1p[j] = f2bf(lw1[(size_t)k*64 + col]);
  }
}

// ---------------- Kernel A: node transforms (unchanged) ----------------
__global__ __launch_bounds__(256) void k_node(
    const float* __restrict__ node_input,
    const float* __restrict__ w_src0, const float* __restrict__ b_src0,
    const float* __restrict__ w_src1,
    const float* __restrict__ w_dst0, const float* __restrict__ b_dst0,
    const float* __restrict__ w_dst1,
    float* __restrict__ ns_src, float* __restrict__ ns_dst,
    float* __restrict__ nv_src, float* __restrict__ nv_dst)
{
  __shared__ float sNI[8*321];
  int t = threadIdx.x;
  int n0 = blockIdx.x*8;
  for (int idx=t; idx<8*320; idx+=256){
    int nd = idx/320, r = idx - nd*320;
    sNI[nd*321+r] = node_input[(size_t)(n0+nd)*320 + r];
  }
  __syncthreads();
  {
    int o = t & 127, half = t >> 7;
    const float* w = half ? w_dst0 : w_src0;
    const float* b = half ? b_dst0 : b_src0;
    float* outp = half ? ns_dst : ns_src;
    float acc[8];
    #pragma unroll
    for (int nd=0;nd<8;nd++) acc[nd]=0.f;
    for (int k=0;k<128;k++){
      float wv = w[k*128+o];
      #pragma unroll
      for (int nd=0;nd<8;nd++) acc[nd] += sNI[nd*321+k]*wv;
    }
    const float rs = 0.08838834764831845f;
    float bo = b[o];
    #pragma unroll
    for (int nd=0;nd<8;nd++) outp[(size_t)(n0+nd)*128+o] = acc[nd]*rs + bo;
  }
  if (t < 192){
    int o = t & 63, c = t >> 6;
    for (int half=0; half<2; half++){
      const float* w = half ? w_dst1 : w_src1;
      float* outp = half ? nv_dst : nv_src;
      float acc[8];
      #pragma unroll
      for (int nd=0;nd<8;nd++) acc[nd]=0.f;
      for (int i=0;i<64;i++){
        float wv = w[i*64+o];
        #pragma unroll
        for (int nd=0;nd<8;nd++) acc[nd] += sNI[nd*321+128+i*3+c]*wv;
      }
      #pragma unroll
      for (int nd=0;nd<8;nd++) outp[(size_t)(n0+nd)*192 + o*3 + c] = acc[nd]*0.125f;
    }
  }
}

// ---------------- Kernel C: EB=16; f32 alpha chain + MFMA val/m1 ----------------
#define OEA  0       // 16*4
#define OMV  64      // 16*196
#define OASV 3200    // 16*132
#define OBVS 5312    // 16*65
#define OWV1 6352    // 16*65
#define OES  7392    // 16*68  (P0-P1)
#define OD0  7392    // 16*196 (P3-P4)
#define OD1  7392    // 3*2112 (P5)
#define OH1  13728   // 16*68  (P1-P2)
#define OH2  14816   // 16*68  (P2-P3)
#define OMS  15904   // 16*132 (P0-P3)

__global__ __launch_bounds__(256) void k_edge3(
  const float* __restrict__ edge_attr, const float* __restrict__ edge_scalars,
  const int* __restrict__ edge_src, const int* __restrict__ edge_dst,
  const float* __restrict__ ns_src, const float* __restrict__ ns_dst,
  const float* __restrict__ nv_src, const float* __restrict__ nv_dst,
  const float* __restrict__ rw1, const float* __restrict__ rb1,
  const float* __restrict__ rw2, const float* __restrict__ rb2,
  const float* __restrict__ rw3, const float* __restrict__ rb3,
  const float* __restrict__ lw0, const float* __restrict__ lb0,
  const ushort_t* __restrict__ lw0p, const ushort_t* __restrict__ lw1p,
  const float* __restrict__ alpha_dot,
  float* __restrict__ galpha, __hip_bfloat16* __restrict__ gval,
  __hip_bfloat16* __restrict__ gm1)
{
  __shared__ __align__(16) float L[18016];
  const int t = threadIdx.x;
  const int e0 = blockIdx.x * EB;

  // ---- P0: staging ----
  {
    int e = t>>4, l = t&15;
    int s = edge_src[e0+e], d = edge_dst[e0+e];
    #pragma unroll
    for (int j=0;j<2;j++){
      int idx = l + 16*j;
      float4 a = *(const float4*)&ns_src[(size_t)s*128 + idx*4];
      float4 b = *(const float4*)&ns_dst[(size_t)d*128 + idx*4];
      float4 r; r.x=a.x+b.x; r.y=a.y+b.y; r.z=a.z+b.z; r.w=a.w+b.w;
      *(float4*)&L[OMS + e*132 + idx*4] = r;
    }
    #pragma unroll
    for (int j=0;j<3;j++){
      int idx = l + 16*j;
      float4 a = *(const float4*)&nv_src[(size_t)s*192 + idx*4];
      float4 b = *(const float4*)&nv_dst[(size_t)d*192 + idx*4];
      float4 r; r.x=a.x+b.x; r.y=a.y+b.y; r.z=a.z+b.z; r.w=a.w+b.w;
      *(float4*)&L[OMV + e*196 + idx*4] = r;
    }
    *(float4*)&L[OES + e*68 + l*4] = *(const float4*)&edge_scalars[(size_t)(e0+e)*64 + l*4];
  }
  if (t < 64) L[OEA + t] = edge_attr[(size_t)e0*4 + t];
  __syncthreads();

  // ---- P1: h1 = silu(es @ rw1 + rb1) ----
  {
    int e = t>>4, o = (t&15)*4;
    float4 b = *(const float4*)&rb1[o];
    float a0=b.x, a1=b.y, a2=b.z, a3=b.w;
    for (int k=0;k<64;k+=4){
      float4 x = *(const float4*)&L[OES + e*68 + k];
      #pragma unroll
      for (int kk=0;kk<4;kk++){
        float4 w = *(const float4*)&rw1[(k+kk)*64 + o];
        float xv = (kk==0)?x.x:(kk==1)?x.y:(kk==2)?x.z:x.w;
        a0 += xv*w.x; a1 += xv*w.y; a2 += xv*w.z; a3 += xv*w.w;
      }
    }
    float4 r; r.x=a0*sigmoidf_(a0); r.y=a1*sigmoidf_(a1); r.z=a2*sigmoidf_(a2); r.w=a3*sigmoidf_(a3);
    *(float4*)&L[OH1 + e*68 + o] = r;
  }
  __syncthreads();

  // ---- P2: h2 = silu(h1 @ rw2 + rb2) ----
  {
    int e = t>>4, o = (t&15)*4;
    float4 b = *(const float4*)&rb2[o];
    float a0=b.x, a1=b.y, a2=b.z, a3=b.w;
    for (int k=0;k<64;k+=4){
      float4 x = *(const float4*)&L[OH1 + e*68 + k];
      #pragma unroll
      for (int kk=0;kk<4;kk++){
        float4 w = *(const float4*)&rw2[(k+kk)*64 + o];
        float xv = (kk==0)?x.x:(kk==1)?x.y:(kk==2)?x.z:x.w;
        a0 += xv*w.x; a1 += xv*w.y; a2 += xv*w.z; a3 += xv*w.w;
      }
    }
    float4 r; r.x=a0*sigmoidf_(a0); r.y=a1*sigmoidf_(a1); r.z=a2*sigmoidf_(a2); r.w=a3*sigmoidf_(a3);
    *(float4*)&L[OH2 + e*68 + o] = r;
  }
  __syncthreads();

  // ---- P3: w = h2 @ rw3 + rb3 (f32, alpha-critical), consumed on the fly ----
  {
    int og = t&63, eg = t>>6;
    int eb4 = eg*4;
    {
      int o = og*4;
      float4 b3 = *(const float4*)&rb3[o];
      float acc[4][4];
      #pragma unroll
      for (int e2=0;e2<4;e2++){ acc[e2][0]=b3.x; acc[e2][1]=b3.y; acc[e2][2]=b3.z; acc[e2][3]=b3.w; }
      #pragma unroll 2
      for (int k=0;k<64;k+=4){
        float4 h[4];
        #pragma unroll
        for (int e2=0;e2<4;e2++) h[e2] = *(const float4*)&L[OH2 + (eb4+e2)*68 + k];
        #pragma unroll
        for (int kk=0;kk<4;kk++){
          float4 w = *(const float4*)&rw3[(size_t)(k+kk)*448 + o];
          #pragma unroll
          for (int e2=0;e2<4;e2++){
            float xv = (kk==0)?h[e2].x:(kk==1)?h[e2].y:(kk==2)?h[e2].z:h[e2].w;
            acc[e2][0]+=xv*w.x; acc[e2][1]+=xv*w.y; acc[e2][2]+=xv*w.z; acc[e2][3]+=xv*w.w;
          }
        }
      }
      if (og < 32){
        #pragma unroll
        for (int e2=0;e2<4;e2++){
          int e = eb4+e2;
          float es = L[OEA + e*4];
          float4 ms = *(const float4*)&L[OMS + e*132 + o];
          float4 r; r.x=acc[e2][0]*ms.x*es; r.y=acc[e2][1]*ms.y*es; r.z=acc[e2][2]*ms.z*es; r.w=acc[e2][3]*ms.w*es;
          *(float4*)&L[OD0 + e*196 + o] = r;
        }
      } else {
        int oo = o-128;
        #pragma unroll
        for (int e2=0;e2<4;e2++){
          int e = eb4+e2;
          float4 ms = *(const float4*)&L[OMS + e*132 + oo];
          float4 r; r.x=acc[e2][0]*ms.x; r.y=acc[e2][1]*ms.y; r.z=acc[e2][2]*ms.z; r.w=acc[e2][3]*ms.w;
          *(float4*)&L[OASV + e*132 + oo] = r;
        }
      }
    }
    {
      int o1 = 256 + og*3;
      float acc[4][3];
      #pragma unroll
      for (int j=0;j<3;j++){ float b=rb3[o1+j]; acc[0][j]=b; acc[1][j]=b; acc[2][j]=b; acc[3][j]=b; }
      #pragma unroll 2
      for (int k=0;k<64;k+=4){
        float4 h[4];
        #pragma unroll
        for (int e2=0;e2<4;e2++) h[e2] = *(const float4*)&L[OH2 + (eb4+e2)*68 + k];
        #pragma unroll
        for (int kk=0;kk<4;kk++){
          #pragma unroll
          for (int j=0;j<3;j++){
            float w = rw3[(size_t)(k+kk)*448 + o1 + j];
            #pragma unroll
            for (int e2=0;e2<4;e2++){
              float xv = (kk==0)?h[e2].x:(kk==1)?h[e2].y:(kk==2)?h[e2].z:h[e2].w;
              acc[e2][j] += xv*w;
            }
          }
        }
      }
      #pragma unroll
      for (int e2=0;e2<4;e2++){
        int e = eb4+e2;
        float es = L[OEA + e*4];
        #pragma unroll
        for (int j=0;j<3;j++){
          int col = o1+j;
          float a = acc[e2][j];
          if (col < 320){
            L[OBVS + e*65 + (col-256)] = a*es;
          } else if (col < 384){
            int oo = col-320;
            float dot = L[OMV+e*196+oo*3]  *L[OEA+e*4+1]
                      + L[OMV+e*196+oo*3+1]*L[OEA+e*4+2]
                      + L[OMV+e*196+oo*3+2]*L[OEA+e*4+3];
            L[OD0 + e*196 + 128 + oo] = a*dot*0.5773502691896258f;
          } else {
            L[OWV1 + e*65 + (col-384)] = a*0.7071067811865476f;
          }
        }
      }
    }
  }
  __syncthreads();

  // ---- P4a: alpha logits in f32 (col = h*40 + kk0; d0 reads broadcast) ----
  {
    int a = t&31, eg = t>>5;
    int col = (a>>3)*40 + (a&7);
    int h = a>>3, kk0 = a&7;
    int ea = eg*2;
    float s0 = 0.f, s1 = 0.f;
    for (int k=0;k<192;k+=4){
      float4 xa = *(const float4*)&L[OD0 + ea*196 + k];
      float4 xb = *(const float4*)&L[OD0 + (ea+1)*196 + k];
      float w0 = lw0[(size_t)(k+0)*160 + col];
      float w1 = lw0[(size_t)(k+1)*160 + col];
      float w2 = lw0[(size_t)(k+2)*160 + col];
      float w3 = lw0[(size_t)(k+3)*160 + col];
      s0 += xa.x*w0 + xa.y*w1 + xa.z*w2 + xa.w*w3;
      s1 += xb.x*w0 + xb.y*w1 + xb.z*w2 + xb.w*w3;
    }
    const float rs = 0.07216878364870323f;
    float lb = lb0[col], ad = alpha_dot[h*8 + kk0];
    float m0 = s0*rs + lb, m1v = s1*rs + lb;
    float p0 = (0.6f*m0 + 0.4f*m0*(2.f*sigmoidf_(m0)-1.f))*ad;
    float p1 = (0.6f*m1v + 0.4f*m1v*(2.f*sigmoidf_(m1v)-1.f))*ad;
    #pragma unroll
    for (int m=1;m<8;m<<=1){
      p0 += __shfl_xor(p0, m);
      p1 += __shfl_xor(p1, m);
    }
    if (kk0 == 0){
      galpha[(size_t)(e0+ea)*4 + h]   = p0;
      galpha[(size_t)(e0+ea+1)*4 + h] = p1;
    }
  }

  // ---- P4b: val via MFMA (perm tiles 2..9), A = bf16(d0), B = lw0p ----
  {
    int lane = t&63, w = t>>6;
    int arow = lane&15, kg = lane>>4;
    int n0 = 2 + 2*w, n1 = 3 + 2*w;
    f32x4 acc0 = {0.f,0.f,0.f,0.f}, acc1 = {0.f,0.f,0.f,0.f};
    #pragma unroll
    for (int kt=0; kt<6; kt++){
      int k0 = kt*32 + kg*8;
      float4 xa = *(const float4*)&L[OD0 + arow*196 + k0];
      float4 xb = *(const float4*)&L[OD0 + arow*196 + k0 + 4];
      s16x8 af;
      af[0]=(short)f2bf(xa.x); af[1]=(short)f2bf(xa.y); af[2]=(short)f2bf(xa.z); af[3]=(short)f2bf(xa.w);
      af[4]=(short)f2bf(xb.x); af[5]=(short)f2bf(xb.y); af[6]=(short)f2bf(xb.z); af[7]=(short)f2bf(xb.w);
      s16x8 b0 = *(const s16x8*)&lw0p[(size_t)((n0*6 + kt)*64 + lane)*8];
      s16x8 b1 = *(const s16x8*)&lw0p[(size_t)((n1*6 + kt)*64 + lane)*8];
      acc0 = __builtin_amdgcn_mfma_f32_16x16x32_bf16(af, b0, acc0, 0,0,0);
      acc1 = __builtin_amdgcn_mfma_f32_16x16x32_bf16(af, b1, acc1, 0,0,0);
    }
    const float rs = 0.07216878364870323f;
    {
      int q = (n0-2)*16 + (lane&15);
      float lb = lb0[(q>>5)*40 + 8 + (q&31)];
      #pragma unroll
      for (int r=0;r<4;r++){
        int er = (lane>>4)*4 + r;
        gval[(size_t)(e0+er)*128 + q] = __float2bfloat16(acc0[r]*rs + lb);
      }
    }
    {
      int q = (n1-2)*16 + (lane&15);
      float lb = lb0[(q>>5)*40 + 8 + (q&31)];
      #pragma unroll
      for (int r=0;r<4;r++){
        int er = (lane>>4)*4 + r;
        gval[(size_t)(e0+er)*128 + q] = __float2bfloat16(acc1[r]*rs + lb);
      }
    }
  }
  __syncthreads();

  // ---- P5-prep: build d1 (rows 128..255 of full d1, per component) in f32 LDS ----
  {
    for (int idx=t; idx<6144; idx+=256){
      int c = idx>>11, rem = idx&2047, e = rem>>7, i = rem&127;
      float v;
      if (i < 64){
        v = L[OBVS + e*65 + i] * L[OMV + e*196 + i*3 + c];
      } else {
        int ii = i-64;
        int ca = (c+1)%3, cb = (c+2)%3;
        v = L[OWV1 + e*65 + ii] *
            (L[OMV+e*196+ii*3+ca]*L[OEA+e*4+1+cb] - L[OMV+e*196+ii*3+cb]*L[OEA+e*4+1+ca]);
      }
      L[OD1 + c*2112 + e*132 + i] = v;
    }
  }
  __syncthreads();

  // ---- P5: m1_c = concat(asv*ev_c, d1_c) @ lw1 via MFMA; wave w owns N-tile w ----
  {
    int lane = t&63, nt = t>>6;
    int arow = lane&15, kg = lane>>4;
    float ev0 = L[OEA + arow*4 + 1];
    float ev1 = L[OEA + arow*4 + 2];
    float ev2 = L[OEA + arow*4 + 3];
    f32x4 acc0 = {0.f,0.f,0.f,0.f}, acc1 = {0.f,0.f,0.f,0.f}, acc2 = {0.f,0.f,0.f,0.f};
    #pragma unroll
    for (int kt=0; kt<8; kt++){
      s16x8 b = *(const s16x8*)&lw1p[(size_t)((nt*8 + kt)*64 + lane)*8];
      if (kt < 4){
        int k0 = kt*32 + kg*8;
        float4 xa = *(const float4*)&L[OASV + arow*132 + k0];
        float4 xb = *(const float4*)&L[OASV + arow*132 + k0 + 4];
        float x[8] = {xa.x,xa.y,xa.z,xa.w,xb.x,xb.y,xb.z,xb.w};
        s16x8 a0, a1, a2;
        #pragma unroll
        for (int i=0;i<8;i++){
          a0[i] = (short)f2bf(x[i]*ev0);
          a1[i] = (short)f2bf(x[i]*ev1);
          a2[i] = (short)f2bf(x[i]*ev2);
        }
        acc0 = __builtin_amdgcn_mfma_f32_16x16x32_bf16(a0, b, acc0, 0,0,0);
        acc1 = __builtin_amdgcn_mfma_f32_16x16x32_bf16(a1, b, acc1, 0,0,0);
        acc2 = __builtin_amdgcn_mfma_f32_16x16x32_bf16(a2, b, acc2, 0,0,0);
      } else {
        int k0 = (kt-4)*32 + kg*8;
        #pragma unroll
        for (int c=0;c<3;c++){
          float4 ya = *(const float4*)&L[OD1 + c*2112 + arow*132 + k0];
          float4 yb = *(const float4*)&L[OD1 + c*2112 + arow*132 + k0 + 4];
          s16x8 af;
          af[0]=(short)f2bf(ya.x); af[1]=(short)f2bf(ya.y); af[2]=(short)f2bf(ya.z); af[3]=(short)f2bf(ya.w);
          af[4]=(short)f2bf(yb.x); af[5]=(short)f2bf(yb.y); af[6]=(short)f2bf(yb.z); af[7]=(short)f2bf(yb.w);
          if (c==0)      acc0 = __builtin_amdgcn_mfma_f32_16x16x32_bf16(af, b, acc0, 0,0,0);
          else if (c==1) acc1 = __builtin_amdgcn_mfma_f32_16x16x32_bf16(af, b, acc1, 0,0,0);
          else           acc2 = __builtin_amdgcn_mfma_f32_16x16x32_bf16(af, b, acc2, 0,0,0);
        }
      }
    }
    const float r16 = 0.0625f;
    int col = nt*16 + (lane&15);
    #pragma unroll
    for (int r=0;r<4;r++){
      int er = (lane>>4)*4 + r;
      gm1[((size_t)(e0+er)*3 + 0)*64 + col] = __float2bfloat16(acc0[r]*r16);
      gm1[((size_t)(e0+er)*3 + 1)*64 + col] = __float2bfloat16(acc1[r]*r16);
      gm1[((size_t)(e0+er)*3 + 2)*64 + col] = __float2bfloat16(acc2[r]*r16);
    }
  }
}

// ---------------- Kernel D: per-dst softmax + aggregation (unchanged) ----------------
__global__ __launch_bounds__(320) void k_agg(
  const int* __restrict__ edge_dst,
  const float* __restrict__ galpha, const __hip_bfloat16* __restrict__ gval,
  const __hip_bfloat16* __restrict__ gm1,
  const float* __restrict__ pw0, const float* __restrict__ pb0,
  const float* __restrict__ pw1,
  float* __restrict__ out)
{
  __shared__ float sRed[256], sW[256], sAm[4], sInv[4], sNS[128], sNV[192];
  int t = threadIdx.x;
  int n = blockIdx.x;
  int lo, hi;
  {
    int a=0,b=N_EDGES;
    while(a<b){int m=(a+b)>>1; if (edge_dst[m] < n) a=m+1; else b=m;}
    lo=a; a=lo; b=N_EDGES;
    while(a<b){int m=(a+b)>>1; if (edge_dst[m] < n+1) a=m+1; else b=m;}
    hi=a;
  }
  if (t < 256){
    int g=t>>2, h=t&3;
    float m=-1e30f;
    for (int e=lo+g; e<hi; e+=64) m = fmaxf(m, galpha[(size_t)e*4+h]);
    sRed[t]=m;
  }
  __syncthreads();
  for (int s=32; s>=1; s>>=1){
    if (t < s*4) sRed[t] = fmaxf(sRed[t], sRed[t+s*4]);
    __syncthreads();
  }
  if (t<4) sAm[t] = (hi>lo) ? sRed[t] : 0.f;
  __syncthreads();
  if (t < 256){
    int g=t>>2, h=t&3; float ssum=0.f;
    for (int e=lo+g; e<hi; e+=64) ssum += __expf(galpha[(size_t)e*4+h]-sAm[h]);
    sRed[t]=ssum;
  }
  __syncthreads();
  for (int s=32; s>=1; s>>=1){
    if (t < s*4) sRed[t] += sRed[t+s*4];
    __syncthreads();
  }
  if (t<4) sInv[t] = 1.f / fmaxf(sRed[t], 1e-12f);
  __syncthreads();
  float acc = 0.f;
  int cq=0, oq=0, hq=0;
  if (t < 128){ hq = t>>5; }
  else { int q=t-128; cq=q>>6; oq=q&63; hq=oq>>4; }
  for (int base=lo; base<hi; base+=64){
    int nn = min(64, hi-base);
    if (t < 256){ int j=t>>2,h=t&3; if (j<nn) sW[t] = __expf(galpha[(size_t)(base+j)*4+h]-sAm[h])*sInv[h]; }
    __syncthreads();
    if (t < 128){
      for (int j=0;j<nn;j++) acc += sW[j*4+hq]*__bfloat162float(gval[(size_t)(base+j)*128+t]);
    } else {
      for (int j=0;j<nn;j++) acc += sW[j*4+hq]*__bfloat162float(gm1[(size_t)((size_t)(base+j)*3+cq)*64+oq]);
    }
    __syncthreads();
  }
  if (t < 128) sNS[t]=acc; else sNV[oq*3+cq]=acc;
  __syncthreads();
  if (t < 128){
    float a = 0.f;
    for (int k=0;k<128;k++) a += sNS[k]*pw0[k*128+t];
    out[(size_t)n*320+t] = a*0.08838834764831845f + pb0[t];
  } else {
    float a = 0.f;
    for (int i=0;i<64;i++) a += sNV[i*3+cq]*pw1[i*64+oq];
    out[(size_t)n*320+128+oq*3+cq] = a*0.125f;
  }
}

extern "C" void kernel_launch(void* const* d_in, const int* in_sizes, int n_in,
                              void* d_out, int out_size, void* d_ws, size_t ws_size,
                              hipStream_t stream)
{
  const float* node_input  = (const float*)d_in[0];
  const float* edge_attr   = (const float*)d_in[1];
  const float* edge_scalars= (const float*)d_in[2];
  const int*   edge_src    = (const int*)d_in[3];
  const int*   edge_dst    = (const int*)d_in[4];
  const float* w_src0=(const float*)d_in[5];  const float* b_src0=(const float*)d_in[6];
  const float* w_src1=(const float*)d_in[7];
  const float* w_dst0=(const float*)d_in[8];  const float* b_dst0=(const float*)d_in[9];
  const float* w_dst1=(const float*)d_in[10];
  const float* rw1=(const float*)d_in[11];    const float* rb1=(const float*)d_in[12];
  const float* rw2=(const float*)d_in[13];    const float* rb2=(const float*)d_in[14];
  const float* rw3=(const float*)d_in[15];    const float* rb3=(const float*)d_in[16];
  const float* lw0=(const float*)d_in[17];    const float* lb0=(const float*)d_in[18];
  const float* lw1=(const float*)d_in[19];
  const float* alpha_dot=(const float*)d_in[20];
  const float* pw0=(const float*)d_in[21];    const float* pb0=(const float*)d_in[22];
  const float* pw1=(const float*)d_in[23];
  float* out = (float*)d_out;

  float* ns_src = (float*)d_ws;
  float* ns_dst = ns_src + (size_t)N_NODES*128;
  float* nv_src = ns_dst + (size_t)N_NODES*128;
  float* nv_dst = nv_src + (size_t)N_NODES*192;
  float* galpha = nv_dst + (size_t)N_NODES*192;
  __hip_bfloat16* gval = (__hip_bfloat16*)(galpha + (size_t)N_EDGES*4);
  __hip_bfloat16* gm1  = gval + (size_t)N_EDGES*128;
  ushort_t* lw0p = (ushort_t*)(gm1 + (size_t)N_EDGES*192);
  ushort_t* lw1p = lw0p + 30720;

  k_pack<<<184, 256, 0, stream>>>(lw0, lw1, lw0p, lw1p);
  k_node<<<N_NODES/8, 256, 0, stream>>>(node_input, w_src0,b_src0,w_src1,
                                        w_dst0,b_dst0,w_dst1,
                                        ns_src,ns_dst,nv_src,nv_dst);
  k_edge3<<<N_EDGES/EB, 256, 0, stream>>>(edge_attr, edge_scalars, edge_src, edge_dst,
                                          ns_src,ns_dst,nv_src,nv_dst,
                                          rw1,rb1,rw2,rb2,rw3,rb3,
                                          lw0,lb0,lw0p,lw1p,alpha_dot,
                                          galpha,gval,gm1);
  k_agg<<<N_NODES, 320, 0, stream>>>(edge_dst, galpha, gval, gm1, pw0,pb0,pw1, out);
}

// Round 7
// 728.890 us; speedup vs baseline: 9.4799x; 1.0008x over previous
//
#include <hip/hip_runtime.h>
#include <hip/hip_bf16.h>
#include <math.h>

#define N_NODES 10000
#define N_EDGES 160000
#define EB 16

typedef unsigned short ushort_t;
using f32x4 = __attribute__((ext_vector_type(4))) float;
using s16x8 = __attribute__((ext_vector_type(8))) short;

__device__ __forceinline__ float sigmoidf_(float x){ return 1.f/(1.f+__expf(-x)); }
__device__ __forceinline__ unsigned short f2bf(float x){
  __hip_bfloat16 h = __float2bfloat16(x);
  return *reinterpret_cast<unsigned short*>(&h);
}

// ---------------- Kernel P: pack lw0 (col-permuted) + lw1 into bf16 MFMA-frag order ----
// lw0p: [10 nt][6 kt][64 lane][8]  (perm: cols 0..31 = alpha cols, 32..159 = gval order)
// lw1p: [4 nt][8 kt][64 lane][8]
__global__ __launch_bounds__(256) void k_pack(
  const float* __restrict__ lw0, const float* __restrict__ lw1,
  ushort_t* __restrict__ lw0p, ushort_t* __restrict__ lw1p)
{
  int idx = blockIdx.x*256 + threadIdx.x;
  if (idx < 30720){
    int nt = idx/3072, r = idx - nt*3072;
    int kt = r>>9, lane = (r>>3)&63, i = r&7;
    int k = kt*32 + (lane>>4)*8 + i;
    int cp = nt*16 + (lane&15);
    int col;
    if (cp < 32){ col = (cp>>3)*40 + (cp&7); }
    else { int q = cp-32; col = (q>>5)*40 + 8 + (q&31); }
    lw0p[idx] = f2bf(lw0[(size_t)k*160 + col]);
  } else if (idx < 47104){
    int j = idx - 30720;
    int nt = j/4096, r = j - nt*4096;
    int kt = r>>9, lane = (r>>3)&63, i = r&7;
    int k = kt*32 + (lane>>4)*8 + i;
    int col = nt*16 + (lane&15);
    lw1p[j] = f2bf(lw1[(size_t)k*64 + col]);
  }
}

// ---------------- Kernel A: node transforms (unchanged) ----------------
__global__ __launch_bounds__(256) void k_node(
    const float* __restrict__ node_input,
    const float* __restrict__ w_src0, const float* __restrict__ b_src0,
    const float* __restrict__ w_src1,
    const float* __restrict__ w_dst0, const float* __restrict__ b_dst0,
    const float* __restrict__ w_dst1,
    float* __restrict__ ns_src, float* __restrict__ ns_dst,
    float* __restrict__ nv_src, float* __restrict__ nv_dst)
{
  __shared__ float sNI[8*321];
  int t = threadIdx.x;
  int n0 = blockIdx.x*8;
  for (int idx=t; idx<8*320; idx+=256){
    int nd = idx/320, r = idx - nd*320;
    sNI[nd*321+r] = node_input[(size_t)(n0+nd)*320 + r];
  }
  __syncthreads();
  {
    int o = t & 127, half = t >> 7;
    const float* w = half ? w_dst0 : w_src0;
    const float* b = half ? b_dst0 : b_src0;
    float* outp = half ? ns_dst : ns_src;
    float acc[8];
    #pragma unroll
    for (int nd=0;nd<8;nd++) acc[nd]=0.f;
    for (int k=0;k<128;k++){
      float wv = w[k*128+o];
      #pragma unroll
      for (int nd=0;nd<8;nd++) acc[nd] += sNI[nd*321+k]*wv;
    }
    const float rs = 0.08838834764831845f;
    float bo = b[o];
    #pragma unroll
    for (int nd=0;nd<8;nd++) outp[(size_t)(n0+nd)*128+o] = acc[nd]*rs + bo;
  }
  if (t < 192){
    int o = t & 63, c = t >> 6;
    for (int half=0; half<2; half++){
      const float* w = half ? w_dst1 : w_src1;
      float* outp = half ? nv_dst : nv_src;
      float acc[8];
      #pragma unroll
      for (int nd=0;nd<8;nd++) acc[nd]=0.f;
      for (int i=0;i<64;i++){
        float wv = w[i*64+o];
        #pragma unroll
        for (int nd=0;nd<8;nd++) acc[nd] += sNI[nd*321+128+i*3+c]*wv;
      }
      #pragma unroll
      for (int nd=0;nd<8;nd++) outp[(size_t)(n0+nd)*192 + o*3 + c] = acc[nd]*0.125f;
    }
  }
}

// ---------------- Kernel C: EB=16; f32 alpha chain + MFMA val/m1 ----------------
#define OEA  0       // 16*4
#define OMV  64      // 16*196
#define OASV 3200    // 16*132
#define OBVS 5312    // 16*65
#define OWV1 6352    // 16*65
#define OES  7392    // 16*68  (P0-P1)
#define OD0  7392    // 16*196 (P3-P4)
#define OD1  7392    // 3*2112 (P5)
#define OH1  13728   // 16*68  (P1-P2)
#define OH2  14816   // 16*68  (P2-P3)
#define OMS  15904   // 16*132 (P0-P3)

__global__ __launch_bounds__(256) void k_edge3(
  const float* __restrict__ edge_attr, const float* __restrict__ edge_scalars,
  const int* __restrict__ edge_src, const int* __restrict__ edge_dst,
  const float* __restrict__ ns_src, const float* __restrict__ ns_dst,
  const float* __restrict__ nv_src, const float* __restrict__ nv_dst,
  const float* __restrict__ rw1, const float* __restrict__ rb1,
  const float* __restrict__ rw2, const float* __restrict__ rb2,
  const float* __restrict__ rw3, const float* __restrict__ rb3,
  const float* __restrict__ lw0, const float* __restrict__ lb0,
  const ushort_t* __restrict__ lw0p, const ushort_t* __restrict__ lw1p,
  const float* __restrict__ alpha_dot,
  float* __restrict__ galpha, __hip_bfloat16* __restrict__ gval,
  __hip_bfloat16* __restrict__ gm1)
{
  __shared__ __align__(16) float L[18016];
  const int t = threadIdx.x;
  const int e0 = blockIdx.x * EB;

  // ---- P0: staging ----
  {
    int e = t>>4, l = t&15;
    int s = edge_src[e0+e], d = edge_dst[e0+e];
    #pragma unroll
    for (int j=0;j<2;j++){
      int idx = l + 16*j;
      float4 a = *(const float4*)&ns_src[(size_t)s*128 + idx*4];
      float4 b = *(const float4*)&ns_dst[(size_t)d*128 + idx*4];
      float4 r; r.x=a.x+b.x; r.y=a.y+b.y; r.z=a.z+b.z; r.w=a.w+b.w;
      *(float4*)&L[OMS + e*132 + idx*4] = r;
    }
    #pragma unroll
    for (int j=0;j<3;j++){
      int idx = l + 16*j;
      float4 a = *(const float4*)&nv_src[(size_t)s*192 + idx*4];
      float4 b = *(const float4*)&nv_dst[(size_t)d*192 + idx*4];
      float4 r; r.x=a.x+b.x; r.y=a.y+b.y; r.z=a.z+b.z; r.w=a.w+b.w;
      *(float4*)&L[OMV + e*196 + idx*4] = r;
    }
    *(float4*)&L[OES + e*68 + l*4] = *(const float4*)&edge_scalars[(size_t)(e0+e)*64 + l*4];
  }
  if (t < 64) L[OEA + t] = edge_attr[(size_t)e0*4 + t];
  __syncthreads();

  // ---- P1: h1 = silu(es @ rw1 + rb1) ----
  {
    int e = t>>4, o = (t&15)*4;
    float4 b = *(const float4*)&rb1[o];
    float a0=b.x, a1=b.y, a2=b.z, a3=b.w;
    for (int k=0;k<64;k+=4){
      float4 x = *(const float4*)&L[OES + e*68 + k];
      #pragma unroll
      for (int kk=0;kk<4;kk++){
        float4 w = *(const float4*)&rw1[(k+kk)*64 + o];
        float xv = (kk==0)?x.x:(kk==1)?x.y:(kk==2)?x.z:x.w;
        a0 += xv*w.x; a1 += xv*w.y; a2 += xv*w.z; a3 += xv*w.w;
      }
    }
    float4 r; r.x=a0*sigmoidf_(a0); r.y=a1*sigmoidf_(a1); r.z=a2*sigmoidf_(a2); r.w=a3*sigmoidf_(a3);
    *(float4*)&L[OH1 + e*68 + o] = r;
  }
  __syncthreads();

  // ---- P2: h2 = silu(h1 @ rw2 + rb2) ----
  {
    int e = t>>4, o = (t&15)*4;
    float4 b = *(const float4*)&rb2[o];
    float a0=b.x, a1=b.y, a2=b.z, a3=b.w;
    for (int k=0;k<64;k+=4){
      float4 x = *(const float4*)&L[OH1 + e*68 + k];
      #pragma unroll
      for (int kk=0;kk<4;kk++){
        float4 w = *(const float4*)&rw2[(k+kk)*64 + o];
        float xv = (kk==0)?x.x:(kk==1)?x.y:(kk==2)?x.z:x.w;
        a0 += xv*w.x; a1 += xv*w.y; a2 += xv*w.z; a3 += xv*w.w;
      }
    }
    float4 r; r.x=a0*sigmoidf_(a0); r.y=a1*sigmoidf_(a1); r.z=a2*sigmoidf_(a2); r.w=a3*sigmoidf_(a3);
    *(float4*)&L[OH2 + e*68 + o] = r;
  }
  __syncthreads();

  // ---- P3: w = h2 @ rw3 + rb3 (f32, alpha-critical), consumed on the fly ----
  {
    int og = t&63, eg = t>>6;
    int eb4 = eg*4;
    {
      int o = og*4;
      float4 b3 = *(const float4*)&rb3[o];
      float acc[4][4];
      #pragma unroll
      for (int e2=0;e2<4;e2++){ acc[e2][0]=b3.x; acc[e2][1]=b3.y; acc[e2][2]=b3.z; acc[e2][3]=b3.w; }
      #pragma unroll 2
      for (int k=0;k<64;k+=4){
        float4 h[4];
        #pragma unroll
        for (int e2=0;e2<4;e2++) h[e2] = *(const float4*)&L[OH2 + (eb4+e2)*68 + k];
        #pragma unroll
        for (int kk=0;kk<4;kk++){
          float4 w = *(const float4*)&rw3[(size_t)(k+kk)*448 + o];
          #pragma unroll
          for (int e2=0;e2<4;e2++){
            float xv = (kk==0)?h[e2].x:(kk==1)?h[e2].y:(kk==2)?h[e2].z:h[e2].w;
            acc[e2][0]+=xv*w.x; acc[e2][1]+=xv*w.y; acc[e2][2]+=xv*w.z; acc[e2][3]+=xv*w.w;
          }
        }
      }
      if (og < 32){
        #pragma unroll
        for (int e2=0;e2<4;e2++){
          int e = eb4+e2;
          float es = L[OEA + e*4];
          float4 ms = *(const float4*)&L[OMS + e*132 + o];
          float4 r; r.x=acc[e2][0]*ms.x*es; r.y=acc[e2][1]*ms.y*es; r.z=acc[e2][2]*ms.z*es; r.w=acc[e2][3]*ms.w*es;
          *(float4*)&L[OD0 + e*196 + o] = r;
        }
      } else {
        int oo = o-128;
        #pragma unroll
        for (int e2=0;e2<4;e2++){
          int e = eb4+e2;
          float4 ms = *(const float4*)&L[OMS + e*132 + oo];
          float4 r; r.x=acc[e2][0]*ms.x; r.y=acc[e2][1]*ms.y; r.z=acc[e2][2]*ms.z; r.w=acc[e2][3]*ms.w;
          *(float4*)&L[OASV + e*132 + oo] = r;
        }
      }
    }
    {
      int o1 = 256 + og*3;
      float acc[4][3];
      #pragma unroll
      for (int j=0;j<3;j++){ float b=rb3[o1+j]; acc[0][j]=b; acc[1][j]=b; acc[2][j]=b; acc[3][j]=b; }
      #pragma unroll 2
      for (int k=0;k<64;k+=4){
        float4 h[4];
        #pragma unroll
        for (int e2=0;e2<4;e2++) h[e2] = *(const float4*)&L[OH2 + (eb4+e2)*68 + k];
        #pragma unroll
        for (int kk=0;kk<4;kk++){
          #pragma unroll
          for (int j=0;j<3;j++){
            float w = rw3[(size_t)(k+kk)*448 + o1 + j];
            #pragma unroll
            for (int e2=0;e2<4;e2++){
              float xv = (kk==0)?h[e2].x:(kk==1)?h[e2].y:(kk==2)?h[e2].z:h[e2].w;
              acc[e2][j] += xv*w;
            }
          }
        }
      }
      #pragma unroll
      for (int e2=0;e2<4;e2++){
        int e = eb4+e2;
        float es = L[OEA + e*4];
        #pragma unroll
        for (int j=0;j<3;j++){
          int col = o1+j;
          float a = acc[e2][j];
          if (col < 320){
            L[OBVS + e*65 + (col-256)] = a*es;
          } else if (col < 384){
            int oo = col-320;
            float dot = L[OMV+e*196+oo*3]  *L[OEA+e*4+1]
                      + L[OMV+e*196+oo*3+1]*L[OEA+e*4+2]
                      + L[OMV+e*196+oo*3+2]*L[OEA+e*4+3];
            L[OD0 + e*196 + 128 + oo] = a*dot*0.5773502691896258f;
          } else {
            L[OWV1 + e*65 + (col-384)] = a*0.7071067811865476f;
          }
        }
      }
    }
  }
  __syncthreads();

  // ---- P4a: alpha logits in f32 (col = h*40 + kk0; d0 reads broadcast) ----
  {
    int a = t&31, eg = t>>5;
    int col = (a>>3)*40 + (a&7);
    int h = a>>3, kk0 = a&7;
    int ea = eg*2;
    float s0 = 0.f, s1 = 0.f;
    for (int k=0;k<192;k+=4){
      float4 xa = *(const float4*)&L[OD0 + ea*196 + k];
      float4 xb = *(const float4*)&L[OD0 + (ea+1)*196 + k];
      float w0 = lw0[(size_t)(k+0)*160 + col];
      float w1 = lw0[(size_t)(k+1)*160 + col];
      float w2 = lw0[(size_t)(k+2)*160 + col];
      float w3 = lw0[(size_t)(k+3)*160 + col];
      s0 += xa.x*w0 + xa.y*w1 + xa.z*w2 + xa.w*w3;
      s1 += xb.x*w0 + xb.y*w1 + xb.z*w2 + xb.w*w3;
    }
    const float rs = 0.07216878364870323f;
    float lb = lb0[col], ad = alpha_dot[h*8 + kk0];
    float m0 = s0*rs + lb, m1v = s1*rs + lb;
    float p0 = (0.6f*m0 + 0.4f*m0*(2.f*sigmoidf_(m0)-1.f))*ad;
    float p1 = (0.6f*m1v + 0.4f*m1v*(2.f*sigmoidf_(m1v)-1.f))*ad;
    #pragma unroll
    for (int m=1;m<8;m<<=1){
      p0 += __shfl_xor(p0, m);
      p1 += __shfl_xor(p1, m);
    }
    if (kk0 == 0){
      galpha[(size_t)(e0+ea)*4 + h]   = p0;
      galpha[(size_t)(e0+ea+1)*4 + h] = p1;
    }
  }

  // ---- P4b: val via MFMA (perm tiles 2..9), A = bf16(d0), B = lw0p ----
  {
    int lane = t&63, w = t>>6;
    int arow = lane&15, kg = lane>>4;
    int n0 = 2 + 2*w, n1 = 3 + 2*w;
    f32x4 acc0 = {0.f,0.f,0.f,0.f}, acc1 = {0.f,0.f,0.f,0.f};
    #pragma unroll
    for (int kt=0; kt<6; kt++){
      int k0 = kt*32 + kg*8;
      float4 xa = *(const float4*)&L[OD0 + arow*196 + k0];
      float4 xb = *(const float4*)&L[OD0 + arow*196 + k0 + 4];
      s16x8 af;
      af[0]=(short)f2bf(xa.x); af[1]=(short)f2bf(xa.y); af[2]=(short)f2bf(xa.z); af[3]=(short)f2bf(xa.w);
      af[4]=(short)f2bf(xb.x); af[5]=(short)f2bf(xb.y); af[6]=(short)f2bf(xb.z); af[7]=(short)f2bf(xb.w);
      s16x8 b0 = *(const s16x8*)&lw0p[(size_t)((n0*6 + kt)*64 + lane)*8];
      s16x8 b1 = *(const s16x8*)&lw0p[(size_t)((n1*6 + kt)*64 + lane)*8];
      acc0 = __builtin_amdgcn_mfma_f32_16x16x32_bf16(af, b0, acc0, 0,0,0);
      acc1 = __builtin_amdgcn_mfma_f32_16x16x32_bf16(af, b1, acc1, 0,0,0);
    }
    const float rs = 0.07216878364870323f;
    {
      int q = (n0-2)*16 + (lane&15);
      float lb = lb0[(q>>5)*40 + 8 + (q&31)];
      #pragma unroll
      for (int r=0;r<4;r++){
        int er = (lane>>4)*4 + r;
        gval[(size_t)(e0+er)*128 + q] = __float2bfloat16(acc0[r]*rs + lb);
      }
    }
    {
      int q = (n1-2)*16 + (lane&15);
      float lb = lb0[(q>>5)*40 + 8 + (q&31)];
      #pragma unroll
      for (int r=0;r<4;r++){
        int er = (lane>>4)*4 + r;
        gval[(size_t)(e0+er)*128 + q] = __float2bfloat16(acc1[r]*rs + lb);
      }
    }
  }
  __syncthreads();

  // ---- P5-prep: build d1 (rows 128..255 of full d1, per component) in f32 LDS ----
  {
    for (int idx=t; idx<6144; idx+=256){
      int c = idx>>11, rem = idx&2047, e = rem>>7, i = rem&127;
      float v;
      if (i < 64){
        v = L[OBVS + e*65 + i] * L[OMV + e*196 + i*3 + c];
      } else {
        int ii = i-64;
        int ca = (c+1)%3, cb = (c+2)%3;
        v = L[OWV1 + e*65 + ii] *
            (L[OMV+e*196+ii*3+ca]*L[OEA+e*4+1+cb] - L[OMV+e*196+ii*3+cb]*L[OEA+e*4+1+ca]);
      }
      L[OD1 + c*2112 + e*132 + i] = v;
    }
  }
  __syncthreads();

  // ---- P5: m1_c = concat(asv*ev_c, d1_c) @ lw1 via MFMA; wave w owns N-tile w ----
  {
    int lane = t&63, nt = t>>6;
    int arow = lane&15, kg = lane>>4;
    float ev0 = L[OEA + arow*4 + 1];
    float ev1 = L[OEA + arow*4 + 2];
    float ev2 = L[OEA + arow*4 + 3];
    f32x4 acc0 = {0.f,0.f,0.f,0.f}, acc1 = {0.f,0.f,0.f,0.f}, acc2 = {0.f,0.f,0.f,0.f};
    #pragma unroll
    for (int kt=0; kt<8; kt++){
      s16x8 b = *(const s16x8*)&lw1p[(size_t)((nt*8 + kt)*64 + lane)*8];
      if (kt < 4){
        int k0 = kt*32 + kg*8;
        float4 xa = *(const float4*)&L[OASV + arow*132 + k0];
        float4 xb = *(const float4*)&L[OASV + arow*132 + k0 + 4];
        float x[8] = {xa.x,xa.y,xa.z,xa.w,xb.x,xb.y,xb.z,xb.w};
        s16x8 a0, a1, a2;
        #pragma unroll
        for (int i=0;i<8;i++){
          a0[i] = (short)f2bf(x[i]*ev0);
          a1[i] = (short)f2bf(x[i]*ev1);
          a2[i] = (short)f2bf(x[i]*ev2);
        }
        acc0 = __builtin_amdgcn_mfma_f32_16x16x32_bf16(a0, b, acc0, 0,0,0);
        acc1 = __builtin_amdgcn_mfma_f32_16x16x32_bf16(a1, b, acc1, 0,0,0);
        acc2 = __builtin_amdgcn_mfma_f32_16x16x32_bf16(a2, b, acc2, 0,0,0);
      } else {
        int k0 = (kt-4)*32 + kg*8;
        #pragma unroll
        for (int c=0;c<3;c++){
          float4 ya = *(const float4*)&L[OD1 + c*2112 + arow*132 + k0];
          float4 yb = *(const float4*)&L[OD1 + c*2112 + arow*132 + k0 + 4];
          s16x8 af;
          af[0]=(short)f2bf(ya.x); af[1]=(short)f2bf(ya.y); af[2]=(short)f2bf(ya.z); af[3]=(short)f2bf(ya.w);
          af[4]=(short)f2bf(yb.x); af[5]=(short)f2bf(yb.y); af[6]=(short)f2bf(yb.z); af[7]=(short)f2bf(yb.w);
          if (c==0)      acc0 = __builtin_amdgcn_mfma_f32_16x16x32_bf16(af, b, acc0, 0,0,0);
          else if (c==1) acc1 = __builtin_amdgcn_mfma_f32_16x16x32_bf16(af, b, acc1, 0,0,0);
          else           acc2 = __builtin_amdgcn_mfma_f32_16x16x32_bf16(af, b, acc2, 0,0,0);
        }
      }
    }
    const float r16 = 0.0625f;
    int col = nt*16 + (lane&15);
    #pragma unroll
    for (int r=0;r<4;r++){
      int er = (lane>>4)*4 + r;
      gm1[((size_t)(e0+er)*3 + 0)*64 + col] = __float2bfloat16(acc0[r]*r16);
      gm1[((size_t)(e0+er)*3 + 1)*64 + col] = __float2bfloat16(acc1[r]*r16);
      gm1[((size_t)(e0+er)*3 + 2)*64 + col] = __float2bfloat16(acc2[r]*r16);
    }
  }
}

// ---------------- Kernel D: per-dst softmax + aggregation (unchanged) ----------------
__global__ __launch_bounds__(320) void k_agg(
  const int* __restrict__ edge_dst,
  const float* __restrict__ galpha, const __hip_bfloat16* __restrict__ gval,
  const __hip_bfloat16* __restrict__ gm1,
  const float* __restrict__ pw0, const float* __restrict__ pb0,
  const float* __restrict__ pw1,
  float* __restrict__ out)
{
  __shared__ float sRed[256], sW[256], sAm[4], sInv[4], sNS[128], sNV[192];
  int t = threadIdx.x;
  int n = blockIdx.x;
  int lo, hi;
  {
    int a=0,b=N_EDGES;
    while(a<b){int m=(a+b)>>1; if (edge_dst[m] < n) a=m+1; else b=m;}
    lo=a; a=lo; b=N_EDGES;
    while(a<b){int m=(a+b)>>1; if (edge_dst[m] < n+1) a=m+1; else b=m;}
    hi=a;
  }
  if (t < 256){
    int g=t>>2, h=t&3;
    float m=-1e30f;
    for (int e=lo+g; e<hi; e+=64) m = fmaxf(m, galpha[(size_t)e*4+h]);
    sRed[t]=m;
  }
  __syncthreads();
  for (int s=32; s>=1; s>>=1){
    if (t < s*4) sRed[t] = fmaxf(sRed[t], sRed[t+s*4]);
    __syncthreads();
  }
  if (t<4) sAm[t] = (hi>lo) ? sRed[t] : 0.f;
  __syncthreads();
  if (t < 256){
    int g=t>>2, h=t&3; float ssum=0.f;
    for (int e=lo+g; e<hi; e+=64) ssum += __expf(galpha[(size_t)e*4+h]-sAm[h]);
    sRed[t]=ssum;
  }
  __syncthreads();
  for (int s=32; s>=1; s>>=1){
    if (t < s*4) sRed[t] += sRed[t+s*4];
    __syncthreads();
  }
  if (t<4) sInv[t] = 1.f / fmaxf(sRed[t], 1e-12f);
  __syncthreads();
  float acc = 0.f;
  int cq=0, oq=0, hq=0;
  if (t < 128){ hq = t>>5; }
  else { int q=t-128; cq=q>>6; oq=q&63; hq=oq>>4; }
  for (int base=lo; base<hi; base+=64){
    int nn = min(64, hi-base);
    if (t < 256){ int j=t>>2,h=t&3; if (j<nn) sW[t] = __expf(galpha[(size_t)(base+j)*4+h]-sAm[h])*sInv[h]; }
    __syncthreads();
    if (t < 128){
      for (int j=0;j<nn;j++) acc += sW[j*4+hq]*__bfloat162float(gval[(size_t)(base+j)*128+t]);
    } else {
      for (int j=0;j<nn;j++) acc += sW[j*4+hq]*__bfloat162float(gm1[(size_t)((size_t)(base+j)*3+cq)*64+oq]);
    }
    __syncthreads();
  }
  if (t < 128) sNS[t]=acc; else sNV[oq*3+cq]=acc;
  __syncthreads();
  if (t < 128){
    float a = 0.f;
    for (int k=0;k<128;k++) a += sNS[k]*pw0[k*128+t];
    out[(size_t)n*320+t] = a*0.08838834764831845f + pb0[t];
  } else {
    float a = 0.f;
    for (int i=0;i<64;i++) a += sNV[i*3+cq]*pw1[i*64+oq];
    out[(size_t)n*320+128+oq*3+cq] = a*0.125f;
  }
}

extern "C" void kernel_launch(void* const* d_in, const int* in_sizes, int n_in,
                              void* d_out, int out_size, void* d_ws, size_t ws_size,
                              hipStream_t stream)
{
  const float* node_input  = (const float*)d_in[0];
  const float* edge_attr   = (const float*)d_in[1];
  const float* edge_scalars= (const float*)d_in[2];
  const int*   edge_src    = (const int*)d_in[3];
  const int*   edge_dst    = (const int*)d_in[4];
  const float* w_src0=(const float*)d_in[5];  const float* b_src0=(const float*)d_in[6];
  const float* w_src1=(const float*)d_in[7];
  const float* w_dst0=(const float*)d_in[8];  const float* b_dst0=(const float*)d_in[9];
  const float* w_dst1=(const float*)d_in[10];
  const float* rw1=(const float*)d_in[11];    const float* rb1=(const float*)d_in[12];
  const float* rw2=(const float*)d_in[13];    const float* rb2=(const float*)d_in[14];
  const float* rw3=(const float*)d_in[15];    const float* rb3=(const float*)d_in[16];
  const float* lw0=(const float*)d_in[17];    const float* lb0=(const float*)d_in[18];
  const float* lw1=(const float*)d_in[19];
  const float* alpha_dot=(const float*)d_in[20];
  const float* pw0=(const float*)d_in[21];    const float* pb0=(const float*)d_in[22];
  const float* pw1=(const float*)d_in[23];
  float* out = (float*)d_out;

  float* ns_src = (float*)d_ws;
  float* ns_dst = ns_src + (size_t)N_NODES*128;
  float* nv_src = ns_dst + (size_t)N_NODES*128;
  float* nv_dst = nv_src + (size_t)N_NODES*192;
  float* galpha = nv_dst + (size_t)N_NODES*192;
  __hip_bfloat16* gval = (__hip_bfloat16*)(galpha + (size_t)N_EDGES*4);
  __hip_bfloat16* gm1  = gval + (size_t)N_EDGES*128;
  ushort_t* lw0p = (ushort_t*)(gm1 + (size_t)N_EDGES*192);
  ushort_t* lw1p = lw0p + 30720;

  k_pack<<<184, 256, 0, stream>>>(lw0, lw1, lw0p, lw1p);
  k_node<<<N_NODES/8, 256, 0, stream>>>(node_input, w_src0,b_src0,w_src1,
                                        w_dst0,b_dst0,w_dst1,
                                        ns_src,ns_dst,nv_src,nv_dst);
  k_edge3<<<N_EDGES/EB, 256, 0, stream>>>(edge_attr, edge_scalars, edge_src, edge_dst,
                                          ns_src,ns_dst,nv_src,nv_dst,
                                          rw1,rb1,rw2,rb2,rw3,rb3,
                                          lw0,lb0,lw0p,lw1p,alpha_dot,
                                          galpha,gval,gm1);
  k_agg<<<N_NODES, 320, 0, stream>>>(edge_dst, galpha, gval, gm1, pw0,pb0,pw1, out);
}

// Round 8
// 378.582 us; speedup vs baseline: 18.2519x; 1.9253x over previous
//
#include <hip/hip_runtime.h>
#include <hip/hip_bf16.h>
#include <math.h>

#define N_NODES 10000
#define N_EDGES 160000
#define EB 16

typedef unsigned short ushort_t;
using f32x4 = __attribute__((ext_vector_type(4))) float;
using s16x8 = __attribute__((ext_vector_type(8))) short;

__device__ __forceinline__ float sigmoidf_(float x){ return 1.f/(1.f+__expf(-x)); }
__device__ __forceinline__ ushort_t f2bf(float x){
  __hip_bfloat16 h = __float2bfloat16(x);
  return *reinterpret_cast<ushort_t*>(&h);
}
__device__ __forceinline__ float bf2f(ushort_t u){
  unsigned int v = ((unsigned int)u)<<16;
  return __uint_as_float(v);
}

// ---- packed-weight ushort offsets (in pk) ----
#define PK_RW1H  0
#define PK_RW1L  4096
#define PK_RW2H  8192
#define PK_RW2L  12288
#define PK_RW3AH 16384
#define PK_RW3AL 28672
#define PK_RW3P  40960
#define PK_LW0AH 57344
#define PK_LW0AL 63488
#define PK_LW0P  69632
#define PK_LW1P  94208
#define PK_TOTAL 110592

// ---------------- k_pack: split/pack all edge-GEMM weights into MFMA frag order ----
// frag layout everywhere: [nt][kt][lane][8]; k = kt*32 + (lane>>4)*8 + i; col = map(nt*16 + (lane&15))
__global__ __launch_bounds__(256) void k_pack(
  const float* __restrict__ rw1, const float* __restrict__ rw2,
  const float* __restrict__ rw3, const float* __restrict__ lw0,
  const float* __restrict__ lw1, ushort_t* __restrict__ pk)
{
  int idx = blockIdx.x*256 + threadIdx.x;
  if (idx < 4096){                                 // rw1 (hi+lo) [4nt][2kt]
    int nt=idx>>10, r=idx&1023, kt=r>>9, q=r&511, l=q>>3, i=q&7;
    int k = kt*32 + (l>>4)*8 + i, col = nt*16 + (l&15);
    float x = rw1[k*64 + col];
    ushort_t hi = f2bf(x);
    pk[PK_RW1H+idx] = hi; pk[PK_RW1L+idx] = f2bf(x - bf2f(hi));
  } else if (idx < 8192){                          // rw2
    int j = idx-4096;
    int nt=j>>10, r=j&1023, kt=r>>9, q=r&511, l=q>>3, i=q&7;
    int k = kt*32 + (l>>4)*8 + i, col = nt*16 + (l&15);
    float x = rw2[k*64 + col];
    ushort_t hi = f2bf(x);
    pk[PK_RW2H+j] = hi; pk[PK_RW2L+j] = f2bf(x - bf2f(hi));
  } else if (idx < 20480){                         // rw3 alpha cols (hi+lo) [12nt][2kt]
    int j = idx-8192;
    int nt=j>>10, r=j&1023, kt=r>>9, q=r&511, l=q>>3, i=q&7;
    int k = kt*32 + (l>>4)*8 + i;
    int col = (nt<8) ? nt*16+(l&15) : 320+(nt-8)*16+(l&15);
    float x = rw3[(size_t)k*448 + col];
    ushort_t hi = f2bf(x);
    pk[PK_RW3AH+j] = hi; pk[PK_RW3AL+j] = f2bf(x - bf2f(hi));
  } else if (idx < 36864){                         // rw3 payload cols (hi) [16nt][2kt]
    int j = idx-20480;
    int nt=j>>10, r=j&1023, kt=r>>9, q=r&511, l=q>>3, i=q&7;
    int k = kt*32 + (l>>4)*8 + i;
    int v = nt*16 + (l&15);
    int col = (v<128) ? 128+v : (v<192) ? 256+(v-128) : 384+(v-192);
    pk[PK_RW3P+j] = f2bf(rw3[(size_t)k*448 + col]);
  } else if (idx < 43008){                         // lw0 alpha cols (hi+lo) [2nt][6kt]
    int j = idx-36864;
    int nt=j/3072, r=j-nt*3072, kt=r>>9, q=r&511, l=q>>3, i=q&7;
    int k = kt*32 + (l>>4)*8 + i;
    int qq = nt*16 + (l&15);
    int col = (qq>>3)*40 + (qq&7);
    float x = lw0[(size_t)k*160 + col];
    ushort_t hi = f2bf(x);
    pk[PK_LW0AH+j] = hi; pk[PK_LW0AL+j] = f2bf(x - bf2f(hi));
  } else if (idx < 67584){                         // lw0 val cols (hi) [8nt][6kt]
    int j = idx-43008;
    int nt=j/3072, r=j-nt*3072, kt=r>>9, q=r&511, l=q>>3, i=q&7;
    int k = kt*32 + (l>>4)*8 + i;
    int v = nt*16 + (l&15);
    int col = (v>>5)*40 + 8 + (v&31);
    pk[PK_LW0P+j] = f2bf(lw0[(size_t)k*160 + col]);
  } else if (idx < 83968){                         // lw1 (hi) [4nt][8kt]
    int j = idx-67584;
    int nt=j>>12, r=j&4095, kt=r>>9, q=r&511, l=q>>3, i=q&7;
    int k = kt*32 + (l>>4)*8 + i, col = nt*16 + (l&15);
    pk[PK_LW1P+j] = f2bf(lw1[(size_t)k*64 + col]);
  }
}

// ---------------- Kernel A: node transforms (unchanged) ----------------
__global__ __launch_bounds__(256) void k_node(
    const float* __restrict__ node_input,
    const float* __restrict__ w_src0, const float* __restrict__ b_src0,
    const float* __restrict__ w_src1,
    const float* __restrict__ w_dst0, const float* __restrict__ b_dst0,
    const float* __restrict__ w_dst1,
    float* __restrict__ ns_src, float* __restrict__ ns_dst,
    float* __restrict__ nv_src, float* __restrict__ nv_dst)
{
  __shared__ float sNI[8*321];
  int t = threadIdx.x;
  int n0 = blockIdx.x*8;
  for (int idx=t; idx<8*320; idx+=256){
    int nd = idx/320, r = idx - nd*320;
    sNI[nd*321+r] = node_input[(size_t)(n0+nd)*320 + r];
  }
  __syncthreads();
  {
    int o = t & 127, half = t >> 7;
    const float* w = half ? w_dst0 : w_src0;
    const float* b = half ? b_dst0 : b_src0;
    float* outp = half ? ns_dst : ns_src;
    float acc[8];
    #pragma unroll
    for (int nd=0;nd<8;nd++) acc[nd]=0.f;
    for (int k=0;k<128;k++){
      float wv = w[k*128+o];
      #pragma unroll
      for (int nd=0;nd<8;nd++) acc[nd] += sNI[nd*321+k]*wv;
    }
    const float rs = 0.08838834764831845f;
    float bo = b[o];
    #pragma unroll
    for (int nd=0;nd<8;nd++) outp[(size_t)(n0+nd)*128+o] = acc[nd]*rs + bo;
  }
  if (t < 192){
    int o = t & 63, c = t >> 6;
    for (int half=0; half<2; half++){
      const float* w = half ? w_dst1 : w_src1;
      float* outp = half ? nv_dst : nv_src;
      float acc[8];
      #pragma unroll
      for (int nd=0;nd<8;nd++) acc[nd]=0.f;
      for (int i=0;i<64;i++){
        float wv = w[i*64+o];
        #pragma unroll
        for (int nd=0;nd<8;nd++) acc[nd] += sNI[nd*321+128+i*3+c]*wv;
      }
      #pragma unroll
      for (int nd=0;nd<8;nd++) outp[(size_t)(n0+nd)*192 + o*3 + c] = acc[nd]*0.125f;
    }
  }
}

// ---------------- Kernel C: all-MFMA edge pipeline ----------------
// LDS float offsets (12960 floats = 51.8KB -> 3 blocks/CU):
#define OEA   0
#define OMV   64
#define OMS   3200
#define FX    5312
#define ESHI_US  (FX*2)
#define ESLO_US  (FX*2+1152)
#define D0HI_US  (FX*2)
#define D0LO_US  (FX*2+3200)
#define D1_US    (FX*2)          /* comp stride 2176 us */
#define FY    8576
#define H1HI_US  (FY*2)
#define H1LO_US  (FY*2+1152)
#define ASV_US   (FY*2)
#define FH2   9728
#define H2HI_US  (FH2*2)
#define H2LO_US  (FH2*2+1152)
#define OBVS  10880
#define OWV1  11920

#define MFMA(a,b,c) __builtin_amdgcn_mfma_f32_16x16x32_bf16((a),(b),(c),0,0,0)

__global__ __launch_bounds__(256) void k_edge4(
  const float* __restrict__ edge_attr, const float* __restrict__ edge_scalars,
  const int* __restrict__ edge_src, const int* __restrict__ edge_dst,
  const float* __restrict__ ns_src, const float* __restrict__ ns_dst,
  const float* __restrict__ nv_src, const float* __restrict__ nv_dst,
  const float* __restrict__ rb1, const float* __restrict__ rb2,
  const float* __restrict__ rb3, const float* __restrict__ lb0,
  const float* __restrict__ alpha_dot,
  const ushort_t* __restrict__ pk,
  float* __restrict__ galpha, __hip_bfloat16* __restrict__ gval,
  __hip_bfloat16* __restrict__ gm1)
{
  __shared__ __align__(16) float L[12960];
  ushort_t* LU = (ushort_t*)L;
  const int t = threadIdx.x;
  const int e0 = blockIdx.x * EB;
  const int lane = t & 63, w = t >> 6;
  const int arow = lane & 15, kg = lane >> 4, c16 = lane & 15;

  // ---- P0: stage ms/mv (f32), es (split bf16), ea (f32) ----
  {
    int e = t>>4, l = t&15;
    int s = edge_src[e0+e], d = edge_dst[e0+e];
    #pragma unroll
    for (int j=0;j<2;j++){
      int idx = l + 16*j;
      float4 a = *(const float4*)&ns_src[(size_t)s*128 + idx*4];
      float4 b = *(const float4*)&ns_dst[(size_t)d*128 + idx*4];
      float4 r; r.x=a.x+b.x; r.y=a.y+b.y; r.z=a.z+b.z; r.w=a.w+b.w;
      *(float4*)&L[OMS + e*132 + idx*4] = r;
    }
    #pragma unroll
    for (int j=0;j<3;j++){
      int idx = l + 16*j;
      float4 a = *(const float4*)&nv_src[(size_t)s*192 + idx*4];
      float4 b = *(const float4*)&nv_dst[(size_t)d*192 + idx*4];
      float4 r; r.x=a.x+b.x; r.y=a.y+b.y; r.z=a.z+b.z; r.w=a.w+b.w;
      *(float4*)&L[OMV + e*196 + idx*4] = r;
    }
    float4 x = *(const float4*)&edge_scalars[(size_t)(e0+e)*64 + l*4];
    ushort4 hi, lo;
    { ushort_t h=f2bf(x.x); hi.x=h; lo.x=f2bf(x.x-bf2f(h)); }
    { ushort_t h=f2bf(x.y); hi.y=h; lo.y=f2bf(x.y-bf2f(h)); }
    { ushort_t h=f2bf(x.z); hi.z=h; lo.z=f2bf(x.z-bf2f(h)); }
    { ushort_t h=f2bf(x.w); hi.w=h; lo.w=f2bf(x.w-bf2f(h)); }
    *(ushort4*)&LU[ESHI_US + e*72 + l*4] = hi;
    *(ushort4*)&LU[ESLO_US + e*72 + l*4] = lo;
  }
  if (t < 64) L[OEA + t] = edge_attr[(size_t)e0*4 + t];
  __syncthreads();

  // ---- P1: h1 = silu(es @ rw1 + rb1), 3-MFMA split, wave w owns N-tile w ----
  {
    s16x8 ah0 = *(const s16x8*)&LU[ESHI_US + arow*72 + 0  + kg*8];
    s16x8 ah1 = *(const s16x8*)&LU[ESHI_US + arow*72 + 32 + kg*8];
    s16x8 al0 = *(const s16x8*)&LU[ESLO_US + arow*72 + 0  + kg*8];
    s16x8 al1 = *(const s16x8*)&LU[ESLO_US + arow*72 + 32 + kg*8];
    f32x4 acc = {0.f,0.f,0.f,0.f};
    s16x8 bh0 = *(const s16x8*)&pk[PK_RW1H + (size_t)((w*2+0)*64+lane)*8];
    s16x8 bl0 = *(const s16x8*)&pk[PK_RW1L + (size_t)((w*2+0)*64+lane)*8];
    s16x8 bh1 = *(const s16x8*)&pk[PK_RW1H + (size_t)((w*2+1)*64+lane)*8];
    s16x8 bl1 = *(const s16x8*)&pk[PK_RW1L + (size_t)((w*2+1)*64+lane)*8];
    acc = MFMA(ah0,bh0,acc); acc = MFMA(ah0,bl0,acc); acc = MFMA(al0,bh0,acc);
    acc = MFMA(ah1,bh1,acc); acc = MFMA(ah1,bl1,acc); acc = MFMA(al1,bh1,acc);
    int col = w*16 + c16;
    float rb = rb1[col];
    #pragma unroll
    for (int r=0;r<4;r++){
      int er = kg*4 + r;
      float v = acc[r] + rb;
      float h = v*sigmoidf_(v);
      ushort_t hi = f2bf(h);
      LU[H1HI_US + er*72 + col] = hi;
      LU[H1LO_US + er*72 + col] = f2bf(h - bf2f(hi));
    }
  }
  __syncthreads();

  // ---- P2: h2 = silu(h1 @ rw2 + rb2) ----
  {
    s16x8 ah0 = *(const s16x8*)&LU[H1HI_US + arow*72 + 0  + kg*8];
    s16x8 ah1 = *(const s16x8*)&LU[H1HI_US + arow*72 + 32 + kg*8];
    s16x8 al0 = *(const s16x8*)&LU[H1LO_US + arow*72 + 0  + kg*8];
    s16x8 al1 = *(const s16x8*)&LU[H1LO_US + arow*72 + 32 + kg*8];
    f32x4 acc = {0.f,0.f,0.f,0.f};
    s16x8 bh0 = *(const s16x8*)&pk[PK_RW2H + (size_t)((w*2+0)*64+lane)*8];
    s16x8 bl0 = *(const s16x8*)&pk[PK_RW2L + (size_t)((w*2+0)*64+lane)*8];
    s16x8 bh1 = *(const s16x8*)&pk[PK_RW2H + (size_t)((w*2+1)*64+lane)*8];
    s16x8 bl1 = *(const s16x8*)&pk[PK_RW2L + (size_t)((w*2+1)*64+lane)*8];
    acc = MFMA(ah0,bh0,acc); acc = MFMA(ah0,bl0,acc); acc = MFMA(al0,bh0,acc);
    acc = MFMA(ah1,bh1,acc); acc = MFMA(ah1,bl1,acc); acc = MFMA(al1,bh1,acc);
    int col = w*16 + c16;
    float rb = rb2[col];
    #pragma unroll
    for (int r=0;r<4;r++){
      int er = kg*4 + r;
      float v = acc[r] + rb;
      float h = v*sigmoidf_(v);
      ushort_t hi = f2bf(h);
      LU[H2HI_US + er*72 + col] = hi;
      LU[H2LO_US + er*72 + col] = f2bf(h - bf2f(hi));
    }
  }
  __syncthreads();

  // ---- P3: w = h2 @ rw3 + rb3 (alpha cols 3-MFMA, payload cols 1-MFMA) ----
  {
    s16x8 ah0 = *(const s16x8*)&LU[H2HI_US + arow*72 + 0  + kg*8];
    s16x8 ah1 = *(const s16x8*)&LU[H2HI_US + arow*72 + 32 + kg*8];
    s16x8 al0 = *(const s16x8*)&LU[H2LO_US + arow*72 + 0  + kg*8];
    s16x8 al1 = *(const s16x8*)&LU[H2LO_US + arow*72 + 32 + kg*8];

    if (w < 3){
      #pragma unroll
      for (int ai=0; ai<4; ai++){
        int a = w*4 + ai;
        f32x4 acc = {0.f,0.f,0.f,0.f};
        s16x8 bh0 = *(const s16x8*)&pk[PK_RW3AH + (size_t)((a*2+0)*64+lane)*8];
        s16x8 bl0 = *(const s16x8*)&pk[PK_RW3AL + (size_t)((a*2+0)*64+lane)*8];
        s16x8 bh1 = *(const s16x8*)&pk[PK_RW3AH + (size_t)((a*2+1)*64+lane)*8];
        s16x8 bl1 = *(const s16x8*)&pk[PK_RW3AL + (size_t)((a*2+1)*64+lane)*8];
        acc = MFMA(ah0,bh0,acc); acc = MFMA(ah0,bl0,acc); acc = MFMA(al0,bh0,acc);
        acc = MFMA(ah1,bh1,acc); acc = MFMA(ah1,bl1,acc); acc = MFMA(al1,bh1,acc);
        if (a < 8){
          int i = a*16 + c16;
          float b3 = rb3[i];
          #pragma unroll
          for (int r=0;r<4;r++){
            int er = kg*4 + r;
            float d0v = (acc[r]+b3) * L[OMS + er*132 + i] * L[OEA + er*4];
            ushort_t hi = f2bf(d0v);
            LU[D0HI_US + er*200 + i] = hi;
            LU[D0LO_US + er*200 + i] = f2bf(d0v - bf2f(hi));
          }
        } else {
          int j = (a-8)*16 + c16;
          float b3 = rb3[320 + j];
          #pragma unroll
          for (int r=0;r<4;r++){
            int er = kg*4 + r;
            float dot = L[OMV+er*196+j*3+0]*L[OEA+er*4+1]
                      + L[OMV+er*196+j*3+1]*L[OEA+er*4+2]
                      + L[OMV+er*196+j*3+2]*L[OEA+er*4+3];
            float d0v = (acc[r]+b3) * dot * 0.5773502691896258f;
            ushort_t hi = f2bf(d0v);
            LU[D0HI_US + er*200 + 128 + j] = hi;
            LU[D0LO_US + er*200 + 128 + j] = f2bf(d0v - bf2f(hi));
          }
        }
      }
      // one payload tile
      {
        int p = w;
        f32x4 acc = {0.f,0.f,0.f,0.f};
        s16x8 b0 = *(const s16x8*)&pk[PK_RW3P + (size_t)((p*2+0)*64+lane)*8];
        s16x8 b1 = *(const s16x8*)&pk[PK_RW3P + (size_t)((p*2+1)*64+lane)*8];
        acc = MFMA(ah0,b0,acc); acc = MFMA(ah1,b1,acc);
        int q = p*16 + c16;   // p<3 -> q<48 -> always asv branch
        float b3 = rb3[128 + q];
        #pragma unroll
        for (int r=0;r<4;r++){
          int er = kg*4 + r;
          LU[ASV_US + er*136 + q] = f2bf((acc[r]+b3) * L[OMS + er*132 + q]);
        }
      }
    } else {
      #pragma unroll 1
      for (int p=3; p<16; p++){
        f32x4 acc = {0.f,0.f,0.f,0.f};
        s16x8 b0 = *(const s16x8*)&pk[PK_RW3P + (size_t)((p*2+0)*64+lane)*8];
        s16x8 b1 = *(const s16x8*)&pk[PK_RW3P + (size_t)((p*2+1)*64+lane)*8];
        acc = MFMA(ah0,b0,acc); acc = MFMA(ah1,b1,acc);
        int q = p*16 + c16;
        if (q < 128){
          float b3 = rb3[128 + q];
          #pragma unroll
          for (int r=0;r<4;r++){
            int er = kg*4 + r;
            LU[ASV_US + er*136 + q] = f2bf((acc[r]+b3) * L[OMS + er*132 + q]);
          }
        } else if (q < 192){
          float b3 = rb3[256 + (q-128)];
          #pragma unroll
          for (int r=0;r<4;r++){
            int er = kg*4 + r;
            L[OBVS + er*65 + (q-128)] = (acc[r]+b3) * L[OEA + er*4];
          }
        } else {
          float b3 = rb3[384 + (q-192)];
          #pragma unroll
          for (int r=0;r<4;r++){
            int er = kg*4 + r;
            L[OWV1 + er*65 + (q-192)] = (acc[r]+b3) * 0.7071067811865476f;
          }
        }
      }
    }
  }
  __syncthreads();

  // ---- P4: waves 0,1 -> alpha logits (3-MFMA); waves 2,3 -> val (1-MFMA) ----
  const float rs192 = 0.07216878364870323f;
  if (w < 2){
    int nt = w;
    s16x8 ah[6], al[6];
    #pragma unroll
    for (int kt=0;kt<6;kt++){
      ah[kt] = *(const s16x8*)&LU[D0HI_US + arow*200 + kt*32 + kg*8];
      al[kt] = *(const s16x8*)&LU[D0LO_US + arow*200 + kt*32 + kg*8];
    }
    f32x4 acc = {0.f,0.f,0.f,0.f};
    #pragma unroll
    for (int kt=0;kt<6;kt++){
      s16x8 bh = *(const s16x8*)&pk[PK_LW0AH + (size_t)((nt*6+kt)*64+lane)*8];
      s16x8 bl = *(const s16x8*)&pk[PK_LW0AL + (size_t)((nt*6+kt)*64+lane)*8];
      acc = MFMA(ah[kt],bh,acc); acc = MFMA(ah[kt],bl,acc); acc = MFMA(al[kt],bh,acc);
    }
    int q = nt*16 + c16;
    int realcol = (q>>3)*40 + (q&7);
    float lbv = lb0[realcol];
    float ad  = alpha_dot[q];
    #pragma unroll
    for (int r=0;r<4;r++){
      float m = acc[r]*rs192 + lbv;
      float p = (0.6f*m + 0.4f*m*(2.f*sigmoidf_(m)-1.f))*ad;
      p += __shfl_xor(p, 1);
      p += __shfl_xor(p, 2);
      p += __shfl_xor(p, 4);
      if ((lane&7)==0){
        int er = kg*4 + r;
        galpha[(size_t)(e0+er)*4 + (q>>3)] = p;
      }
    }
  } else {
    s16x8 af[6];
    #pragma unroll
    for (int kt=0;kt<6;kt++)
      af[kt] = *(const s16x8*)&LU[D0HI_US + arow*200 + kt*32 + kg*8];
    #pragma unroll
    for (int j=0;j<4;j++){
      int v = (w-2)*4 + j;
      f32x4 acc = {0.f,0.f,0.f,0.f};
      #pragma unroll
      for (int kt=0;kt<6;kt++){
        s16x8 b = *(const s16x8*)&pk[PK_LW0P + (size_t)((v*6+kt)*64+lane)*8];
        acc = MFMA(af[kt],b,acc);
      }
      int q = v*16 + c16;
      int realcol = (q>>5)*40 + 8 + (q&31);
      float lbv = lb0[realcol];
      #pragma unroll
      for (int r=0;r<4;r++){
        int er = kg*4 + r;
        gval[(size_t)(e0+er)*128 + q] = __float2bfloat16(acc[r]*rs192 + lbv);
      }
    }
  }
  __syncthreads();

  // ---- P5-prep: d1 rows 128..255 per component, bf16 ----
  for (int idx=t; idx<6144; idx+=256){
    int c = idx>>11, rem = idx&2047, e = rem>>7, i = rem&127;
    float v;
    if (i < 64){
      v = L[OBVS + e*65 + i] * L[OMV + e*196 + i*3 + c];
    } else {
      int ii = i-64;
      int ca = (c+1)%3, cb = (c+2)%3;
      v = L[OWV1 + e*65 + ii] *
          (L[OMV+e*196+ii*3+ca]*L[OEA+e*4+1+cb] - L[OMV+e*196+ii*3+cb]*L[OEA+e*4+1+ca]);
    }
    LU[D1_US + c*2176 + e*136 + i] = f2bf(v);
  }
  __syncthreads();

  // ---- P5: m1_c = concat(asv*ev_c, d1_c) @ lw1; wave w owns N-tile w ----
  {
    int nt = w;
    float ev0 = L[OEA + arow*4 + 1];
    float ev1 = L[OEA + arow*4 + 2];
    float ev2 = L[OEA + arow*4 + 3];
    f32x4 acc0 = {0.f,0.f,0.f,0.f}, acc1 = {0.f,0.f,0.f,0.f}, acc2 = {0.f,0.f,0.f,0.f};
    #pragma unroll
    for (int kt=0; kt<4; kt++){
      s16x8 raw = *(const s16x8*)&LU[ASV_US + arow*136 + kt*32 + kg*8];
      s16x8 a0, a1, a2;
      #pragma unroll
      for (int i=0;i<8;i++){
        float x = bf2f((ushort_t)raw[i]);
        a0[i] = (short)f2bf(x*ev0);
        a1[i] = (short)f2bf(x*ev1);
        a2[i] = (short)f2bf(x*ev2);
      }
      s16x8 b = *(const s16x8*)&pk[PK_LW1P + (size_t)((nt*8+kt)*64+lane)*8];
      acc0 = MFMA(a0,b,acc0); acc1 = MFMA(a1,b,acc1); acc2 = MFMA(a2,b,acc2);
    }
    #pragma unroll
    for (int kt=4; kt<8; kt++){
      s16x8 b = *(const s16x8*)&pk[PK_LW1P + (size_t)((nt*8+kt)*64+lane)*8];
      s16x8 af0 = *(const s16x8*)&LU[D1_US + 0*2176 + arow*136 + (kt-4)*32 + kg*8];
      s16x8 af1 = *(const s16x8*)&LU[D1_US + 1*2176 + arow*136 + (kt-4)*32 + kg*8];
      s16x8 af2 = *(const s16x8*)&LU[D1_US + 2*2176 + arow*136 + (kt-4)*32 + kg*8];
      acc0 = MFMA(af0,b,acc0); acc1 = MFMA(af1,b,acc1); acc2 = MFMA(af2,b,acc2);
    }
    const float r16 = 0.0625f;
    int col = nt*16 + c16;
    #pragma unroll
    for (int r=0;r<4;r++){
      int er = kg*4 + r;
      gm1[((size_t)(e0+er)*3 + 0)*64 + col] = __float2bfloat16(acc0[r]*r16);
      gm1[((size_t)(e0+er)*3 + 1)*64 + col] = __float2bfloat16(acc1[r]*r16);
      gm1[((size_t)(e0+er)*3 + 2)*64 + col] = __float2bfloat16(acc2[r]*r16);
    }
  }
}

// ---------------- Kernel D: per-dst softmax + aggregation (unchanged) ----------------
__global__ __launch_bounds__(320) void k_agg(
  const int* __restrict__ edge_dst,
  const float* __restrict__ galpha, const __hip_bfloat16* __restrict__ gval,
  const __hip_bfloat16* __restrict__ gm1,
  const float* __restrict__ pw0, const float* __restrict__ pb0,
  const float* __restrict__ pw1,
  float* __restrict__ out)
{
  __shared__ float sRed[256], sW[256], sAm[4], sInv[4], sNS[128], sNV[192];
  int t = threadIdx.x;
  int n = blockIdx.x;
  int lo, hi;
  {
    int a=0,b=N_EDGES;
    while(a<b){int m=(a+b)>>1; if (edge_dst[m] < n) a=m+1; else b=m;}
    lo=a; a=lo; b=N_EDGES;
    while(a<b){int m=(a+b)>>1; if (edge_dst[m] < n+1) a=m+1; else b=m;}
    hi=a;
  }
  if (t < 256){
    int g=t>>2, h=t&3;
    float m=-1e30f;
    for (int e=lo+g; e<hi; e+=64) m = fmaxf(m, galpha[(size_t)e*4+h]);
    sRed[t]=m;
  }
  __syncthreads();
  for (int s=32; s>=1; s>>=1){
    if (t < s*4) sRed[t] = fmaxf(sRed[t], sRed[t+s*4]);
    __syncthreads();
  }
  if (t<4) sAm[t] = (hi>lo) ? sRed[t] : 0.f;
  __syncthreads();
  if (t < 256){
    int g=t>>2, h=t&3; float ssum=0.f;
    for (int e=lo+g; e<hi; e+=64) ssum += __expf(galpha[(size_t)e*4+h]-sAm[h]);
    sRed[t]=ssum;
  }
  __syncthreads();
  for (int s=32; s>=1; s>>=1){
    if (t < s*4) sRed[t] += sRed[t+s*4];
    __syncthreads();
  }
  if (t<4) sInv[t] = 1.f / fmaxf(sRed[t], 1e-12f);
  __syncthreads();
  float acc = 0.f;
  int cq=0, oq=0, hq=0;
  if (t < 128){ hq = t>>5; }
  else { int q=t-128; cq=q>>6; oq=q&63; hq=oq>>4; }
  for (int base=lo; base<hi; base+=64){
    int nn = min(64, hi-base);
    if (t < 256){ int j=t>>2,h=t&3; if (j<nn) sW[t] = __expf(galpha[(size_t)(base+j)*4+h]-sAm[h])*sInv[h]; }
    __syncthreads();
    if (t < 128){
      for (int j=0;j<nn;j++) acc += sW[j*4+hq]*__bfloat162float(gval[(size_t)(base+j)*128+t]);
    } else {
      for (int j=0;j<nn;j++) acc += sW[j*4+hq]*__bfloat162float(gm1[(size_t)((size_t)(base+j)*3+cq)*64+oq]);
    }
    __syncthreads();
  }
  if (t < 128) sNS[t]=acc; else sNV[oq*3+cq]=acc;
  __syncthreads();
  if (t < 128){
    float a = 0.f;
    for (int k=0;k<128;k++) a += sNS[k]*pw0[k*128+t];
    out[(size_t)n*320+t] = a*0.08838834764831845f + pb0[t];
  } else {
    float a = 0.f;
    for (int i=0;i<64;i++) a += sNV[i*3+cq]*pw1[i*64+oq];
    out[(size_t)n*320+128+oq*3+cq] = a*0.125f;
  }
}

extern "C" void kernel_launch(void* const* d_in, const int* in_sizes, int n_in,
                              void* d_out, int out_size, void* d_ws, size_t ws_size,
                              hipStream_t stream)
{
  const float* node_input  = (const float*)d_in[0];
  const float* edge_attr   = (const float*)d_in[1];
  const float* edge_scalars= (const float*)d_in[2];
  const int*   edge_src    = (const int*)d_in[3];
  const int*   edge_dst    = (const int*)d_in[4];
  const float* w_src0=(const float*)d_in[5];  const float* b_src0=(const float*)d_in[6];
  const float* w_src1=(const float*)d_in[7];
  const float* w_dst0=(const float*)d_in[8];  const float* b_dst0=(const float*)d_in[9];
  const float* w_dst1=(const float*)d_in[10];
  const float* rw1=(const float*)d_in[11];    const float* rb1=(const float*)d_in[12];
  const float* rw2=(const float*)d_in[13];    const float* rb2=(const float*)d_in[14];
  const float* rw3=(const float*)d_in[15];    const float* rb3=(const float*)d_in[16];
  const float* lw0=(const float*)d_in[17];    const float* lb0=(const float*)d_in[18];
  const float* lw1=(const float*)d_in[19];
  const float* alpha_dot=(const float*)d_in[20];
  const float* pw0=(const float*)d_in[21];    const float* pb0=(const float*)d_in[22];
  const float* pw1=(const float*)d_in[23];
  float* out = (float*)d_out;

  float* ns_src = (float*)d_ws;
  float* ns_dst = ns_src + (size_t)N_NODES*128;
  float* nv_src = ns_dst + (size_t)N_NODES*128;
  float* nv_dst = nv_src + (size_t)N_NODES*192;
  float* galpha = nv_dst + (size_t)N_NODES*192;
  __hip_bfloat16* gval = (__hip_bfloat16*)(galpha + (size_t)N_EDGES*4);
  __hip_bfloat16* gm1  = gval + (size_t)N_EDGES*128;
  ushort_t* pk = (ushort_t*)(gm1 + (size_t)N_EDGES*192);

  k_pack<<<328, 256, 0, stream>>>(rw1, rw2, rw3, lw0, lw1, pk);
  k_node<<<N_NODES/8, 256, 0, stream>>>(node_input, w_src0,b_src0,w_src1,
                                        w_dst0,b_dst0,w_dst1,
                                        ns_src,ns_dst,nv_src,nv_dst);
  k_edge4<<<N_EDGES/EB, 256, 0, stream>>>(edge_attr, edge_scalars, edge_src, edge_dst,
                                          ns_src,ns_dst,nv_src,nv_dst,
                                          rb1,rb2,rb3,lb0,alpha_dot,pk,
                                          galpha,gval,gm1);
  k_agg<<<N_NODES, 320, 0, stream>>>(edge_dst, galpha, gval, gm1, pw0,pb0,pw1, out);
}

// Round 9
// 351.430 us; speedup vs baseline: 19.6620x; 1.0773x over previous
//
#include <hip/hip_runtime.h>
#include <hip/hip_bf16.h>
#include <math.h>

#define N_NODES 10000
#define N_EDGES 160000
#define EB 16

typedef unsigned short ushort_t;
using f32x4 = __attribute__((ext_vector_type(4))) float;
using s16x8 = __attribute__((ext_vector_type(8))) short;

__device__ __forceinline__ float sigmoidf_(float x){ return 1.f/(1.f+__expf(-x)); }
__device__ __forceinline__ ushort_t f2bf(float x){
  __hip_bfloat16 h = __float2bfloat16(x);
  return *reinterpret_cast<ushort_t*>(&h);
}
__device__ __forceinline__ float bf2f(ushort_t u){
  unsigned int v = ((unsigned int)u)<<16;
  return __uint_as_float(v);
}

// ---- packed-weight ushort offsets (in pk) ----
#define PK_RW1H  0
#define PK_RW1L  4096
#define PK_RW2H  8192
#define PK_RW2L  12288
#define PK_RW3AH 16384
#define PK_RW3AL 28672
#define PK_RW3P  40960
#define PK_LW0AH 57344
#define PK_LW0AL 63488
#define PK_LW0P  69632
#define PK_LW1P  94208
#define PK_TOTAL 110592

// ---------------- k_pack (unchanged from round 8) ----------------
__global__ __launch_bounds__(256) void k_pack(
  const float* __restrict__ rw1, const float* __restrict__ rw2,
  const float* __restrict__ rw3, const float* __restrict__ lw0,
  const float* __restrict__ lw1, ushort_t* __restrict__ pk)
{
  int idx = blockIdx.x*256 + threadIdx.x;
  if (idx < 4096){
    int nt=idx>>10, r=idx&1023, kt=r>>9, q=r&511, l=q>>3, i=q&7;
    int k = kt*32 + (l>>4)*8 + i, col = nt*16 + (l&15);
    float x = rw1[k*64 + col];
    ushort_t hi = f2bf(x);
    pk[PK_RW1H+idx] = hi; pk[PK_RW1L+idx] = f2bf(x - bf2f(hi));
  } else if (idx < 8192){
    int j = idx-4096;
    int nt=j>>10, r=j&1023, kt=r>>9, q=r&511, l=q>>3, i=q&7;
    int k = kt*32 + (l>>4)*8 + i, col = nt*16 + (l&15);
    float x = rw2[k*64 + col];
    ushort_t hi = f2bf(x);
    pk[PK_RW2H+j] = hi; pk[PK_RW2L+j] = f2bf(x - bf2f(hi));
  } else if (idx < 20480){
    int j = idx-8192;
    int nt=j>>10, r=j&1023, kt=r>>9, q=r&511, l=q>>3, i=q&7;
    int k = kt*32 + (l>>4)*8 + i;
    int col = (nt<8) ? nt*16+(l&15) : 320+(nt-8)*16+(l&15);
    float x = rw3[(size_t)k*448 + col];
    ushort_t hi = f2bf(x);
    pk[PK_RW3AH+j] = hi; pk[PK_RW3AL+j] = f2bf(x - bf2f(hi));
  } else if (idx < 36864){
    int j = idx-20480;
    int nt=j>>10, r=j&1023, kt=r>>9, q=r&511, l=q>>3, i=q&7;
    int k = kt*32 + (l>>4)*8 + i;
    int v = nt*16 + (l&15);
    int col = (v<128) ? 128+v : (v<192) ? 256+(v-128) : 384+(v-192);
    pk[PK_RW3P+j] = f2bf(rw3[(size_t)k*448 + col]);
  } else if (idx < 43008){
    int j = idx-36864;
    int nt=j/3072, r=j-nt*3072, kt=r>>9, q=r&511, l=q>>3, i=q&7;
    int k = kt*32 + (l>>4)*8 + i;
    int qq = nt*16 + (l&15);
    int col = (qq>>3)*40 + (qq&7);
    float x = lw0[(size_t)k*160 + col];
    ushort_t hi = f2bf(x);
    pk[PK_LW0AH+j] = hi; pk[PK_LW0AL+j] = f2bf(x - bf2f(hi));
  } else if (idx < 67584){
    int j = idx-43008;
    int nt=j/3072, r=j-nt*3072, kt=r>>9, q=r&511, l=q>>3, i=q&7;
    int k = kt*32 + (l>>4)*8 + i;
    int v = nt*16 + (l&15);
    int col = (v>>5)*40 + 8 + (v&31);
    pk[PK_LW0P+j] = f2bf(lw0[(size_t)k*160 + col]);
  } else if (idx < 83968){
    int j = idx-67584;
    int nt=j>>12, r=j&4095, kt=r>>9, q=r&511, l=q>>3, i=q&7;
    int k = kt*32 + (l>>4)*8 + i, col = nt*16 + (l&15);
    pk[PK_LW1P+j] = f2bf(lw1[(size_t)k*64 + col]);
  }
}

// ---------------- Kernel A: node transforms (unchanged) ----------------
__global__ __launch_bounds__(256) void k_node(
    const float* __restrict__ node_input,
    const float* __restrict__ w_src0, const float* __restrict__ b_src0,
    const float* __restrict__ w_src1,
    const float* __restrict__ w_dst0, const float* __restrict__ b_dst0,
    const float* __restrict__ w_dst1,
    float* __restrict__ ns_src, float* __restrict__ ns_dst,
    float* __restrict__ nv_src, float* __restrict__ nv_dst)
{
  __shared__ float sNI[8*321];
  int t = threadIdx.x;
  int n0 = blockIdx.x*8;
  for (int idx=t; idx<8*320; idx+=256){
    int nd = idx/320, r = idx - nd*320;
    sNI[nd*321+r] = node_input[(size_t)(n0+nd)*320 + r];
  }
  __syncthreads();
  {
    int o = t & 127, half = t >> 7;
    const float* w = half ? w_dst0 : w_src0;
    const float* b = half ? b_dst0 : b_src0;
    float* outp = half ? ns_dst : ns_src;
    float acc[8];
    #pragma unroll
    for (int nd=0;nd<8;nd++) acc[nd]=0.f;
    for (int k=0;k<128;k++){
      float wv = w[k*128+o];
      #pragma unroll
      for (int nd=0;nd<8;nd++) acc[nd] += sNI[nd*321+k]*wv;
    }
    const float rs = 0.08838834764831845f;
    float bo = b[o];
    #pragma unroll
    for (int nd=0;nd<8;nd++) outp[(size_t)(n0+nd)*128+o] = acc[nd]*rs + bo;
  }
  if (t < 192){
    int o = t & 63, c = t >> 6;
    for (int half=0; half<2; half++){
      const float* w = half ? w_dst1 : w_src1;
      float* outp = half ? nv_dst : nv_src;
      float acc[8];
      #pragma unroll
      for (int nd=0;nd<8;nd++) acc[nd]=0.f;
      for (int i=0;i<64;i++){
        float wv = w[i*64+o];
        #pragma unroll
        for (int nd=0;nd<8;nd++) acc[nd] += sNI[nd*321+128+i*3+c]*wv;
      }
      #pragma unroll
      for (int nd=0;nd<8;nd++) outp[(size_t)(n0+nd)*192 + o*3 + c] = acc[nd]*0.125f;
    }
  }
}

// ---------------- Kernel C: all-MFMA edge pipeline, v2 ----------------
// LDS float offsets (13184 floats = 52.7KB -> 3 blocks/CU):
#define OEA   0       // 64
#define OMV   64      // mvT: e*204 + c*68 + i  (3264)
#define OMS   3328    // e*132 (2112)
#define FX    5440    // X region: ES(P0-P1) / D0(P3-P4) / D1(P5)  (3264)
#define ESHI_US  (FX*2)
#define ESLO_US  (FX*2+1152)
#define D0HI_US  (FX*2)
#define D0LO_US  (FX*2+3200)
#define D1_US    (FX*2)          /* comp stride 2176 us */
#define FY    8704    // H1(P1-P2) / ASV(P3-P5)  (1152)
#define H1HI_US  (FY*2)
#define H1LO_US  (FY*2+1152)
#define ASV_US   (FY*2)          /* 2176 us, ends 19584 < H2HI 19712 */
#define FH2   9856   // H2 (1152)
#define H2HI_US  (FH2*2)
#define H2LO_US  (FH2*2+1152)
#define OBVS  11008   // e*68 (1088)
#define OWV1  12096   // e*68 (1088)

#define MFMA(a,b,c) __builtin_amdgcn_mfma_f32_16x16x32_bf16((a),(b),(c),0,0,0)

__global__ __launch_bounds__(256) void k_edge5(
  const float* __restrict__ edge_attr, const float* __restrict__ edge_scalars,
  const int* __restrict__ edge_src, const int* __restrict__ edge_dst,
  const float* __restrict__ ns_src, const float* __restrict__ ns_dst,
  const float* __restrict__ nv_src, const float* __restrict__ nv_dst,
  const float* __restrict__ rb1, const float* __restrict__ rb2,
  const float* __restrict__ rb3, const float* __restrict__ lb0,
  const float* __restrict__ alpha_dot,
  const ushort_t* __restrict__ pk,
  float* __restrict__ galpha, __hip_bfloat16* __restrict__ gval,
  __hip_bfloat16* __restrict__ gm1)
{
  __shared__ __align__(16) float L[13184];
  ushort_t* LU = (ushort_t*)L;
  const int t = threadIdx.x;
  const int e0 = blockIdx.x * EB;
  const int lane = t & 63, w = t >> 6;
  const int arow = lane & 15, kg = lane >> 4, c16 = lane & 15;

  // ---- P0: stage ms (f32), mvT (f32, comp-major), es (split bf16), ea ----
  {
    int e = t>>4, l = t&15;
    int s = edge_src[e0+e], d = edge_dst[e0+e];
    #pragma unroll
    for (int j=0;j<2;j++){
      int idx = l + 16*j;
      float4 a = *(const float4*)&ns_src[(size_t)s*128 + idx*4];
      float4 b = *(const float4*)&ns_dst[(size_t)d*128 + idx*4];
      float4 r; r.x=a.x+b.x; r.y=a.y+b.y; r.z=a.z+b.z; r.w=a.w+b.w;
      *(float4*)&L[OMS + e*132 + idx*4] = r;
    }
    // mv transposed: this lane covers i in [l*4, l*4+4), all 3 comps
    float f[12];
    #pragma unroll
    for (int j=0;j<3;j++){
      float4 a = *(const float4*)&nv_src[(size_t)s*192 + l*12 + j*4];
      float4 b = *(const float4*)&nv_dst[(size_t)d*192 + l*12 + j*4];
      f[j*4+0]=a.x+b.x; f[j*4+1]=a.y+b.y; f[j*4+2]=a.z+b.z; f[j*4+3]=a.w+b.w;
    }
    #pragma unroll
    for (int c=0;c<3;c++){
      float4 r; r.x=f[c]; r.y=f[3+c]; r.z=f[6+c]; r.w=f[9+c];
      *(float4*)&L[OMV + e*204 + c*68 + l*4] = r;
    }
    float4 x = *(const float4*)&edge_scalars[(size_t)(e0+e)*64 + l*4];
    ushort4 hi, lo;
    { ushort_t h=f2bf(x.x); hi.x=h; lo.x=f2bf(x.x-bf2f(h)); }
    { ushort_t h=f2bf(x.y); hi.y=h; lo.y=f2bf(x.y-bf2f(h)); }
    { ushort_t h=f2bf(x.z); hi.z=h; lo.z=f2bf(x.z-bf2f(h)); }
    { ushort_t h=f2bf(x.w); hi.w=h; lo.w=f2bf(x.w-bf2f(h)); }
    *(ushort4*)&LU[ESHI_US + e*72 + l*4] = hi;
    *(ushort4*)&LU[ESLO_US + e*72 + l*4] = lo;
  }
  if (t < 64) L[OEA + t] = edge_attr[(size_t)e0*4 + t];
  __syncthreads();

  // ---- P1: h1 = silu(es @ rw1 + rb1), 3-MFMA split ----
  {
    s16x8 ah0 = *(const s16x8*)&LU[ESHI_US + arow*72 + 0  + kg*8];
    s16x8 ah1 = *(const s16x8*)&LU[ESHI_US + arow*72 + 32 + kg*8];
    s16x8 al0 = *(const s16x8*)&LU[ESLO_US + arow*72 + 0  + kg*8];
    s16x8 al1 = *(const s16x8*)&LU[ESLO_US + arow*72 + 32 + kg*8];
    f32x4 acc = {0.f,0.f,0.f,0.f};
    s16x8 bh0 = *(const s16x8*)&pk[PK_RW1H + (size_t)((w*2+0)*64+lane)*8];
    s16x8 bl0 = *(const s16x8*)&pk[PK_RW1L + (size_t)((w*2+0)*64+lane)*8];
    s16x8 bh1 = *(const s16x8*)&pk[PK_RW1H + (size_t)((w*2+1)*64+lane)*8];
    s16x8 bl1 = *(const s16x8*)&pk[PK_RW1L + (size_t)((w*2+1)*64+lane)*8];
    acc = MFMA(ah0,bh0,acc); acc = MFMA(ah0,bl0,acc); acc = MFMA(al0,bh0,acc);
    acc = MFMA(ah1,bh1,acc); acc = MFMA(ah1,bl1,acc); acc = MFMA(al1,bh1,acc);
    int col = w*16 + c16;
    float rb = rb1[col];
    #pragma unroll
    for (int r=0;r<4;r++){
      int er = kg*4 + r;
      float v = acc[r] + rb;
      float h = v*sigmoidf_(v);
      ushort_t hi = f2bf(h);
      LU[H1HI_US + er*72 + col] = hi;
      LU[H1LO_US + er*72 + col] = f2bf(h - bf2f(hi));
    }
  }
  __syncthreads();

  // ---- P2: h2 = silu(h1 @ rw2 + rb2) ----
  {
    s16x8 ah0 = *(const s16x8*)&LU[H1HI_US + arow*72 + 0  + kg*8];
    s16x8 ah1 = *(const s16x8*)&LU[H1HI_US + arow*72 + 32 + kg*8];
    s16x8 al0 = *(const s16x8*)&LU[H1LO_US + arow*72 + 0  + kg*8];
    s16x8 al1 = *(const s16x8*)&LU[H1LO_US + arow*72 + 32 + kg*8];
    f32x4 acc = {0.f,0.f,0.f,0.f};
    s16x8 bh0 = *(const s16x8*)&pk[PK_RW2H + (size_t)((w*2+0)*64+lane)*8];
    s16x8 bl0 = *(const s16x8*)&pk[PK_RW2L + (size_t)((w*2+0)*64+lane)*8];
    s16x8 bh1 = *(const s16x8*)&pk[PK_RW2H + (size_t)((w*2+1)*64+lane)*8];
    s16x8 bl1 = *(const s16x8*)&pk[PK_RW2L + (size_t)((w*2+1)*64+lane)*8];
    acc = MFMA(ah0,bh0,acc); acc = MFMA(ah0,bl0,acc); acc = MFMA(al0,bh0,acc);
    acc = MFMA(ah1,bh1,acc); acc = MFMA(ah1,bl1,acc); acc = MFMA(al1,bh1,acc);
    int col = w*16 + c16;
    float rb = rb2[col];
    #pragma unroll
    for (int r=0;r<4;r++){
      int er = kg*4 + r;
      float v = acc[r] + rb;
      float h = v*sigmoidf_(v);
      ushort_t hi = f2bf(h);
      LU[H2HI_US + er*72 + col] = hi;
      LU[H2LO_US + er*72 + col] = f2bf(h - bf2f(hi));
    }
  }
  __syncthreads();

  // ---- P3: w = h2 @ rw3 + rb3 (alpha cols 3-MFMA, payload cols 1-MFMA) ----
  {
    s16x8 ah0 = *(const s16x8*)&LU[H2HI_US + arow*72 + 0  + kg*8];
    s16x8 ah1 = *(const s16x8*)&LU[H2HI_US + arow*72 + 32 + kg*8];
    s16x8 al0 = *(const s16x8*)&LU[H2LO_US + arow*72 + 0  + kg*8];
    s16x8 al1 = *(const s16x8*)&LU[H2LO_US + arow*72 + 32 + kg*8];

    if (w < 3){
      #pragma unroll
      for (int ai=0; ai<4; ai++){
        int a = w*4 + ai;
        f32x4 acc = {0.f,0.f,0.f,0.f};
        s16x8 bh0 = *(const s16x8*)&pk[PK_RW3AH + (size_t)((a*2+0)*64+lane)*8];
        s16x8 bl0 = *(const s16x8*)&pk[PK_RW3AL + (size_t)((a*2+0)*64+lane)*8];
        s16x8 bh1 = *(const s16x8*)&pk[PK_RW3AH + (size_t)((a*2+1)*64+lane)*8];
        s16x8 bl1 = *(const s16x8*)&pk[PK_RW3AL + (size_t)((a*2+1)*64+lane)*8];
        acc = MFMA(ah0,bh0,acc); acc = MFMA(ah0,bl0,acc); acc = MFMA(al0,bh0,acc);
        acc = MFMA(ah1,bh1,acc); acc = MFMA(ah1,bl1,acc); acc = MFMA(al1,bh1,acc);
        if (a < 8){
          int i = a*16 + c16;
          float b3 = rb3[i];
          #pragma unroll
          for (int r=0;r<4;r++){
            int er = kg*4 + r;
            float d0v = (acc[r]+b3) * L[OMS + er*132 + i] * L[OEA + er*4];
            ushort_t hi = f2bf(d0v);
            LU[D0HI_US + er*200 + i] = hi;
            LU[D0LO_US + er*200 + i] = f2bf(d0v - bf2f(hi));
          }
        } else {
          int j = (a-8)*16 + c16;
          float b3 = rb3[320 + j];
          #pragma unroll
          for (int r=0;r<4;r++){
            int er = kg*4 + r;
            float dot = L[OMV+er*204      +j]*L[OEA+er*4+1]
                      + L[OMV+er*204+ 68  +j]*L[OEA+er*4+2]
                      + L[OMV+er*204+136  +j]*L[OEA+er*4+3];
            float d0v = (acc[r]+b3) * dot * 0.5773502691896258f;
            ushort_t hi = f2bf(d0v);
            LU[D0HI_US + er*200 + 128 + j] = hi;
            LU[D0LO_US + er*200 + 128 + j] = f2bf(d0v - bf2f(hi));
          }
        }
      }
      {
        int p = w;
        f32x4 acc = {0.f,0.f,0.f,0.f};
        s16x8 b0 = *(const s16x8*)&pk[PK_RW3P + (size_t)((p*2+0)*64+lane)*8];
        s16x8 b1 = *(const s16x8*)&pk[PK_RW3P + (size_t)((p*2+1)*64+lane)*8];
        acc = MFMA(ah0,b0,acc); acc = MFMA(ah1,b1,acc);
        int q = p*16 + c16;
        float b3 = rb3[128 + q];
        #pragma unroll
        for (int r=0;r<4;r++){
          int er = kg*4 + r;
          LU[ASV_US + er*136 + q] = f2bf((acc[r]+b3) * L[OMS + er*132 + q]);
        }
      }
    } else {
      #pragma unroll 1
      for (int p=3; p<16; p++){
        f32x4 acc = {0.f,0.f,0.f,0.f};
        s16x8 b0 = *(const s16x8*)&pk[PK_RW3P + (size_t)((p*2+0)*64+lane)*8];
        s16x8 b1 = *(const s16x8*)&pk[PK_RW3P + (size_t)((p*2+1)*64+lane)*8];
        acc = MFMA(ah0,b0,acc); acc = MFMA(ah1,b1,acc);
        int q = p*16 + c16;
        if (q < 128){
          float b3 = rb3[128 + q];
          #pragma unroll
          for (int r=0;r<4;r++){
            int er = kg*4 + r;
            LU[ASV_US + er*136 + q] = f2bf((acc[r]+b3) * L[OMS + er*132 + q]);
          }
        } else if (q < 192){
          float b3 = rb3[256 + (q-128)];
          #pragma unroll
          for (int r=0;r<4;r++){
            int er = kg*4 + r;
            L[OBVS + er*68 + (q-128)] = (acc[r]+b3) * L[OEA + er*4];
          }
        } else {
          float b3 = rb3[384 + (q-192)];
          #pragma unroll
          for (int r=0;r<4;r++){
            int er = kg*4 + r;
            L[OWV1 + er*68 + (q-192)] = (acc[r]+b3) * 0.7071067811865476f;
          }
        }
      }
    }
  }
  __syncthreads();

  // ---- P4: waves 0,1 -> alpha logits (3-MFMA); waves 2,3 -> val (1-MFMA) ----
  const float rs192 = 0.07216878364870323f;
  if (w < 2){
    int nt = w;
    s16x8 ah[6], al[6];
    #pragma unroll
    for (int kt=0;kt<6;kt++){
      ah[kt] = *(const s16x8*)&LU[D0HI_US + arow*200 + kt*32 + kg*8];
      al[kt] = *(const s16x8*)&LU[D0LO_US + arow*200 + kt*32 + kg*8];
    }
    f32x4 acc = {0.f,0.f,0.f,0.f};
    #pragma unroll
    for (int kt=0;kt<6;kt++){
      s16x8 bh = *(const s16x8*)&pk[PK_LW0AH + (size_t)((nt*6+kt)*64+lane)*8];
      s16x8 bl = *(const s16x8*)&pk[PK_LW0AL + (size_t)((nt*6+kt)*64+lane)*8];
      acc = MFMA(ah[kt],bh,acc); acc = MFMA(ah[kt],bl,acc); acc = MFMA(al[kt],bh,acc);
    }
    int q = nt*16 + c16;
    int realcol = (q>>3)*40 + (q&7);
    float lbv = lb0[realcol];
    float ad  = alpha_dot[q];
    #pragma unroll
    for (int r=0;r<4;r++){
      float m = acc[r]*rs192 + lbv;
      float p = (0.6f*m + 0.4f*m*(2.f*sigmoidf_(m)-1.f))*ad;
      p += __shfl_xor(p, 1);
      p += __shfl_xor(p, 2);
      p += __shfl_xor(p, 4);
      if ((lane&7)==0){
        int er = kg*4 + r;
        galpha[(size_t)(e0+er)*4 + (q>>3)] = p;
      }
    }
  } else {
    s16x8 af[6];
    #pragma unroll
    for (int kt=0;kt<6;kt++)
      af[kt] = *(const s16x8*)&LU[D0HI_US + arow*200 + kt*32 + kg*8];
    #pragma unroll
    for (int j=0;j<4;j++){
      int v = (w-2)*4 + j;
      f32x4 acc = {0.f,0.f,0.f,0.f};
      #pragma unroll
      for (int kt=0;kt<6;kt++){
        s16x8 b = *(const s16x8*)&pk[PK_LW0P + (size_t)((v*6+kt)*64+lane)*8];
        acc = MFMA(af[kt],b,acc);
      }
      int q = v*16 + c16;
      int realcol = (q>>5)*40 + 8 + (q&31);
      float lbv = lb0[realcol];
      #pragma unroll
      for (int r=0;r<4;r++){
        int er = kg*4 + r;
        gval[(size_t)(e0+er)*128 + q] = __float2bfloat16(acc[r]*rs192 + lbv);
      }
    }
  }
  __syncthreads();

  // ---- P5-prep: d1 rows 128..255 per component, vectorized ----
  for (int idx=t; idx<1536; idx+=256){
    int c = idx>>9, rem = idx&511, e = rem>>5, i4 = rem&31;
    int i = i4*4;
    float4 r;
    if (i < 64){
      float4 b = *(const float4*)&L[OBVS + e*68 + i];
      float4 m = *(const float4*)&L[OMV + e*204 + c*68 + i];
      r.x=b.x*m.x; r.y=b.y*m.y; r.z=b.z*m.z; r.w=b.w*m.w;
    } else {
      int ii = i - 64;
      int ca = (c+1)%3, cb = (c+2)%3;
      float4 wv = *(const float4*)&L[OWV1 + e*68 + ii];
      float4 ma = *(const float4*)&L[OMV + e*204 + ca*68 + ii];
      float4 mb = *(const float4*)&L[OMV + e*204 + cb*68 + ii];
      float eaa = L[OEA + e*4 + 1 + ca], ebb = L[OEA + e*4 + 1 + cb];
      r.x = wv.x*(ma.x*ebb - mb.x*eaa);
      r.y = wv.y*(ma.y*ebb - mb.y*eaa);
      r.z = wv.z*(ma.z*ebb - mb.z*eaa);
      r.w = wv.w*(ma.w*ebb - mb.w*eaa);
    }
    ushort4 u; u.x=f2bf(r.x); u.y=f2bf(r.y); u.z=f2bf(r.z); u.w=f2bf(r.w);
    *(ushort4*)&LU[D1_US + c*2176 + e*136 + i] = u;
  }
  __syncthreads();

  // ---- P5: m1_c = ev_c * (asv @ lw1[0:128]) + d1_c @ lw1[128:256]; wave w = N-tile ----
  {
    int nt = w;
    f32x4 z = {0.f,0.f,0.f,0.f};
    #pragma unroll
    for (int kt=0; kt<4; kt++){
      s16x8 a = *(const s16x8*)&LU[ASV_US + arow*136 + kt*32 + kg*8];
      s16x8 b = *(const s16x8*)&pk[PK_LW1P + (size_t)((nt*8+kt)*64+lane)*8];
      z = MFMA(a,b,z);
    }
    f32x4 acc0 = {0.f,0.f,0.f,0.f}, acc1 = {0.f,0.f,0.f,0.f}, acc2 = {0.f,0.f,0.f,0.f};
    #pragma unroll
    for (int kt=4; kt<8; kt++){
      s16x8 b = *(const s16x8*)&pk[PK_LW1P + (size_t)((nt*8+kt)*64+lane)*8];
      s16x8 af0 = *(const s16x8*)&LU[D1_US + 0*2176 + arow*136 + (kt-4)*32 + kg*8];
      s16x8 af1 = *(const s16x8*)&LU[D1_US + 1*2176 + arow*136 + (kt-4)*32 + kg*8];
      s16x8 af2 = *(const s16x8*)&LU[D1_US + 2*2176 + arow*136 + (kt-4)*32 + kg*8];
      acc0 = MFMA(af0,b,acc0); acc1 = MFMA(af1,b,acc1); acc2 = MFMA(af2,b,acc2);
    }
    const float r16 = 0.0625f;
    int col = nt*16 + c16;
    #pragma unroll
    for (int r=0;r<4;r++){
      int er = kg*4 + r;
      float ev0 = L[OEA + er*4 + 1];
      float ev1 = L[OEA + er*4 + 2];
      float ev2 = L[OEA + er*4 + 3];
      gm1[((size_t)(e0+er)*3 + 0)*64 + col] = __float2bfloat16((z[r]*ev0 + acc0[r])*r16);
      gm1[((size_t)(e0+er)*3 + 1)*64 + col] = __float2bfloat16((z[r]*ev1 + acc1[r])*r16);
      gm1[((size_t)(e0+er)*3 + 2)*64 + col] = __float2bfloat16((z[r]*ev2 + acc2[r])*r16);
    }
  }
}

// ---------------- Kernel D: per-dst softmax + aggregation (unchanged) ----------------
__global__ __launch_bounds__(320) void k_agg(
  const int* __restrict__ edge_dst,
  const float* __restrict__ galpha, const __hip_bfloat16* __restrict__ gval,
  const __hip_bfloat16* __restrict__ gm1,
  const float* __restrict__ pw0, const float* __restrict__ pb0,
  const float* __restrict__ pw1,
  float* __restrict__ out)
{
  __shared__ float sRed[256], sW[256], sAm[4], sInv[4], sNS[128], sNV[192];
  int t = threadIdx.x;
  int n = blockIdx.x;
  int lo, hi;
  {
    int a=0,b=N_EDGES;
    while(a<b){int m=(a+b)>>1; if (edge_dst[m] < n) a=m+1; else b=m;}
    lo=a; a=lo; b=N_EDGES;
    while(a<b){int m=(a+b)>>1; if (edge_dst[m] < n+1) a=m+1; else b=m;}
    hi=a;
  }
  if (t < 256){
    int g=t>>2, h=t&3;
    float m=-1e30f;
    for (int e=lo+g; e<hi; e+=64) m = fmaxf(m, galpha[(size_t)e*4+h]);
    sRed[t]=m;
  }
  __syncthreads();
  for (int s=32; s>=1; s>>=1){
    if (t < s*4) sRed[t] = fmaxf(sRed[t], sRed[t+s*4]);
    __syncthreads();
  }
  if (t<4) sAm[t] = (hi>lo) ? sRed[t] : 0.f;
  __syncthreads();
  if (t < 256){
    int g=t>>2, h=t&3; float ssum=0.f;
    for (int e=lo+g; e<hi; e+=64) ssum += __expf(galpha[(size_t)e*4+h]-sAm[h]);
    sRed[t]=ssum;
  }
  __syncthreads();
  for (int s=32; s>=1; s>>=1){
    if (t < s*4) sRed[t] += sRed[t+s*4];
    __syncthreads();
  }
  if (t<4) sInv[t] = 1.f / fmaxf(sRed[t], 1e-12f);
  __syncthreads();
  float acc = 0.f;
  int cq=0, oq=0, hq=0;
  if (t < 128){ hq = t>>5; }
  else { int q=t-128; cq=q>>6; oq=q&63; hq=oq>>4; }
  for (int base=lo; base<hi; base+=64){
    int nn = min(64, hi-base);
    if (t < 256){ int j=t>>2,h=t&3; if (j<nn) sW[t] = __expf(galpha[(size_t)(base+j)*4+h]-sAm[h])*sInv[h]; }
    __syncthreads();
    if (t < 128){
      for (int j=0;j<nn;j++) acc += sW[j*4+hq]*__bfloat162float(gval[(size_t)(base+j)*128+t]);
    } else {
      for (int j=0;j<nn;j++) acc += sW[j*4+hq]*__bfloat162float(gm1[(size_t)((size_t)(base+j)*3+cq)*64+oq]);
    }
    __syncthreads();
  }
  if (t < 128) sNS[t]=acc; else sNV[oq*3+cq]=acc;
  __syncthreads();
  if (t < 128){
    float a = 0.f;
    for (int k=0;k<128;k++) a += sNS[k]*pw0[k*128+t];
    out[(size_t)n*320+t] = a*0.08838834764831845f + pb0[t];
  } else {
    float a = 0.f;
    for (int i=0;i<64;i++) a += sNV[i*3+cq]*pw1[i*64+oq];
    out[(size_t)n*320+128+oq*3+cq] = a*0.125f;
  }
}

extern "C" void kernel_launch(void* const* d_in, const int* in_sizes, int n_in,
                              void* d_out, int out_size, void* d_ws, size_t ws_size,
                              hipStream_t stream)
{
  const float* node_input  = (const float*)d_in[0];
  const float* edge_attr   = (const float*)d_in[1];
  const float* edge_scalars= (const float*)d_in[2];
  const int*   edge_src    = (const int*)d_in[3];
  const int*   edge_dst    = (const int*)d_in[4];
  const float* w_src0=(const float*)d_in[5];  const float* b_src0=(const float*)d_in[6];
  const float* w_src1=(const float*)d_in[7];
  const float* w_dst0=(const float*)d_in[8];  const float* b_dst0=(const float*)d_in[9];
  const float* w_dst1=(const float*)d_in[10];
  const float* rw1=(const float*)d_in[11];    const float* rb1=(const float*)d_in[12];
  const float* rw2=(const float*)d_in[13];    const float* rb2=(const float*)d_in[14];
  const float* rw3=(const float*)d_in[15];    const float* rb3=(const float*)d_in[16];
  const float* lw0=(const float*)d_in[17];    const float* lb0=(const float*)d_in[18];
  const float* lw1=(const float*)d_in[19];
  const float* alpha_dot=(const float*)d_in[20];
  const float* pw0=(const float*)d_in[21];    const float* pb0=(const float*)d_in[22];
  const float* pw1=(const float*)d_in[23];
  float* out = (float*)d_out;

  float* ns_src = (float*)d_ws;
  float* ns_dst = ns_src + (size_t)N_NODES*128;
  float* nv_src = ns_dst + (size_t)N_NODES*128;
  float* nv_dst = nv_src + (size_t)N_NODES*192;
  float* galpha = nv_dst + (size_t)N_NODES*192;
  __hip_bfloat16* gval = (__hip_bfloat16*)(galpha + (size_t)N_EDGES*4);
  __hip_bfloat16* gm1  = gval + (size_t)N_EDGES*128;
  ushort_t* pk = (ushort_t*)(gm1 + (size_t)N_EDGES*192);

  k_pack<<<328, 256, 0, stream>>>(rw1, rw2, rw3, lw0, lw1, pk);
  k_node<<<N_NODES/8, 256, 0, stream>>>(node_input, w_src0,b_src0,w_src1,
                                        w_dst0,b_dst0,w_dst1,
                                        ns_src,ns_dst,nv_src,nv_dst);
  k_edge5<<<N_EDGES/EB, 256, 0, stream>>>(edge_attr, edge_scalars, edge_src, edge_dst,
                                          ns_src,ns_dst,nv_src,nv_dst,
                                          rb1,rb2,rb3,lb0,alpha_dot,pk,
                                          galpha,gval,gm1);
  k_agg<<<N_NODES, 320, 0, stream>>>(edge_dst, galpha, gval, gm1, pw0,pb0,pw1, out);
}

// Round 10
// 269.023 us; speedup vs baseline: 25.6848x; 1.3063x over previous
//
#include <hip/hip_runtime.h>
#include <hip/hip_bf16.h>
#include <math.h>

#define N_NODES 10000
#define N_EDGES 160000
#define EB 16

typedef unsigned short ushort_t;
using f32x4 = __attribute__((ext_vector_type(4))) float;
using s16x8 = __attribute__((ext_vector_type(8))) short;

__device__ __forceinline__ float sigmoidf_(float x){ return 1.f/(1.f+__expf(-x)); }
__device__ __forceinline__ ushort_t f2bf(float x){
  __hip_bfloat16 h = __float2bfloat16(x);
  return *reinterpret_cast<ushort_t*>(&h);
}
__device__ __forceinline__ float bf2f(ushort_t u){
  unsigned int v = ((unsigned int)u)<<16;
  return __uint_as_float(v);
}

// ---- packed-weight ushort offsets (in pk) ----
#define PK_RW1H  0
#define PK_RW1L  4096
#define PK_RW2H  8192
#define PK_RW2L  12288
#define PK_RW3AH 16384
#define PK_RW3AL 28672
#define PK_RW3P  40960
#define PK_LW0AH 57344
#define PK_LW0AL 63488
#define PK_LW0P  69632
#define PK_LW1P  94208
#define PK_PW0H  110592
#define PK_PW0L  126976
#define PK_PW1H  143360
#define PK_PW1L  147456
#define PK_TOTAL 151552

// ---------------- k_pack: split/pack weights into MFMA frag order ----------------
// frag layout: [nt][kt][lane][8]; k = kt*32 + (lane>>4)*8 + i; col = map(nt*16 + (lane&15))
__global__ __launch_bounds__(256) void k_pack(
  const float* __restrict__ rw1, const float* __restrict__ rw2,
  const float* __restrict__ rw3, const float* __restrict__ lw0,
  const float* __restrict__ lw1, const float* __restrict__ pw0,
  const float* __restrict__ pw1, ushort_t* __restrict__ pk)
{
  int idx = blockIdx.x*256 + threadIdx.x;
  if (idx < 4096){
    int nt=idx>>10, r=idx&1023, kt=r>>9, q=r&511, l=q>>3, i=q&7;
    int k = kt*32 + (l>>4)*8 + i, col = nt*16 + (l&15);
    float x = rw1[k*64 + col];
    ushort_t hi = f2bf(x);
    pk[PK_RW1H+idx] = hi; pk[PK_RW1L+idx] = f2bf(x - bf2f(hi));
  } else if (idx < 8192){
    int j = idx-4096;
    int nt=j>>10, r=j&1023, kt=r>>9, q=r&511, l=q>>3, i=q&7;
    int k = kt*32 + (l>>4)*8 + i, col = nt*16 + (l&15);
    float x = rw2[k*64 + col];
    ushort_t hi = f2bf(x);
    pk[PK_RW2H+j] = hi; pk[PK_RW2L+j] = f2bf(x - bf2f(hi));
  } else if (idx < 20480){
    int j = idx-8192;
    int nt=j>>10, r=j&1023, kt=r>>9, q=r&511, l=q>>3, i=q&7;
    int k = kt*32 + (l>>4)*8 + i;
    int col = (nt<8) ? nt*16+(l&15) : 320+(nt-8)*16+(l&15);
    float x = rw3[(size_t)k*448 + col];
    ushort_t hi = f2bf(x);
    pk[PK_RW3AH+j] = hi; pk[PK_RW3AL+j] = f2bf(x - bf2f(hi));
  } else if (idx < 36864){
    int j = idx-20480;
    int nt=j>>10, r=j&1023, kt=r>>9, q=r&511, l=q>>3, i=q&7;
    int k = kt*32 + (l>>4)*8 + i;
    int v = nt*16 + (l&15);
    int col = (v<128) ? 128+v : (v<192) ? 256+(v-128) : 384+(v-192);
    pk[PK_RW3P+j] = f2bf(rw3[(size_t)k*448 + col]);
  } else if (idx < 43008){
    int j = idx-36864;
    int nt=j/3072, r=j-nt*3072, kt=r>>9, q=r&511, l=q>>3, i=q&7;
    int k = kt*32 + (l>>4)*8 + i;
    int qq = nt*16 + (l&15);
    int col = (qq>>3)*40 + (qq&7);
    float x = lw0[(size_t)k*160 + col];
    ushort_t hi = f2bf(x);
    pk[PK_LW0AH+j] = hi; pk[PK_LW0AL+j] = f2bf(x - bf2f(hi));
  } else if (idx < 67584){
    int j = idx-43008;
    int nt=j/3072, r=j-nt*3072, kt=r>>9, q=r&511, l=q>>3, i=q&7;
    int k = kt*32 + (l>>4)*8 + i;
    int v = nt*16 + (l&15);
    int col = (v>>5)*40 + 8 + (v&31);
    pk[PK_LW0P+j] = f2bf(lw0[(size_t)k*160 + col]);
  } else if (idx < 83968){
    int j = idx-67584;
    int nt=j>>12, r=j&4095, kt=r>>9, q=r&511, l=q>>3, i=q&7;
    int k = kt*32 + (l>>4)*8 + i, col = nt*16 + (l&15);
    pk[PK_LW1P+j] = f2bf(lw1[(size_t)k*64 + col]);
  } else if (idx < 100352){                          // pw0 hi+lo [8nt][4kt]
    int j = idx-83968;
    int nt=j>>11, r=j&2047, kt=r>>9, q=r&511, l=q>>3, i=q&7;
    int k = kt*32 + (l>>4)*8 + i, col = nt*16 + (l&15);
    float x = pw0[k*128 + col];
    ushort_t hi = f2bf(x);
    pk[PK_PW0H+j] = hi; pk[PK_PW0L+j] = f2bf(x - bf2f(hi));
  } else if (idx < 104448){                          // pw1 hi+lo [4nt][2kt]
    int j = idx-100352;
    int nt=j>>10, r=j&1023, kt=r>>9, q=r&511, l=q>>3, i=q&7;
    int k = kt*32 + (l>>4)*8 + i, col = nt*16 + (l&15);
    float x = pw1[k*64 + col];
    ushort_t hi = f2bf(x);
    pk[PK_PW1H+j] = hi; pk[PK_PW1L+j] = f2bf(x - bf2f(hi));
  }
}

// ---------------- Kernel A: node transforms (unchanged) ----------------
__global__ __launch_bounds__(256) void k_node(
    const float* __restrict__ node_input,
    const float* __restrict__ w_src0, const float* __restrict__ b_src0,
    const float* __restrict__ w_src1,
    const float* __restrict__ w_dst0, const float* __restrict__ b_dst0,
    const float* __restrict__ w_dst1,
    float* __restrict__ ns_src, float* __restrict__ ns_dst,
    float* __restrict__ nv_src, float* __restrict__ nv_dst)
{
  __shared__ float sNI[8*321];
  int t = threadIdx.x;
  int n0 = blockIdx.x*8;
  for (int idx=t; idx<8*320; idx+=256){
    int nd = idx/320, r = idx - nd*320;
    sNI[nd*321+r] = node_input[(size_t)(n0+nd)*320 + r];
  }
  __syncthreads();
  {
    int o = t & 127, half = t >> 7;
    const float* w = half ? w_dst0 : w_src0;
    const float* b = half ? b_dst0 : b_src0;
    float* outp = half ? ns_dst : ns_src;
    float acc[8];
    #pragma unroll
    for (int nd=0;nd<8;nd++) acc[nd]=0.f;
    for (int k=0;k<128;k++){
      float wv = w[k*128+o];
      #pragma unroll
      for (int nd=0;nd<8;nd++) acc[nd] += sNI[nd*321+k]*wv;
    }
    const float rs = 0.08838834764831845f;
    float bo = b[o];
    #pragma unroll
    for (int nd=0;nd<8;nd++) outp[(size_t)(n0+nd)*128+o] = acc[nd]*rs + bo;
  }
  if (t < 192){
    int o = t & 63, c = t >> 6;
    for (int half=0; half<2; half++){
      const float* w = half ? w_dst1 : w_src1;
      float* outp = half ? nv_dst : nv_src;
      float acc[8];
      #pragma unroll
      for (int nd=0;nd<8;nd++) acc[nd]=0.f;
      for (int i=0;i<64;i++){
        float wv = w[i*64+o];
        #pragma unroll
        for (int nd=0;nd<8;nd++) acc[nd] += sNI[nd*321+128+i*3+c]*wv;
      }
      #pragma unroll
      for (int nd=0;nd<8;nd++) outp[(size_t)(n0+nd)*192 + o*3 + c] = acc[nd]*0.125f;
    }
  }
}

// ---------------- Kernel C: all-MFMA edge pipeline (unchanged from round 9) ----------------
#define OEA   0
#define OMV   64
#define OMS   3328
#define FX    5440
#define ESHI_US  (FX*2)
#define ESLO_US  (FX*2+1152)
#define D0HI_US  (FX*2)
#define D0LO_US  (FX*2+3200)
#define D1_US    (FX*2)
#define FY    8704
#define H1HI_US  (FY*2)
#define H1LO_US  (FY*2+1152)
#define ASV_US   (FY*2)
#define FH2   9856
#define H2HI_US  (FH2*2)
#define H2LO_US  (FH2*2+1152)
#define OBVS  11008
#define OWV1  12096

#define MFMA(a,b,c) __builtin_amdgcn_mfma_f32_16x16x32_bf16((a),(b),(c),0,0,0)

__global__ __launch_bounds__(256) void k_edge5(
  const float* __restrict__ edge_attr, const float* __restrict__ edge_scalars,
  const int* __restrict__ edge_src, const int* __restrict__ edge_dst,
  const float* __restrict__ ns_src, const float* __restrict__ ns_dst,
  const float* __restrict__ nv_src, const float* __restrict__ nv_dst,
  const float* __restrict__ rb1, const float* __restrict__ rb2,
  const float* __restrict__ rb3, const float* __restrict__ lb0,
  const float* __restrict__ alpha_dot,
  const ushort_t* __restrict__ pk,
  float* __restrict__ galpha, __hip_bfloat16* __restrict__ gval,
  __hip_bfloat16* __restrict__ gm1)
{
  __shared__ __align__(16) float L[13184];
  ushort_t* LU = (ushort_t*)L;
  const int t = threadIdx.x;
  const int e0 = blockIdx.x * EB;
  const int lane = t & 63, w = t >> 6;
  const int arow = lane & 15, kg = lane >> 4, c16 = lane & 15;

  // ---- P0 ----
  {
    int e = t>>4, l = t&15;
    int s = edge_src[e0+e], d = edge_dst[e0+e];
    #pragma unroll
    for (int j=0;j<2;j++){
      int idx = l + 16*j;
      float4 a = *(const float4*)&ns_src[(size_t)s*128 + idx*4];
      float4 b = *(const float4*)&ns_dst[(size_t)d*128 + idx*4];
      float4 r; r.x=a.x+b.x; r.y=a.y+b.y; r.z=a.z+b.z; r.w=a.w+b.w;
      *(float4*)&L[OMS + e*132 + idx*4] = r;
    }
    float f[12];
    #pragma unroll
    for (int j=0;j<3;j++){
      float4 a = *(const float4*)&nv_src[(size_t)s*192 + l*12 + j*4];
      float4 b = *(const float4*)&nv_dst[(size_t)d*192 + l*12 + j*4];
      f[j*4+0]=a.x+b.x; f[j*4+1]=a.y+b.y; f[j*4+2]=a.z+b.z; f[j*4+3]=a.w+b.w;
    }
    #pragma unroll
    for (int c=0;c<3;c++){
      float4 r; r.x=f[c]; r.y=f[3+c]; r.z=f[6+c]; r.w=f[9+c];
      *(float4*)&L[OMV + e*204 + c*68 + l*4] = r;
    }
    float4 x = *(const float4*)&edge_scalars[(size_t)(e0+e)*64 + l*4];
    ushort4 hi, lo;
    { ushort_t h=f2bf(x.x); hi.x=h; lo.x=f2bf(x.x-bf2f(h)); }
    { ushort_t h=f2bf(x.y); hi.y=h; lo.y=f2bf(x.y-bf2f(h)); }
    { ushort_t h=f2bf(x.z); hi.z=h; lo.z=f2bf(x.z-bf2f(h)); }
    { ushort_t h=f2bf(x.w); hi.w=h; lo.w=f2bf(x.w-bf2f(h)); }
    *(ushort4*)&LU[ESHI_US + e*72 + l*4] = hi;
    *(ushort4*)&LU[ESLO_US + e*72 + l*4] = lo;
  }
  if (t < 64) L[OEA + t] = edge_attr[(size_t)e0*4 + t];
  __syncthreads();

  // ---- P1 ----
  {
    s16x8 ah0 = *(const s16x8*)&LU[ESHI_US + arow*72 + 0  + kg*8];
    s16x8 ah1 = *(const s16x8*)&LU[ESHI_US + arow*72 + 32 + kg*8];
    s16x8 al0 = *(const s16x8*)&LU[ESLO_US + arow*72 + 0  + kg*8];
    s16x8 al1 = *(const s16x8*)&LU[ESLO_US + arow*72 + 32 + kg*8];
    f32x4 acc = {0.f,0.f,0.f,0.f};
    s16x8 bh0 = *(const s16x8*)&pk[PK_RW1H + (size_t)((w*2+0)*64+lane)*8];
    s16x8 bl0 = *(const s16x8*)&pk[PK_RW1L + (size_t)((w*2+0)*64+lane)*8];
    s16x8 bh1 = *(const s16x8*)&pk[PK_RW1H + (size_t)((w*2+1)*64+lane)*8];
    s16x8 bl1 = *(const s16x8*)&pk[PK_RW1L + (size_t)((w*2+1)*64+lane)*8];
    acc = MFMA(ah0,bh0,acc); acc = MFMA(ah0,bl0,acc); acc = MFMA(al0,bh0,acc);
    acc = MFMA(ah1,bh1,acc); acc = MFMA(ah1,bl1,acc); acc = MFMA(al1,bh1,acc);
    int col = w*16 + c16;
    float rb = rb1[col];
    #pragma unroll
    for (int r=0;r<4;r++){
      int er = kg*4 + r;
      float v = acc[r] + rb;
      float h = v*sigmoidf_(v);
      ushort_t hi = f2bf(h);
      LU[H1HI_US + er*72 + col] = hi;
      LU[H1LO_US + er*72 + col] = f2bf(h - bf2f(hi));
    }
  }
  __syncthreads();

  // ---- P2 ----
  {
    s16x8 ah0 = *(const s16x8*)&LU[H1HI_US + arow*72 + 0  + kg*8];
    s16x8 ah1 = *(const s16x8*)&LU[H1HI_US + arow*72 + 32 + kg*8];
    s16x8 al0 = *(const s16x8*)&LU[H1LO_US + arow*72 + 0  + kg*8];
    s16x8 al1 = *(const s16x8*)&LU[H1LO_US + arow*72 + 32 + kg*8];
    f32x4 acc = {0.f,0.f,0.f,0.f};
    s16x8 bh0 = *(const s16x8*)&pk[PK_RW2H + (size_t)((w*2+0)*64+lane)*8];
    s16x8 bl0 = *(const s16x8*)&pk[PK_RW2L + (size_t)((w*2+0)*64+lane)*8];
    s16x8 bh1 = *(const s16x8*)&pk[PK_RW2H + (size_t)((w*2+1)*64+lane)*8];
    s16x8 bl1 = *(const s16x8*)&pk[PK_RW2L + (size_t)((w*2+1)*64+lane)*8];
    acc = MFMA(ah0,bh0,acc); acc = MFMA(ah0,bl0,acc); acc = MFMA(al0,bh0,acc);
    acc = MFMA(ah1,bh1,acc); acc = MFMA(ah1,bl1,acc); acc = MFMA(al1,bh1,acc);
    int col = w*16 + c16;
    float rb = rb2[col];
    #pragma unroll
    for (int r=0;r<4;r++){
      int er = kg*4 + r;
      float v = acc[r] + rb;
      float h = v*sigmoidf_(v);
      ushort_t hi = f2bf(h);
      LU[H2HI_US + er*72 + col] = hi;
      LU[H2LO_US + er*72 + col] = f2bf(h - bf2f(hi));
    }
  }
  __syncthreads();

  // ---- P3 ----
  {
    s16x8 ah0 = *(const s16x8*)&LU[H2HI_US + arow*72 + 0  + kg*8];
    s16x8 ah1 = *(const s16x8*)&LU[H2HI_US + arow*72 + 32 + kg*8];
    s16x8 al0 = *(const s16x8*)&LU[H2LO_US + arow*72 + 0  + kg*8];
    s16x8 al1 = *(const s16x8*)&LU[H2LO_US + arow*72 + 32 + kg*8];

    if (w < 3){
      #pragma unroll
      for (int ai=0; ai<4; ai++){
        int a = w*4 + ai;
        f32x4 acc = {0.f,0.f,0.f,0.f};
        s16x8 bh0 = *(const s16x8*)&pk[PK_RW3AH + (size_t)((a*2+0)*64+lane)*8];
        s16x8 bl0 = *(const s16x8*)&pk[PK_RW3AL + (size_t)((a*2+0)*64+lane)*8];
        s16x8 bh1 = *(const s16x8*)&pk[PK_RW3AH + (size_t)((a*2+1)*64+lane)*8];
        s16x8 bl1 = *(const s16x8*)&pk[PK_RW3AL + (size_t)((a*2+1)*64+lane)*8];
        acc = MFMA(ah0,bh0,acc); acc = MFMA(ah0,bl0,acc); acc = MFMA(al0,bh0,acc);
        acc = MFMA(ah1,bh1,acc); acc = MFMA(ah1,bl1,acc); acc = MFMA(al1,bh1,acc);
        if (a < 8){
          int i = a*16 + c16;
          float b3 = rb3[i];
          #pragma unroll
          for (int r=0;r<4;r++){
            int er = kg*4 + r;
            float d0v = (acc[r]+b3) * L[OMS + er*132 + i] * L[OEA + er*4];
            ushort_t hi = f2bf(d0v);
            LU[D0HI_US + er*200 + i] = hi;
            LU[D0LO_US + er*200 + i] = f2bf(d0v - bf2f(hi));
          }
        } else {
          int j = (a-8)*16 + c16;
          float b3 = rb3[320 + j];
          #pragma unroll
          for (int r=0;r<4;r++){
            int er = kg*4 + r;
            float dot = L[OMV+er*204      +j]*L[OEA+er*4+1]
                      + L[OMV+er*204+ 68  +j]*L[OEA+er*4+2]
                      + L[OMV+er*204+136  +j]*L[OEA+er*4+3];
            float d0v = (acc[r]+b3) * dot * 0.5773502691896258f;
            ushort_t hi = f2bf(d0v);
            LU[D0HI_US + er*200 + 128 + j] = hi;
            LU[D0LO_US + er*200 + 128 + j] = f2bf(d0v - bf2f(hi));
          }
        }
      }
      {
        int p = w;
        f32x4 acc = {0.f,0.f,0.f,0.f};
        s16x8 b0 = *(const s16x8*)&pk[PK_RW3P + (size_t)((p*2+0)*64+lane)*8];
        s16x8 b1 = *(const s16x8*)&pk[PK_RW3P + (size_t)((p*2+1)*64+lane)*8];
        acc = MFMA(ah0,b0,acc); acc = MFMA(ah1,b1,acc);
        int q = p*16 + c16;
        float b3 = rb3[128 + q];
        #pragma unroll
        for (int r=0;r<4;r++){
          int er = kg*4 + r;
          LU[ASV_US + er*136 + q] = f2bf((acc[r]+b3) * L[OMS + er*132 + q]);
        }
      }
    } else {
      #pragma unroll 1
      for (int p=3; p<16; p++){
        f32x4 acc = {0.f,0.f,0.f,0.f};
        s16x8 b0 = *(const s16x8*)&pk[PK_RW3P + (size_t)((p*2+0)*64+lane)*8];
        s16x8 b1 = *(const s16x8*)&pk[PK_RW3P + (size_t)((p*2+1)*64+lane)*8];
        acc = MFMA(ah0,b0,acc); acc = MFMA(ah1,b1,acc);
        int q = p*16 + c16;
        if (q < 128){
          float b3 = rb3[128 + q];
          #pragma unroll
          for (int r=0;r<4;r++){
            int er = kg*4 + r;
            LU[ASV_US + er*136 + q] = f2bf((acc[r]+b3) * L[OMS + er*132 + q]);
          }
        } else if (q < 192){
          float b3 = rb3[256 + (q-128)];
          #pragma unroll
          for (int r=0;r<4;r++){
            int er = kg*4 + r;
            L[OBVS + er*68 + (q-128)] = (acc[r]+b3) * L[OEA + er*4];
          }
        } else {
          float b3 = rb3[384 + (q-192)];
          #pragma unroll
          for (int r=0;r<4;r++){
            int er = kg*4 + r;
            L[OWV1 + er*68 + (q-192)] = (acc[r]+b3) * 0.7071067811865476f;
          }
        }
      }
    }
  }
  __syncthreads();

  // ---- P4 ----
  const float rs192 = 0.07216878364870323f;
  if (w < 2){
    int nt = w;
    s16x8 ah[6], al[6];
    #pragma unroll
    for (int kt=0;kt<6;kt++){
      ah[kt] = *(const s16x8*)&LU[D0HI_US + arow*200 + kt*32 + kg*8];
      al[kt] = *(const s16x8*)&LU[D0LO_US + arow*200 + kt*32 + kg*8];
    }
    f32x4 acc = {0.f,0.f,0.f,0.f};
    #pragma unroll
    for (int kt=0;kt<6;kt++){
      s16x8 bh = *(const s16x8*)&pk[PK_LW0AH + (size_t)((nt*6+kt)*64+lane)*8];
      s16x8 bl = *(const s16x8*)&pk[PK_LW0AL + (size_t)((nt*6+kt)*64+lane)*8];
      acc = MFMA(ah[kt],bh,acc); acc = MFMA(ah[kt],bl,acc); acc = MFMA(al[kt],bh,acc);
    }
    int q = nt*16 + c16;
    int realcol = (q>>3)*40 + (q&7);
    float lbv = lb0[realcol];
    float ad  = alpha_dot[q];
    #pragma unroll
    for (int r=0;r<4;r++){
      float m = acc[r]*rs192 + lbv;
      float p = (0.6f*m + 0.4f*m*(2.f*sigmoidf_(m)-1.f))*ad;
      p += __shfl_xor(p, 1);
      p += __shfl_xor(p, 2);
      p += __shfl_xor(p, 4);
      if ((lane&7)==0){
        int er = kg*4 + r;
        galpha[(size_t)(e0+er)*4 + (q>>3)] = p;
      }
    }
  } else {
    s16x8 af[6];
    #pragma unroll
    for (int kt=0;kt<6;kt++)
      af[kt] = *(const s16x8*)&LU[D0HI_US + arow*200 + kt*32 + kg*8];
    #pragma unroll
    for (int j=0;j<4;j++){
      int v = (w-2)*4 + j;
      f32x4 acc = {0.f,0.f,0.f,0.f};
      #pragma unroll
      for (int kt=0;kt<6;kt++){
        s16x8 b = *(const s16x8*)&pk[PK_LW0P + (size_t)((v*6+kt)*64+lane)*8];
        acc = MFMA(af[kt],b,acc);
      }
      int q = v*16 + c16;
      int realcol = (q>>5)*40 + 8 + (q&31);
      float lbv = lb0[realcol];
      #pragma unroll
      for (int r=0;r<4;r++){
        int er = kg*4 + r;
        gval[(size_t)(e0+er)*128 + q] = __float2bfloat16(acc[r]*rs192 + lbv);
      }
    }
  }
  __syncthreads();

  // ---- P5-prep ----
  for (int idx=t; idx<1536; idx+=256){
    int c = idx>>9, rem = idx&511, e = rem>>5, i4 = rem&31;
    int i = i4*4;
    float4 r;
    if (i < 64){
      float4 b = *(const float4*)&L[OBVS + e*68 + i];
      float4 m = *(const float4*)&L[OMV + e*204 + c*68 + i];
      r.x=b.x*m.x; r.y=b.y*m.y; r.z=b.z*m.z; r.w=b.w*m.w;
    } else {
      int ii = i - 64;
      int ca = (c+1)%3, cb = (c+2)%3;
      float4 wv = *(const float4*)&L[OWV1 + e*68 + ii];
      float4 ma = *(const float4*)&L[OMV + e*204 + ca*68 + ii];
      float4 mb = *(const float4*)&L[OMV + e*204 + cb*68 + ii];
      float eaa = L[OEA + e*4 + 1 + ca], ebb = L[OEA + e*4 + 1 + cb];
      r.x = wv.x*(ma.x*ebb - mb.x*eaa);
      r.y = wv.y*(ma.y*ebb - mb.y*eaa);
      r.z = wv.z*(ma.z*ebb - mb.z*eaa);
      r.w = wv.w*(ma.w*ebb - mb.w*eaa);
    }
    ushort4 u; u.x=f2bf(r.x); u.y=f2bf(r.y); u.z=f2bf(r.z); u.w=f2bf(r.w);
    *(ushort4*)&LU[D1_US + c*2176 + e*136 + i] = u;
  }
  __syncthreads();

  // ---- P5 ----
  {
    int nt = w;
    f32x4 z = {0.f,0.f,0.f,0.f};
    #pragma unroll
    for (int kt=0; kt<4; kt++){
      s16x8 a = *(const s16x8*)&LU[ASV_US + arow*136 + kt*32 + kg*8];
      s16x8 b = *(const s16x8*)&pk[PK_LW1P + (size_t)((nt*8+kt)*64+lane)*8];
      z = MFMA(a,b,z);
    }
    f32x4 acc0 = {0.f,0.f,0.f,0.f}, acc1 = {0.f,0.f,0.f,0.f}, acc2 = {0.f,0.f,0.f,0.f};
    #pragma unroll
    for (int kt=4; kt<8; kt++){
      s16x8 b = *(const s16x8*)&pk[PK_LW1P + (size_t)((nt*8+kt)*64+lane)*8];
      s16x8 af0 = *(const s16x8*)&LU[D1_US + 0*2176 + arow*136 + (kt-4)*32 + kg*8];
      s16x8 af1 = *(const s16x8*)&LU[D1_US + 1*2176 + arow*136 + (kt-4)*32 + kg*8];
      s16x8 af2 = *(const s16x8*)&LU[D1_US + 2*2176 + arow*136 + (kt-4)*32 + kg*8];
      acc0 = MFMA(af0,b,acc0); acc1 = MFMA(af1,b,acc1); acc2 = MFMA(af2,b,acc2);
    }
    const float r16 = 0.0625f;
    int col = nt*16 + c16;
    #pragma unroll
    for (int r=0;r<4;r++){
      int er = kg*4 + r;
      float ev0 = L[OEA + er*4 + 1];
      float ev1 = L[OEA + er*4 + 2];
      float ev2 = L[OEA + er*4 + 3];
      gm1[((size_t)(e0+er)*3 + 0)*64 + col] = __float2bfloat16((z[r]*ev0 + acc0[r])*r16);
      gm1[((size_t)(e0+er)*3 + 1)*64 + col] = __float2bfloat16((z[r]*ev1 + acc1[r])*r16);
      gm1[((size_t)(e0+er)*3 + 2)*64 + col] = __float2bfloat16((z[r]*ev2 + acc2[r])*r16);
    }
  }
}

// ---------------- Kernel D v2: 16-node tile, shfl softmax, MFMA output transform ----------------
__global__ __launch_bounds__(256) void k_agg2(
  const int* __restrict__ edge_dst,
  const float* __restrict__ galpha, const __hip_bfloat16* __restrict__ gval,
  const __hip_bfloat16* __restrict__ gm1,
  const float* __restrict__ pb0, const ushort_t* __restrict__ pk,
  float* __restrict__ out)
{
  __shared__ __align__(16) float sNS[16*132];     // node_s [16][132]
  __shared__ __align__(16) float sNV[3*16*68];    // node_v [3][16][68]
  __shared__ float sAm[64], sInv[64];
  __shared__ int sB[17];
  const int t = threadIdx.x;
  const int n0 = blockIdx.x*16;
  const int lane = t&63, w = t>>6, arow = lane&15, kg = lane>>4, c16 = lane&15;

  if (t < 17){
    int target = n0 + t;
    int a=0,b=N_EDGES;
    while(a<b){ int m=(a+b)>>1; if (edge_dst[m] < target) a=m+1; else b=m; }
    sB[t]=a;
  }
  __syncthreads();

  // per-(node,head) max & denom via 4-thread groups + shfl
  {
    int p = t>>2, g = t&3;
    int node = p>>2, h = p&3;
    int lo = sB[node], hi = sB[node+1];
    float m = -1e30f;
    for (int e=lo+g; e<hi; e+=4) m = fmaxf(m, galpha[(size_t)e*4+h]);
    m = fmaxf(m, __shfl_xor(m,1));
    m = fmaxf(m, __shfl_xor(m,2));
    float am = (hi>lo) ? m : 0.f;
    float s = 0.f;
    for (int e=lo+g; e<hi; e+=4) s += __expf(galpha[(size_t)e*4+h]-am);
    s += __shfl_xor(s,1);
    s += __shfl_xor(s,2);
    if (g==0){ sAm[p]=am; sInv[p]=1.f/fmaxf(s,1e-12f); }
  }
  __syncthreads();

  // weighted accumulation: 16 threads/node, head-aligned value slices
  {
    int node = t>>4, t2 = t&15, h = t2>>2, j = t2&3;
    int lo = sB[node], hi = sB[node+1];
    float am = sAm[node*4+h], inv = sInv[node*4+h];
    float av[8];  float am1[12];
    #pragma unroll
    for (int i=0;i<8;i++) av[i]=0.f;
    #pragma unroll
    for (int i=0;i<12;i++) am1[i]=0.f;
    for (int e=lo; e<hi; e++){
      float wgt = __expf(galpha[(size_t)e*4+h]-am)*inv;
      ushort4 v0 = *(const ushort4*)&gval[(size_t)e*128 + h*32 + j*8];
      ushort4 v1 = *(const ushort4*)&gval[(size_t)e*128 + h*32 + j*8 + 4];
      av[0] += wgt*bf2f(v0.x); av[1] += wgt*bf2f(v0.y);
      av[2] += wgt*bf2f(v0.z); av[3] += wgt*bf2f(v0.w);
      av[4] += wgt*bf2f(v1.x); av[5] += wgt*bf2f(v1.y);
      av[6] += wgt*bf2f(v1.z); av[7] += wgt*bf2f(v1.w);
      #pragma unroll
      for (int c=0;c<3;c++){
        ushort4 mv = *(const ushort4*)&gm1[((size_t)e*3+c)*64 + h*16 + j*4];
        am1[c*4+0] += wgt*bf2f(mv.x); am1[c*4+1] += wgt*bf2f(mv.y);
        am1[c*4+2] += wgt*bf2f(mv.z); am1[c*4+3] += wgt*bf2f(mv.w);
      }
    }
    #pragma unroll
    for (int i=0;i<8;i++) sNS[node*132 + h*32 + j*8 + i] = av[i];
    #pragma unroll
    for (int c=0;c<3;c++)
      #pragma unroll
      for (int i=0;i<4;i++) sNV[c*1088 + node*68 + h*16 + j*4 + i] = am1[c*4+i];
  }
  __syncthreads();

  // out_s = node_s @ pw0 /sqrt(128) + pb0 (split-3 MFMA); wave w -> nt {2w, 2w+1}
  const float rs128 = 0.08838834764831845f;
  #pragma unroll
  for (int q2=0; q2<2; q2++){
    int nt = w*2 + q2;
    f32x4 acc = {0.f,0.f,0.f,0.f};
    #pragma unroll
    for (int kt=0;kt<4;kt++){
      s16x8 ah, al;
      #pragma unroll
      for (int i=0;i<8;i++){
        float x = sNS[arow*132 + kt*32 + kg*8 + i];
        ushort_t hb = f2bf(x);
        ah[i] = (short)hb; al[i] = (short)f2bf(x - bf2f(hb));
      }
      s16x8 bh = *(const s16x8*)&pk[PK_PW0H + (size_t)((nt*4+kt)*64+lane)*8];
      s16x8 bl = *(const s16x8*)&pk[PK_PW0L + (size_t)((nt*4+kt)*64+lane)*8];
      acc = MFMA(ah,bh,acc); acc = MFMA(ah,bl,acc); acc = MFMA(al,bh,acc);
    }
    int col = nt*16 + c16;
    float bb = pb0[col];
    #pragma unroll
    for (int r=0;r<4;r++)
      out[(size_t)(n0 + kg*4 + r)*320 + col] = acc[r]*rs128 + bb;
  }

  // out_v: 12 (c,nt) pairs, 3 per wave (split-3 MFMA)
  #pragma unroll
  for (int q2=0; q2<3; q2++){
    int p3 = w*3 + q2;
    int c = p3>>2, nt = p3&3;
    f32x4 acc = {0.f,0.f,0.f,0.f};
    #pragma unroll
    for (int kt=0;kt<2;kt++){
      s16x8 ah, al;
      #pragma unroll
      for (int i=0;i<8;i++){
        float x = sNV[c*1088 + arow*68 + kt*32 + kg*8 + i];
        ushort_t hb = f2bf(x);
        ah[i] = (short)hb; al[i] = (short)f2bf(x - bf2f(hb));
      }
      s16x8 bh = *(const s16x8*)&pk[PK_PW1H + (size_t)((nt*2+kt)*64+lane)*8];
      s16x8 bl = *(const s16x8*)&pk[PK_PW1L + (size_t)((nt*2+kt)*64+lane)*8];
      acc = MFMA(ah,bh,acc); acc = MFMA(ah,bl,acc); acc = MFMA(al,bh,acc);
    }
    int col = nt*16 + c16;
    #pragma unroll
    for (int r=0;r<4;r++)
      out[(size_t)(n0 + kg*4 + r)*320 + 128 + col*3 + c] = acc[r]*0.125f;
  }
}

extern "C" void kernel_launch(void* const* d_in, const int* in_sizes, int n_in,
                              void* d_out, int out_size, void* d_ws, size_t ws_size,
                              hipStream_t stream)
{
  const float* node_input  = (const float*)d_in[0];
  const float* edge_attr   = (const float*)d_in[1];
  const float* edge_scalars= (const float*)d_in[2];
  const int*   edge_src    = (const int*)d_in[3];
  const int*   edge_dst    = (const int*)d_in[4];
  const float* w_src0=(const float*)d_in[5];  const float* b_src0=(const float*)d_in[6];
  const float* w_src1=(const float*)d_in[7];
  const float* w_dst0=(const float*)d_in[8];  const float* b_dst0=(const float*)d_in[9];
  const float* w_dst1=(const float*)d_in[10];
  const float* rw1=(const float*)d_in[11];    const float* rb1=(const float*)d_in[12];
  const float* rw2=(const float*)d_in[13];    const float* rb2=(const float*)d_in[14];
  const float* rw3=(const float*)d_in[15];    const float* rb3=(const float*)d_in[16];
  const float* lw0=(const float*)d_in[17];    const float* lb0=(const float*)d_in[18];
  const float* lw1=(const float*)d_in[19];
  const float* alpha_dot=(const float*)d_in[20];
  const float* pw0=(const float*)d_in[21];    const float* pb0=(const float*)d_in[22];
  const float* pw1=(const float*)d_in[23];
  float* out = (float*)d_out;

  float* ns_src = (float*)d_ws;
  float* ns_dst = ns_src + (size_t)N_NODES*128;
  float* nv_src = ns_dst + (size_t)N_NODES*128;
  float* nv_dst = nv_src + (size_t)N_NODES*192;
  float* galpha = nv_dst + (size_t)N_NODES*192;
  __hip_bfloat16* gval = (__hip_bfloat16*)(galpha + (size_t)N_EDGES*4);
  __hip_bfloat16* gm1  = gval + (size_t)N_EDGES*128;
  ushort_t* pk = (ushort_t*)(gm1 + (size_t)N_EDGES*192);

  k_pack<<<408, 256, 0, stream>>>(rw1, rw2, rw3, lw0, lw1, pw0, pw1, pk);
  k_node<<<N_NODES/8, 256, 0, stream>>>(node_input, w_src0,b_src0,w_src1,
                                        w_dst0,b_dst0,w_dst1,
                                        ns_src,ns_dst,nv_src,nv_dst);
  k_edge5<<<N_EDGES/EB, 256, 0, stream>>>(edge_attr, edge_scalars, edge_src, edge_dst,
                                          ns_src,ns_dst,nv_src,nv_dst,
                                          rb1,rb2,rb3,lb0,alpha_dot,pk,
                                          galpha,gval,gm1);
  k_agg2<<<N_NODES/16, 256, 0, stream>>>(edge_dst, galpha, gval, gm1, pb0, pk, out);
}